// Round 1
// baseline (252.209 us; speedup 1.0000x reference)
//
#include <hip/hip_runtime.h>
#include <math.h>

typedef unsigned int uint32;

#define N_SURF 8192
#define M_QRY  32768
#define HID    256

// ---- ws layout (in floats) ----
// packed surface float4           : [0, 32768)
// keys  uint32 [4][65536][2]      : [32768, 32768+524288)
// h1T   [256][8192]               : [557056, +2097152)
// dz2T  [256][8192]               : [2654208, +2097152)
// h2R   [8192][256]               : [4751360, +2097152)
// sdf_part [2048]                 : [6848512, ...)
// ori_part [256]
// eg_part  [512]

// ---------------- K0: pack surface points ----------------
__global__ __launch_bounds__(256) void prep_surface(
    const float* __restrict__ sp, float4* __restrict__ packed) {
  int i = blockIdx.x * 256 + threadIdx.x;
  if (i < N_SURF) {
    float x = sp[i * 3 + 0], y = sp[i * 3 + 1], z = sp[i * 3 + 2];
    packed[i] = make_float4(-x, -y, -z, 0.5f * (x * x + y * y + z * z));
  }
}

// ---------------- K1: segmented 2-NN scan ----------------
// grid: 1024 blocks (4 segs x 256 q-blocks) x 256 threads
__global__ __launch_bounds__(256) void scan_knn(
    const float4* __restrict__ packed,
    const float* __restrict__ offp, const float* __restrict__ nearp,
    uint32* __restrict__ keys) {
  int seg = blockIdx.x >> 8;                       // 0..3
  int q = ((blockIdx.x & 255) << 8) + threadIdx.x; // 0..65535
  const float* qp = (q < M_QRY) ? (offp + q * 3) : (nearp + (q - M_QRY) * 3);
  float qx = qp[0], qy = qp[1], qz = qp[2];
  float c0 = 0.5f * (qx * qx + qy * qy + qz * qz);

  uint32 b1a = 0xFFFFFFFFu, b2a = 0xFFFFFFFFu;
  uint32 b1b = 0xFFFFFFFFu, b2b = 0xFFFFFFFFu;
  int base = seg * 2048;
  for (int i = base; i < base + 2048; i += 4) {
    float4 A = packed[i + 0];
    float4 B = packed[i + 1];
    float4 C = packed[i + 2];
    float4 D = packed[i + 3];
    float t0 = fmaf(qx, A.x, fmaf(qy, A.y, fmaf(qz, A.z, A.w + c0)));
    float t1 = fmaf(qx, B.x, fmaf(qy, B.y, fmaf(qz, B.z, B.w + c0)));
    float t2 = fmaf(qx, C.x, fmaf(qy, C.y, fmaf(qz, C.z, C.w + c0)));
    float t3 = fmaf(qx, D.x, fmaf(qy, D.y, fmaf(qz, D.z, D.w + c0)));
    uint32 k0 = (__float_as_uint(fmaxf(t0, 0.f)) & 0xFFFFE000u) | (uint32)(i + 0);
    uint32 k1 = (__float_as_uint(fmaxf(t1, 0.f)) & 0xFFFFE000u) | (uint32)(i + 1);
    uint32 k2 = (__float_as_uint(fmaxf(t2, 0.f)) & 0xFFFFE000u) | (uint32)(i + 2);
    uint32 k3 = (__float_as_uint(fmaxf(t3, 0.f)) & 0xFFFFE000u) | (uint32)(i + 3);
    // two independent top-2 trackers for ILP
    b2a = min(b2a, max(b1a, k0)); b1a = min(b1a, k0);
    b2b = min(b2b, max(b1b, k1)); b1b = min(b1b, k1);
    b2a = min(b2a, max(b1a, k2)); b1a = min(b1a, k2);
    b2b = min(b2b, max(b1b, k3)); b1b = min(b1b, k3);
  }
  uint32 m1 = min(b1a, b1b);
  uint32 m2 = min(max(b1a, b1b), min(b2a, b2b));
  keys[(size_t)(seg * 65536 + q) * 2 + 0] = m1;
  keys[(size_t)(seg * 65536 + q) * 2 + 1] = m2;
}

// ---------------- K1b: merge segments, compute orientation losses ----------------
__global__ __launch_bounds__(256) void knn_finish(
    const uint32* __restrict__ keys,
    const float* __restrict__ sp, const float* __restrict__ sn,
    const float* __restrict__ offp, const float* __restrict__ nearp,
    const float* __restrict__ off_pred, const float* __restrict__ near_pred,
    float* __restrict__ part) {
  int q = blockIdx.x * 256 + threadIdx.x;
  bool isOff = q < M_QRY;
  const float* qp = isOff ? (offp + q * 3) : (nearp + (q - M_QRY) * 3);
  float qx = qp[0], qy = qp[1], qz = qp[2];
  uint32 m1 = 0xFFFFFFFFu, m2 = 0xFFFFFFFFu;
  for (int s = 0; s < 4; s++) {
    uint32 k1 = keys[(size_t)(s * 65536 + q) * 2 + 0];
    uint32 k2 = keys[(size_t)(s * 65536 + q) * 2 + 1];
    m2 = min(m2, max(m1, k1)); m1 = min(m1, k1);
    m2 = min(m2, max(m1, k2)); m1 = min(m1, k2);
  }
  int i1 = (int)(m1 & 8191u), i2 = (int)(m2 & 8191u);
  float d1 = (qx - sp[i1 * 3 + 0]) * sn[i1 * 3 + 0] +
             (qy - sp[i1 * 3 + 1]) * sn[i1 * 3 + 1] +
             (qz - sp[i1 * 3 + 2]) * sn[i1 * 3 + 2];
  float d2 = (qx - sp[i2 * 3 + 0]) * sn[i2 * 3 + 0] +
             (qy - sp[i2 * 3 + 1]) * sn[i2 * 3 + 1] +
             (qz - sp[i2 * 3 + 2]) * sn[i2 * 3 + 2];
  float m = d1 + d2;  // sign(mean) == sign(sum)
  float sg = (m > 0.f) ? 1.f : ((m < 0.f) ? -1.f : 0.f);
  float pred = isOff ? off_pred[q] : near_pred[q - M_QRY];
  float contrib = fmaxf(0.f, -pred * sg);

  __shared__ float red[256];
  int t = threadIdx.x;
  red[t] = contrib;
  __syncthreads();
  for (int s = 128; s > 0; s >>= 1) {
    if (t < s) red[t] += red[t + s];
    __syncthreads();
  }
  if (t == 0) part[blockIdx.x] = red[0];
}

// ---------------- K2: layer-1 (3->256) + softplus, store k-major ----------------
__global__ __launch_bounds__(256) void mlp_l1(
    const float* __restrict__ p, const float* __restrict__ W1,
    const float* __restrict__ b1, float* __restrict__ h1T) {
  int j = blockIdx.x & 255;
  int row = (blockIdx.x >> 8) * 256 + threadIdx.x;
  float w0 = W1[j], w1 = W1[256 + j], w2 = W1[512 + j], bb = b1[j];
  float z = fmaf(p[row * 3 + 0], w0,
            fmaf(p[row * 3 + 1], w1,
            fmaf(p[row * 3 + 2], w2, bb)));
  float h = fmaxf(z, 0.f) + log1pf(expf(-fabsf(z)));  // stable softplus
  h1T[j * N_SURF + row] = h;
}

// ---------------- K3: GEMM1  z2 = h1 @ W2 + b2 ; h2=softplus ; dz2 = W3*sigmoid ----------------
#define BM 64
#define BN 64
#define BK 32
__global__ __launch_bounds__(256) void gemm1(
    const float* __restrict__ AT,   // h1T [256][8192] (k-major)
    const float* __restrict__ W2,   // [256][256]  B[k][j]
    const float* __restrict__ b2,
    const float* __restrict__ W3,   // [256]
    float* __restrict__ h2R,        // [8192][256]
    float* __restrict__ dz2T) {     // [256][8192]
  __shared__ float As[BK][BM];
  __shared__ float Bs[BK][BN];
  int row0 = blockIdx.x * BM;
  int col0 = blockIdx.y * BN;
  int tid = threadIdx.x;
  float acc[4][4] = {};
  for (int k0 = 0; k0 < HID; k0 += BK) {
    for (int c = tid; c < BK * BM / 4; c += 256) {
      int k = c >> 4, f = c & 15;
      *(float4*)&As[k][f * 4] = *(const float4*)&AT[(size_t)(k0 + k) * N_SURF + row0 + f * 4];
    }
    for (int c = tid; c < BK * BN / 4; c += 256) {
      int k = c >> 4, f = c & 15;
      *(float4*)&Bs[k][f * 4] = *(const float4*)&W2[(k0 + k) * HID + col0 + f * 4];
    }
    __syncthreads();
    int ty = tid >> 4, tx = tid & 15;
#pragma unroll
    for (int kk = 0; kk < BK; kk++) {
      float4 av = *(const float4*)&As[kk][ty * 4];
      float4 bv = *(const float4*)&Bs[kk][tx * 4];
      float a_[4] = {av.x, av.y, av.z, av.w};
      float b_[4] = {bv.x, bv.y, bv.z, bv.w};
#pragma unroll
      for (int i = 0; i < 4; i++)
#pragma unroll
        for (int j = 0; j < 4; j++)
          acc[i][j] = fmaf(a_[i], b_[j], acc[i][j]);
    }
    __syncthreads();
  }
  int ty = tid >> 4, tx = tid & 15;
  int r = row0 + ty * 4, c = col0 + tx * 4;
  float h2v[4][4];
#pragma unroll
  for (int i = 0; i < 4; i++) {
    float4 hv;
#pragma unroll
    for (int j = 0; j < 4; j++) {
      float z = acc[i][j] + b2[c + j];
      float h = fmaxf(z, 0.f) + log1pf(expf(-fabsf(z)));
      h2v[i][j] = h;
      (&hv.x)[j] = h;
    }
    *(float4*)&h2R[(size_t)(r + i) * HID + c] = hv;
  }
#pragma unroll
  for (int j = 0; j < 4; j++) {
    float w3 = W3[c + j];
    float4 d;
#pragma unroll
    for (int i = 0; i < 4; i++) (&d.x)[i] = w3 * (1.f - expf(-h2v[i][j]));
    *(float4*)&dz2T[(size_t)(c + j) * N_SURF + r] = d;
  }
}

// ---------------- K4: head  pred = h2 . W3 + b3 ; sdf partials ----------------
__global__ __launch_bounds__(256) void head(
    const float* __restrict__ h2R, const float* __restrict__ W3,
    const float* __restrict__ b3, float* __restrict__ sdf_part) {
  int wave = threadIdx.x >> 6, lane = threadIdx.x & 63;
  int row = blockIdx.x * 4 + wave;
  float4 h = *(const float4*)&h2R[(size_t)row * HID + lane * 4];
  float4 w = *(const float4*)&W3[lane * 4];
  float s = h.x * w.x + h.y * w.y + h.z * w.z + h.w * w.w;
  for (int off = 32; off > 0; off >>= 1) s += __shfl_down(s, off);
  __shared__ float red[4];
  if (lane == 0) {
    float pred = s + b3[0];
    red[wave] = pred * pred;
  }
  __syncthreads();
  if (threadIdx.x == 0)
    sdf_part[blockIdx.x] = red[0] + red[1] + red[2] + red[3];
}

// ---------------- K5: GEMM2  dh1 = dz2 @ W2^T ; dz1 ; grad ; eik+gradn partials ----------------
__global__ __launch_bounds__(256) void gemm2(
    const float* __restrict__ AT,   // dz2T [256][8192] (k-major, k=j)
    const float* __restrict__ W2,   // [256][256]; need B[k=j][i] = W2[i][j]
    const float* __restrict__ h1T,  // [256][8192]
    const float* __restrict__ W1,   // [3][256]
    const float* __restrict__ sn,   // [8192][3]
    float* __restrict__ eg_part) {  // [256][2]
  const int BM2 = 32, BN2 = 256, BK2 = 32;
  __shared__ float As[BK2][BM2];    // 4KB
  __shared__ float Bs[BK2][BN2];    // 32KB
  __shared__ float red[96][33];
  __shared__ float gsum[96];
  __shared__ float ee[32], gg[32];
  int row0 = blockIdx.x * BM2;
  int tid = threadIdx.x;
  float acc[4][8] = {};
  for (int k0 = 0; k0 < HID; k0 += BK2) {
    {
      int k = tid >> 3, f = tid & 7;
      *(float4*)&As[k][f * 4] = *(const float4*)&AT[(size_t)(k0 + k) * N_SURF + row0 + f * 4];
    }
#pragma unroll
    for (int f = 0; f < 8; f++) {
      float4 w = *(const float4*)&W2[tid * HID + k0 + f * 4];
      Bs[f * 4 + 0][tid] = w.x;
      Bs[f * 4 + 1][tid] = w.y;
      Bs[f * 4 + 2][tid] = w.z;
      Bs[f * 4 + 3][tid] = w.w;
    }
    __syncthreads();
    int rg = tid >> 5, cg = tid & 31;
#pragma unroll
    for (int kk = 0; kk < BK2; kk++) {
      float4 av = *(const float4*)&As[kk][rg * 4];
      float4 b0 = *(const float4*)&Bs[kk][cg * 4];        // cols [cg*4, cg*4+3]
      float4 b1v = *(const float4*)&Bs[kk][128 + cg * 4]; // cols [128+cg*4, ...]
      float a_[4] = {av.x, av.y, av.z, av.w};
      float b_[8] = {b0.x, b0.y, b0.z, b0.w, b1v.x, b1v.y, b1v.z, b1v.w};
#pragma unroll
      for (int i = 0; i < 4; i++)
#pragma unroll
        for (int j = 0; j < 8; j++)
          acc[i][j] = fmaf(a_[i], b_[j], acc[i][j]);
    }
    __syncthreads();
  }
  int rg = tid >> 5, cg = tid & 31;
  float g[4][3] = {};
#pragma unroll
  for (int i = 0; i < 4; i++) {
    int row = row0 + rg * 4 + i;
#pragma unroll
    for (int jj = 0; jj < 8; jj++) {
      int col = (jj < 4) ? (cg * 4 + jj) : (128 + cg * 4 + (jj - 4));
      float h1 = h1T[(size_t)col * N_SURF + row];
      float s1 = 1.f - expf(-h1);
      float dz1 = acc[i][jj] * s1;
      g[i][0] = fmaf(dz1, W1[col], g[i][0]);
      g[i][1] = fmaf(dz1, W1[256 + col], g[i][1]);
      g[i][2] = fmaf(dz1, W1[512 + col], g[i][2]);
    }
  }
#pragma unroll
  for (int i = 0; i < 4; i++)
#pragma unroll
    for (int k = 0; k < 3; k++) red[(rg * 4 + i) * 3 + k][cg] = g[i][k];
  __syncthreads();
  if (tid < 96) {
    float s = 0.f;
#pragma unroll
    for (int c2 = 0; c2 < 32; c2++) s += red[tid][c2];
    gsum[tid] = s;
  }
  __syncthreads();
  if (tid < 32) {
    float g0 = gsum[tid * 3 + 0], g1 = gsum[tid * 3 + 1], g2 = gsum[tid * 3 + 2];
    int row = row0 + tid;
    float n0 = sn[row * 3 + 0], n1 = sn[row * 3 + 1], n2 = sn[row * 3 + 2];
    float nrm = sqrtf(g0 * g0 + g1 * g1 + g2 * g2);
    ee[tid] = (nrm - 1.f) * (nrm - 1.f);
    gg[tid] = (g0 - n0) * (g0 - n0) + (g1 - n1) * (g1 - n1) + (g2 - n2) * (g2 - n2);
  }
  __syncthreads();
  if (tid == 0) {
    float a = 0.f, b = 0.f;
    for (int i2 = 0; i2 < 32; i2++) { a += ee[i2]; b += gg[i2]; }
    eg_part[blockIdx.x * 2 + 0] = a;
    eg_part[blockIdx.x * 2 + 1] = b;
  }
}

// ---------------- K6: final reduce ----------------
__global__ __launch_bounds__(256) void finalize(
    const float* __restrict__ sdf_part,   // 2048
    const float* __restrict__ ori_part,   // 256 (128 off, 128 near)
    const float* __restrict__ eg_part,    // 512
    float* __restrict__ out) {
  __shared__ float red[256];
  int t = threadIdx.x;
  float s_sdf = 0.f;
  for (int i = t; i < 2048; i += 256) s_sdf += sdf_part[i];
  float s_ori = (t < 128) ? ori_part[t] : 0.f;
  float s_near = (t < 128) ? ori_part[128 + t] : 0.f;
  float s_eik = eg_part[t * 2 + 0];
  float s_gn = eg_part[t * 2 + 1];

  float S[5];
  float vals[5] = {s_sdf, s_ori, s_near, s_eik, s_gn};
  for (int v = 0; v < 5; v++) {
    red[t] = vals[v];
    __syncthreads();
    for (int s = 128; s > 0; s >>= 1) {
      if (t < s) red[t] += red[t + s];
      __syncthreads();
    }
    S[v] = red[0];
    __syncthreads();
  }
  if (t == 0) {
    float sdf = S[0] / 8192.f;
    float ori = S[1] / 32768.f;
    float nearo = S[2] / 32768.f;
    float eik = S[3] / 8192.f;
    float gn = S[4] / 24576.f;
    out[0] = 7000.f * sdf + 600.f * eik + 500.f * ori + 10.f * nearo + 200.f * gn;
    out[1] = sdf;
    out[2] = eik;
    out[3] = ori;
    out[4] = nearo;
    out[5] = gn;
  }
}

extern "C" void kernel_launch(void* const* d_in, const int* in_sizes, int n_in,
                              void* d_out, int out_size, void* d_ws, size_t ws_size,
                              hipStream_t stream) {
  const float* sp       = (const float*)d_in[0];
  const float* sn       = (const float*)d_in[1];
  const float* offp     = (const float*)d_in[2];
  const float* nearp    = (const float*)d_in[3];
  const float* off_pred = (const float*)d_in[4];
  const float* near_pred= (const float*)d_in[5];
  const float* W1 = (const float*)d_in[6];
  const float* b1 = (const float*)d_in[7];
  const float* W2 = (const float*)d_in[8];
  const float* b2 = (const float*)d_in[9];
  const float* W3 = (const float*)d_in[10];
  const float* b3 = (const float*)d_in[11];

  float* ws = (float*)d_ws;
  float4* packed   = (float4*)ws;                 // 32768 floats
  uint32* keys     = (uint32*)(ws + 32768);       // 524288 u32
  float* h1T       = ws + 557056;                 // 2097152
  float* dz2T      = ws + 2654208;                // 2097152
  float* h2R       = ws + 4751360;                // 2097152
  float* sdf_part  = ws + 6848512;                // 2048
  float* ori_part  = sdf_part + 2048;             // 256
  float* eg_part   = ori_part + 256;              // 512
  float* out = (float*)d_out;

  prep_surface<<<32, 256, 0, stream>>>(sp, packed);
  scan_knn<<<1024, 256, 0, stream>>>(packed, offp, nearp, keys);
  knn_finish<<<256, 256, 0, stream>>>(keys, sp, sn, offp, nearp, off_pred, near_pred, ori_part);
  mlp_l1<<<8192, 256, 0, stream>>>(sp, W1, b1, h1T);
  dim3 g1(128, 4);
  gemm1<<<g1, 256, 0, stream>>>(h1T, W2, b2, W3, h2R, dz2T);
  head<<<2048, 256, 0, stream>>>(h2R, W3, b3, sdf_part);
  gemm2<<<256, 256, 0, stream>>>(dz2T, W2, h1T, W1, sn, eg_part);
  finalize<<<1, 256, 0, stream>>>(sdf_part, ori_part, eg_part, out);
}

// Round 2
// 164.208 us; speedup vs baseline: 1.5359x; 1.5359x over previous
//
#include <hip/hip_runtime.h>
#include <math.h>

typedef unsigned int uint32;

#define N_SURF 8192
#define M_QRY  32768
#define M_TOT  65536
#define HID    256

using f16x8  = __attribute__((ext_vector_type(8)))  _Float16;
using f32x16 = __attribute__((ext_vector_type(16))) float;

static __device__ __forceinline__ uint32 umin32(uint32 a, uint32 b) { return a < b ? a : b; }
static __device__ __forceinline__ uint32 umax32(uint32 a, uint32 b) { return a > b ? a : b; }

__device__ __forceinline__ void gload_lds16(const void* g, void* l) {
  __builtin_amdgcn_global_load_lds(
      (const __attribute__((address_space(1))) unsigned int*)g,
      (__attribute__((address_space(3))) unsigned int*)l, 16, 0, 0);
}

// ---- ws layout (floats) ----
// [0)        h1T   [2097152]   (keys[131072 u32] aliases [0,131072) — dead before mlp_l1)
// [2097152)  dz2T  [2097152]   (AqG f16[M][16] = 524288 fl @2097152; BsG = 65536 fl @2621440;
//                               c0G = 65536 fl @2686976 — all dead before gemm1)
// [4194304)  h2R   [2097152]
// [6291456)  sdf_part[2048]  ori_part[256] @6293504  eg_part[512] @6293760

// ---------------- K1: prep — split coords to f16 hi/lo feature vectors ----------------
// Query feature A[k]: [qh0,qh1,qh2, ql0,ql1,ql2, qh0,qh1,qh2, ql0,ql1,ql2, 1,1,1, 0]
// Point feature B[k]: [-sh0,-sh1,-sh2, -sh0,-sh1,-sh2, -sl0,-sl1,-sl2, -sl0,-sl1,-sl2, wh,wl,wll, 0]
// => sum_k A[k]B[k] = 0.5|s|^2 - q.s ;  + C(=0.5|q|^2) = 0.5*d^2
__global__ __launch_bounds__(256) void prep(
    const float* __restrict__ sp,
    const float* __restrict__ offp, const float* __restrict__ nearp,
    _Float16* __restrict__ AqG, _Float16* __restrict__ BsG,
    float* __restrict__ c0G) {
  int tid = threadIdx.x;
  if (blockIdx.x < 256) {
    int q = blockIdx.x * 256 + tid;
    const float* p = (q < M_QRY) ? (offp + q * 3) : (nearp + (q - M_QRY) * 3);
    float x = p[0], y = p[1], z = p[2];
    _Float16 hx = (_Float16)x, hy = (_Float16)y, hz = (_Float16)z;
    _Float16 lx = (_Float16)(x - (float)hx);
    _Float16 ly = (_Float16)(y - (float)hy);
    _Float16 lz = (_Float16)(z - (float)hz);
    float tx = (float)hx + (float)lx, ty = (float)hy + (float)ly, tz = (float)hz + (float)lz;
    _Float16 av[16] = {hx, hy, hz, lx, ly, lz, hx, hy, hz, lx, ly, lz,
                       (_Float16)1.0f, (_Float16)1.0f, (_Float16)1.0f, (_Float16)0.0f};
    float4* dst = (float4*)&AqG[(size_t)q * 16];
    dst[0] = *(float4*)&av[0];
    dst[1] = *(float4*)&av[8];
    c0G[q] = 0.5f * (tx * tx + ty * ty + tz * tz);
  } else {
    int i = (blockIdx.x - 256) * 256 + tid;   // 0..8191
    float x = sp[i * 3 + 0], y = sp[i * 3 + 1], z = sp[i * 3 + 2];
    _Float16 hx = (_Float16)x, hy = (_Float16)y, hz = (_Float16)z;
    _Float16 lx = (_Float16)(x - (float)hx);
    _Float16 ly = (_Float16)(y - (float)hy);
    _Float16 lz = (_Float16)(z - (float)hz);
    float tx = (float)hx + (float)lx, ty = (float)hy + (float)ly, tz = (float)hz + (float)lz;
    float w = 0.5f * (tx * tx + ty * ty + tz * tz);
    _Float16 wh = (_Float16)w;
    float r1 = w - (float)wh;
    _Float16 wl = (_Float16)r1;
    _Float16 wll = (_Float16)(r1 - (float)wl);
    _Float16 nhx = -hx, nhy = -hy, nhz = -hz, nlx = -lx, nly = -ly, nlz = -lz;
    _Float16 b0[8] = {nhx, nhy, nhz, nhx, nhy, nhz, nlx, nly};            // k0..7
    _Float16 b1v[8] = {nlz, nlx, nly, nlz, wh, wl, wll, (_Float16)0.0f};  // k8..15
    int tile = i >> 5, pcol = i & 31;
    // frag order: unit index (tile*2 + half)*32 + pcol, 16B units
    *(float4*)&BsG[(size_t)((tile * 2 + 0) * 32 + pcol) * 8] = *(float4*)&b0[0];
    *(float4*)&BsG[(size_t)((tile * 2 + 1) * 32 + pcol) * 8] = *(float4*)&b1v[0];
  }
}

// ---------------- K2: MFMA 2-NN scan ----------------
// 512 blocks x 256 thr (4 waves); wave owns 32 queries, scans all 8192 points.
// LDS: 2 x 32KB chunk double-buffer (1024 points each).
__global__ __launch_bounds__(256) void scan_knn2(
    const float4* __restrict__ BsG,    // 8192*2 16B units, frag order
    const float4* __restrict__ AqG,    // 65536*2 16B units
    const float* __restrict__ c0G,
    uint32* __restrict__ keys) {       // [65536][2]
  __shared__ float4 Bsh[4096];         // 64KB
  int tid = threadIdx.x;
  int lane = tid & 63, wid = tid >> 6;
  int col = lane & 31, half = lane >> 5;
  int qbase = blockIdx.x * 128 + wid * 32;

  f16x8 afrag = ((const f16x8*)AqG)[(qbase + col) * 2 + half];
  f32x16 c0f;
#pragma unroll
  for (int r = 0; r < 16; r++) {
    int row = (r & 3) + 8 * (r >> 2) + 4 * half;
    c0f[r] = c0G[qbase + row];
  }
  uint32 b1[16], b2[16];
#pragma unroll
  for (int r = 0; r < 16; r++) { b1[r] = 0xFFFFFFFFu; b2[r] = 0xFFFFFFFFu; }

  const char* gbase = (const char*)BsG;
  char* lbase = (char*)&Bsh[0];
  // prologue: stage chunks 0,1 (8 x 16B per thread per chunk)
#pragma unroll
  for (int i = 0; i < 8; i++)
    gload_lds16(gbase + (size_t)(0 * 2048 + i * 256 + tid) * 16, lbase + (0 * 32768 + (i * 256 + tid) * 16));
#pragma unroll
  for (int i = 0; i < 8; i++)
    gload_lds16(gbase + (size_t)(1 * 2048 + i * 256 + tid) * 16, lbase + (1 * 32768 + (i * 256 + tid) * 16));

  uint32 vidx = (uint32)col;
  const uint32 smask = 0xFFFFE000u;
#pragma unroll 1
  for (int c = 0; c < 8; c++) {
    if (c < 7) asm volatile("s_waitcnt vmcnt(8)" ::: "memory");
    else       asm volatile("s_waitcnt vmcnt(0)" ::: "memory");
    __builtin_amdgcn_s_barrier();
    const f16x8* bbuf = (const f16x8*)&Bsh[(c & 1) * 2048];
#pragma unroll 4
    for (int t2 = 0; t2 < 32; t2++) {
      f16x8 bfrag = bbuf[t2 * 64 + lane];
      f32x16 d = __builtin_amdgcn_mfma_f32_32x32x16_f16(afrag, bfrag, c0f, 0, 0, 0);
#pragma unroll
      for (int r = 0; r < 16; r++) {
        uint32 key = (__float_as_uint(d[r]) & smask) | vidx;
        asm("v_med3_u32 %0, %1, %2, %3" : "=v"(b2[r]) : "v"(b1[r]), "v"(b2[r]), "v"(key));
        b1[r] = umin32(b1[r], key);
      }
      vidx += 32;
    }
    __builtin_amdgcn_s_barrier();
    if (c + 2 < 8) {
      int nc = c + 2;
#pragma unroll
      for (int i = 0; i < 8; i++)
        gload_lds16(gbase + (size_t)(nc * 2048 + i * 256 + tid) * 16,
                    lbase + ((nc & 1) * 32768 + (i * 256 + tid) * 16));
    }
  }

  // merge top-2 across the 16 column-lanes (xor 1,2,4,8,16 stays within 32-half)
#pragma unroll
  for (int r = 0; r < 16; r++) {
#pragma unroll
    for (int m = 1; m <= 16; m <<= 1) {
      uint32 o1 = (uint32)__shfl_xor((int)b1[r], m, 64);
      uint32 o2 = (uint32)__shfl_xor((int)b2[r], m, 64);
      uint32 n1 = umin32(b1[r], o1);
      uint32 n2 = umin32(umax32(b1[r], o1), umin32(b2[r], o2));
      b1[r] = n1; b2[r] = n2;
    }
  }
  if (col == 0) {
#pragma unroll
    for (int r = 0; r < 16; r++) {
      int row = (r & 3) + 8 * (r >> 2) + 4 * half;
      keys[(size_t)(qbase + row) * 2 + 0] = b1[r];
      keys[(size_t)(qbase + row) * 2 + 1] = b2[r];
    }
  }
}

// ---------------- K3: gather normals, signs, orientation partials ----------------
__global__ __launch_bounds__(256) void knn_finish(
    const uint32* __restrict__ keys,
    const float* __restrict__ sp, const float* __restrict__ sn,
    const float* __restrict__ offp, const float* __restrict__ nearp,
    const float* __restrict__ off_pred, const float* __restrict__ near_pred,
    float* __restrict__ part) {
  int q = blockIdx.x * 256 + threadIdx.x;
  bool isOff = q < M_QRY;
  const float* qp = isOff ? (offp + q * 3) : (nearp + (q - M_QRY) * 3);
  float qx = qp[0], qy = qp[1], qz = qp[2];
  uint32 m1 = keys[(size_t)q * 2 + 0];
  uint32 m2 = keys[(size_t)q * 2 + 1];
  int i1 = (int)(m1 & 8191u), i2 = (int)(m2 & 8191u);
  float d1 = (qx - sp[i1 * 3 + 0]) * sn[i1 * 3 + 0] +
             (qy - sp[i1 * 3 + 1]) * sn[i1 * 3 + 1] +
             (qz - sp[i1 * 3 + 2]) * sn[i1 * 3 + 2];
  float d2 = (qx - sp[i2 * 3 + 0]) * sn[i2 * 3 + 0] +
             (qy - sp[i2 * 3 + 1]) * sn[i2 * 3 + 1] +
             (qz - sp[i2 * 3 + 2]) * sn[i2 * 3 + 2];
  float m = d1 + d2;
  float sg = (m > 0.f) ? 1.f : ((m < 0.f) ? -1.f : 0.f);
  float pred = isOff ? off_pred[q] : near_pred[q - M_QRY];
  float contrib = fmaxf(0.f, -pred * sg);

  __shared__ float red[256];
  int t = threadIdx.x;
  red[t] = contrib;
  __syncthreads();
  for (int s = 128; s > 0; s >>= 1) {
    if (t < s) red[t] += red[t + s];
    __syncthreads();
  }
  if (t == 0) part[blockIdx.x] = red[0];
}

// ---------------- K4: layer-1 (3->256) + softplus, store k-major ----------------
__global__ __launch_bounds__(256) void mlp_l1(
    const float* __restrict__ p, const float* __restrict__ W1,
    const float* __restrict__ b1, float* __restrict__ h1T) {
  int j = blockIdx.x & 255;
  int row = (blockIdx.x >> 8) * 256 + threadIdx.x;
  float w0 = W1[j], w1 = W1[256 + j], w2 = W1[512 + j], bb = b1[j];
  float z = fmaf(p[row * 3 + 0], w0,
            fmaf(p[row * 3 + 1], w1,
            fmaf(p[row * 3 + 2], w2, bb)));
  float h = fmaxf(z, 0.f) + log1pf(expf(-fabsf(z)));
  h1T[j * N_SURF + row] = h;
}

// ---------------- K5: GEMM1  z2 = h1 @ W2 + b2 ; h2=softplus ; dz2 = W3*sigmoid ----------------
#define BM 64
#define BN 64
#define BK 32
__global__ __launch_bounds__(256) void gemm1(
    const float* __restrict__ AT,   // h1T [256][8192]
    const float* __restrict__ W2,   // [256][256]
    const float* __restrict__ b2,
    const float* __restrict__ W3,   // [256]
    float* __restrict__ h2R,        // [8192][256]
    float* __restrict__ dz2T) {     // [256][8192]
  __shared__ float As[BK][BM];
  __shared__ float Bs[BK][BN];
  int row0 = blockIdx.x * BM;
  int col0 = blockIdx.y * BN;
  int tid = threadIdx.x;
  float acc[4][4] = {};
  for (int k0 = 0; k0 < HID; k0 += BK) {
    for (int c = tid; c < BK * BM / 4; c += 256) {
      int k = c >> 4, f = c & 15;
      *(float4*)&As[k][f * 4] = *(const float4*)&AT[(size_t)(k0 + k) * N_SURF + row0 + f * 4];
    }
    for (int c = tid; c < BK * BN / 4; c += 256) {
      int k = c >> 4, f = c & 15;
      *(float4*)&Bs[k][f * 4] = *(const float4*)&W2[(k0 + k) * HID + col0 + f * 4];
    }
    __syncthreads();
    int ty = tid >> 4, tx = tid & 15;
#pragma unroll
    for (int kk = 0; kk < BK; kk++) {
      float4 av = *(const float4*)&As[kk][ty * 4];
      float4 bv = *(const float4*)&Bs[kk][tx * 4];
      float a_[4] = {av.x, av.y, av.z, av.w};
      float b_[4] = {bv.x, bv.y, bv.z, bv.w};
#pragma unroll
      for (int i = 0; i < 4; i++)
#pragma unroll
        for (int j = 0; j < 4; j++)
          acc[i][j] = fmaf(a_[i], b_[j], acc[i][j]);
    }
    __syncthreads();
  }
  int ty = tid >> 4, tx = tid & 15;
  int r = row0 + ty * 4, c = col0 + tx * 4;
  float h2v[4][4];
#pragma unroll
  for (int i = 0; i < 4; i++) {
    float4 hv;
#pragma unroll
    for (int j = 0; j < 4; j++) {
      float z = acc[i][j] + b2[c + j];
      float h = fmaxf(z, 0.f) + log1pf(expf(-fabsf(z)));
      h2v[i][j] = h;
      (&hv.x)[j] = h;
    }
    *(float4*)&h2R[(size_t)(r + i) * HID + c] = hv;
  }
#pragma unroll
  for (int j = 0; j < 4; j++) {
    float w3 = W3[c + j];
    float4 d;
#pragma unroll
    for (int i = 0; i < 4; i++) (&d.x)[i] = w3 * (1.f - expf(-h2v[i][j]));
    *(float4*)&dz2T[(size_t)(c + j) * N_SURF + r] = d;
  }
}

// ---------------- K6: head  pred = h2 . W3 + b3 ; sdf partials ----------------
__global__ __launch_bounds__(256) void head(
    const float* __restrict__ h2R, const float* __restrict__ W3,
    const float* __restrict__ b3, float* __restrict__ sdf_part) {
  int wave = threadIdx.x >> 6, lane = threadIdx.x & 63;
  int row = blockIdx.x * 4 + wave;
  float4 h = *(const float4*)&h2R[(size_t)row * HID + lane * 4];
  float4 w = *(const float4*)&W3[lane * 4];
  float s = h.x * w.x + h.y * w.y + h.z * w.z + h.w * w.w;
  for (int off = 32; off > 0; off >>= 1) s += __shfl_down(s, off);
  __shared__ float red[4];
  if (lane == 0) {
    float pred = s + b3[0];
    red[wave] = pred * pred;
  }
  __syncthreads();
  if (threadIdx.x == 0)
    sdf_part[blockIdx.x] = red[0] + red[1] + red[2] + red[3];
}

// ---------------- K7: GEMM2  dh1 = dz2 @ W2^T ; dz1 ; grad ; eik+gradn partials ----------------
__global__ __launch_bounds__(256) void gemm2(
    const float* __restrict__ AT,   // dz2T [256][8192]
    const float* __restrict__ W2,   // [256][256]
    const float* __restrict__ h1T,  // [256][8192]
    const float* __restrict__ W1,   // [3][256]
    const float* __restrict__ sn,   // [8192][3]
    float* __restrict__ eg_part) {  // [256][2]
  const int BM2 = 32, BN2 = 256, BK2 = 32;
  __shared__ float As[BK2][BM2];
  __shared__ float Bs[BK2][BN2];
  __shared__ float red[96][33];
  __shared__ float gsum[96];
  __shared__ float ee[32], gg[32];
  int row0 = blockIdx.x * BM2;
  int tid = threadIdx.x;
  float acc[4][8] = {};
  for (int k0 = 0; k0 < HID; k0 += BK2) {
    {
      int k = tid >> 3, f = tid & 7;
      *(float4*)&As[k][f * 4] = *(const float4*)&AT[(size_t)(k0 + k) * N_SURF + row0 + f * 4];
    }
#pragma unroll
    for (int f = 0; f < 8; f++) {
      float4 w = *(const float4*)&W2[tid * HID + k0 + f * 4];
      Bs[f * 4 + 0][tid] = w.x;
      Bs[f * 4 + 1][tid] = w.y;
      Bs[f * 4 + 2][tid] = w.z;
      Bs[f * 4 + 3][tid] = w.w;
    }
    __syncthreads();
    int rg = tid >> 5, cg = tid & 31;
#pragma unroll
    for (int kk = 0; kk < BK2; kk++) {
      float4 av = *(const float4*)&As[kk][rg * 4];
      float4 b0 = *(const float4*)&Bs[kk][cg * 4];
      float4 b1v = *(const float4*)&Bs[kk][128 + cg * 4];
      float a_[4] = {av.x, av.y, av.z, av.w};
      float b_[8] = {b0.x, b0.y, b0.z, b0.w, b1v.x, b1v.y, b1v.z, b1v.w};
#pragma unroll
      for (int i = 0; i < 4; i++)
#pragma unroll
        for (int j = 0; j < 8; j++)
          acc[i][j] = fmaf(a_[i], b_[j], acc[i][j]);
    }
    __syncthreads();
  }
  int rg = tid >> 5, cg = tid & 31;
  float g[4][3] = {};
#pragma unroll
  for (int i = 0; i < 4; i++) {
    int row = row0 + rg * 4 + i;
#pragma unroll
    for (int jj = 0; jj < 8; jj++) {
      int colj = (jj < 4) ? (cg * 4 + jj) : (128 + cg * 4 + (jj - 4));
      float h1 = h1T[(size_t)colj * N_SURF + row];
      float s1 = 1.f - expf(-h1);
      float dz1 = acc[i][jj] * s1;
      g[i][0] = fmaf(dz1, W1[colj], g[i][0]);
      g[i][1] = fmaf(dz1, W1[256 + colj], g[i][1]);
      g[i][2] = fmaf(dz1, W1[512 + colj], g[i][2]);
    }
  }
#pragma unroll
  for (int i = 0; i < 4; i++)
#pragma unroll
    for (int k = 0; k < 3; k++) red[(rg * 4 + i) * 3 + k][cg] = g[i][k];
  __syncthreads();
  if (tid < 96) {
    float s = 0.f;
#pragma unroll
    for (int c2 = 0; c2 < 32; c2++) s += red[tid][c2];
    gsum[tid] = s;
  }
  __syncthreads();
  if (tid < 32) {
    float g0 = gsum[tid * 3 + 0], g1 = gsum[tid * 3 + 1], g2 = gsum[tid * 3 + 2];
    int row = row0 + tid;
    float n0 = sn[row * 3 + 0], n1 = sn[row * 3 + 1], n2 = sn[row * 3 + 2];
    float nrm = sqrtf(g0 * g0 + g1 * g1 + g2 * g2);
    ee[tid] = (nrm - 1.f) * (nrm - 1.f);
    gg[tid] = (g0 - n0) * (g0 - n0) + (g1 - n1) * (g1 - n1) + (g2 - n2) * (g2 - n2);
  }
  __syncthreads();
  if (tid == 0) {
    float a = 0.f, b = 0.f;
    for (int i2 = 0; i2 < 32; i2++) { a += ee[i2]; b += gg[i2]; }
    eg_part[blockIdx.x * 2 + 0] = a;
    eg_part[blockIdx.x * 2 + 1] = b;
  }
}

// ---------------- K8: final reduce ----------------
__global__ __launch_bounds__(256) void finalize(
    const float* __restrict__ sdf_part,
    const float* __restrict__ ori_part,
    const float* __restrict__ eg_part,
    float* __restrict__ out) {
  __shared__ float red[256];
  int t = threadIdx.x;
  float s_sdf = 0.f;
  for (int i = t; i < 2048; i += 256) s_sdf += sdf_part[i];
  float s_ori = (t < 128) ? ori_part[t] : 0.f;
  float s_near = (t < 128) ? ori_part[128 + t] : 0.f;
  float s_eik = eg_part[t * 2 + 0];
  float s_gn = eg_part[t * 2 + 1];

  float S[5];
  float vals[5] = {s_sdf, s_ori, s_near, s_eik, s_gn};
  for (int v = 0; v < 5; v++) {
    red[t] = vals[v];
    __syncthreads();
    for (int s = 128; s > 0; s >>= 1) {
      if (t < s) red[t] += red[t + s];
      __syncthreads();
    }
    S[v] = red[0];
    __syncthreads();
  }
  if (t == 0) {
    float sdf = S[0] / 8192.f;
    float ori = S[1] / 32768.f;
    float nearo = S[2] / 32768.f;
    float eik = S[3] / 8192.f;
    float gn = S[4] / 24576.f;
    out[0] = 7000.f * sdf + 600.f * eik + 500.f * ori + 10.f * nearo + 200.f * gn;
    out[1] = sdf;
    out[2] = eik;
    out[3] = ori;
    out[4] = nearo;
    out[5] = gn;
  }
}

extern "C" void kernel_launch(void* const* d_in, const int* in_sizes, int n_in,
                              void* d_out, int out_size, void* d_ws, size_t ws_size,
                              hipStream_t stream) {
  const float* sp       = (const float*)d_in[0];
  const float* sn       = (const float*)d_in[1];
  const float* offp     = (const float*)d_in[2];
  const float* nearp    = (const float*)d_in[3];
  const float* off_pred = (const float*)d_in[4];
  const float* near_pred= (const float*)d_in[5];
  const float* W1 = (const float*)d_in[6];
  const float* b1 = (const float*)d_in[7];
  const float* W2 = (const float*)d_in[8];
  const float* b2 = (const float*)d_in[9];
  const float* W3 = (const float*)d_in[10];
  const float* b3 = (const float*)d_in[11];

  float* ws = (float*)d_ws;
  float* h1T       = ws;                          // [0, 2097152)
  uint32* keys     = (uint32*)ws;                 // alias, dead before mlp_l1
  float* dz2T      = ws + 2097152;                // [2097152, 4194304)
  _Float16* AqG    = (_Float16*)(ws + 2097152);   // alias, dead before gemm1
  _Float16* BsG    = (_Float16*)(ws + 2621440);   // alias
  float* c0G       = ws + 2686976;                // alias
  float* h2R       = ws + 4194304;                // [4194304, 6291456)
  float* sdf_part  = ws + 6291456;                // 2048
  float* ori_part  = sdf_part + 2048;             // 256
  float* eg_part   = ori_part + 256;              // 512
  float* out = (float*)d_out;

  prep<<<288, 256, 0, stream>>>(sp, offp, nearp, AqG, BsG, c0G);
  scan_knn2<<<512, 256, 0, stream>>>((const float4*)BsG, (const float4*)AqG, c0G, keys);
  knn_finish<<<256, 256, 0, stream>>>(keys, sp, sn, offp, nearp, off_pred, near_pred, ori_part);
  mlp_l1<<<8192, 256, 0, stream>>>(sp, W1, b1, h1T);
  dim3 g1(128, 4);
  gemm1<<<g1, 256, 0, stream>>>(h1T, W2, b2, W3, h2R, dz2T);
  head<<<2048, 256, 0, stream>>>(h2R, W3, b3, sdf_part);
  gemm2<<<256, 256, 0, stream>>>(dz2T, W2, h1T, W1, sn, eg_part);
  finalize<<<1, 256, 0, stream>>>(sdf_part, ori_part, eg_part, out);
}

// Round 3
// 156.124 us; speedup vs baseline: 1.6154x; 1.0518x over previous
//
#include <hip/hip_runtime.h>
#include <math.h>

typedef unsigned int uint32;

#define N_SURF 8192
#define M_QRY  32768
#define M_TOT  65536
#define HID    256

using f16x8  = __attribute__((ext_vector_type(8)))  _Float16;
using f32x16 = __attribute__((ext_vector_type(16))) float;

static __device__ __forceinline__ uint32 umin32(uint32 a, uint32 b) { return a < b ? a : b; }
static __device__ __forceinline__ uint32 umax32(uint32 a, uint32 b) { return a > b ? a : b; }

__device__ __forceinline__ void gload_lds16(const void* g, void* l) {
  __builtin_amdgcn_global_load_lds(
      (const __attribute__((address_space(1))) unsigned int*)g,
      (__attribute__((address_space(3))) unsigned int*)l, 16, 0, 0);
}

// ---- ws layout (floats) ----
// [0)        h1T   [2097152]   (keys[262144 u32] aliases [0,262144) — dead before mlp_l1)
// [2097152)  dz2T  [2097152]   (AqG f16[M][16] = 524288 fl @2097152; BsG = 65536 fl @2621440;
//                               c0G = 65536 fl @2686976 — all dead before gemm1)
// [4194304)  h2R   [2097152]
// [6291456)  sdf_part[2048]  ori_part[256] @6293504  eg_part[512] @6293760

// ---------------- K1: prep — split coords to f16 hi/lo feature vectors ----------------
__global__ __launch_bounds__(256) void prep(
    const float* __restrict__ sp,
    const float* __restrict__ offp, const float* __restrict__ nearp,
    _Float16* __restrict__ AqG, _Float16* __restrict__ BsG,
    float* __restrict__ c0G) {
  int tid = threadIdx.x;
  if (blockIdx.x < 256) {
    int q = blockIdx.x * 256 + tid;
    const float* p = (q < M_QRY) ? (offp + q * 3) : (nearp + (q - M_QRY) * 3);
    float x = p[0], y = p[1], z = p[2];
    _Float16 hx = (_Float16)x, hy = (_Float16)y, hz = (_Float16)z;
    _Float16 lx = (_Float16)(x - (float)hx);
    _Float16 ly = (_Float16)(y - (float)hy);
    _Float16 lz = (_Float16)(z - (float)hz);
    float tx = (float)hx + (float)lx, ty = (float)hy + (float)ly, tz = (float)hz + (float)lz;
    _Float16 av[16] = {hx, hy, hz, lx, ly, lz, hx, hy, hz, lx, ly, lz,
                       (_Float16)1.0f, (_Float16)1.0f, (_Float16)1.0f, (_Float16)0.0f};
    float4* dst = (float4*)&AqG[(size_t)q * 16];
    dst[0] = *(float4*)&av[0];
    dst[1] = *(float4*)&av[8];
    c0G[q] = 0.5f * (tx * tx + ty * ty + tz * tz);
  } else {
    int i = (blockIdx.x - 256) * 256 + tid;   // 0..8191
    float x = sp[i * 3 + 0], y = sp[i * 3 + 1], z = sp[i * 3 + 2];
    _Float16 hx = (_Float16)x, hy = (_Float16)y, hz = (_Float16)z;
    _Float16 lx = (_Float16)(x - (float)hx);
    _Float16 ly = (_Float16)(y - (float)hy);
    _Float16 lz = (_Float16)(z - (float)hz);
    float tx = (float)hx + (float)lx, ty = (float)hy + (float)ly, tz = (float)hz + (float)lz;
    float w = 0.5f * (tx * tx + ty * ty + tz * tz);
    _Float16 wh = (_Float16)w;
    float r1 = w - (float)wh;
    _Float16 wl = (_Float16)r1;
    _Float16 wll = (_Float16)(r1 - (float)wl);
    _Float16 nhx = -hx, nhy = -hy, nhz = -hz, nlx = -lx, nly = -ly, nlz = -lz;
    _Float16 b0[8] = {nhx, nhy, nhz, nhx, nhy, nhz, nlx, nly};            // k0..7
    _Float16 b1v[8] = {nlz, nlx, nly, nlz, wh, wl, wll, (_Float16)0.0f};  // k8..15
    int tile = i >> 5, pcol = i & 31;
    *(float4*)&BsG[(size_t)((tile * 2 + 0) * 32 + pcol) * 8] = *(float4*)&b0[0];
    *(float4*)&BsG[(size_t)((tile * 2 + 1) * 32 + pcol) * 8] = *(float4*)&b1v[0];
  }
}

// ---------------- K2: MFMA 2-NN scan, segmented ----------------
// grid 1024 = 2 segs x 512 q-blocks; block = 4 waves; wave owns 32 queries,
// scans its segment's 4096 points. LDS: 2 x 16KB chunk dbuf (512 points each).
__global__ __launch_bounds__(256, 4) void scan_knn2(
    const float4* __restrict__ BsG,    // 8192*2 16B units, frag order
    const float4* __restrict__ AqG,    // 65536*2 16B units
    const float* __restrict__ c0G,
    uint32* __restrict__ keys) {       // [2][65536][2]
  __shared__ float4 Bsh[2048];         // 32KB
  int tid = threadIdx.x;
  int lane = tid & 63, wid = tid >> 6;
  int col = lane & 31, half = lane >> 5;
  int seg = blockIdx.x >> 9;           // 0..1
  int qb  = blockIdx.x & 511;
  int qbase = qb * 128 + wid * 32;

  f16x8 afrag = ((const f16x8*)AqG)[(qbase + col) * 2 + half];
  f32x16 c0f;
#pragma unroll
  for (int r = 0; r < 16; r++) {
    int row = (r & 3) + 8 * (r >> 2) + 4 * half;
    c0f[r] = c0G[qbase + row];
  }
  uint32 b1[16], b2[16];
#pragma unroll
  for (int r = 0; r < 16; r++) { b1[r] = 0xFFFFFFFFu; b2[r] = 0xFFFFFFFFu; }

  const char* gseg = (const char*)(BsG + (size_t)seg * 8192);
  char* lbase = (char*)&Bsh[0];
  // prologue: stage chunks 0,1 (4 x 16B per thread per chunk)
#pragma unroll
  for (int i = 0; i < 4; i++)
    gload_lds16(gseg + (size_t)(0 * 1024 + i * 256 + tid) * 16,
                lbase + ((0 * 1024 + i * 256 + tid) * 16));
#pragma unroll
  for (int i = 0; i < 4; i++)
    gload_lds16(gseg + (size_t)(1 * 1024 + i * 256 + tid) * 16,
                lbase + ((1024 + i * 256 + tid) * 16));

  uint32 vmask = 0xFFFFE000u;          // keep in VGPR for v_and_or_b32
  int tseg = seg * 128;                // global tile base of this segment
#pragma unroll 1
  for (int c = 0; c < 8; c++) {
    if (c < 7) asm volatile("s_waitcnt vmcnt(4)" ::: "memory");
    else       asm volatile("s_waitcnt vmcnt(0)" ::: "memory");
    __builtin_amdgcn_s_barrier();
    const f16x8* bbuf = (const f16x8*)&Bsh[(c & 1) * 1024];
    int tbase = tseg + c * 16;
#pragma unroll 4
    for (int t2 = 0; t2 < 16; t2++) {
      f16x8 bfrag = bbuf[t2 * 64 + lane];
      f32x16 d = __builtin_amdgcn_mfma_f32_32x32x16_f16(afrag, bfrag, c0f, 0, 0, 0);
      int stile = tbase + t2;          // wave-uniform -> SGPR
#pragma unroll
      for (int r = 0; r < 16; r++) {
        uint32 key;
        asm("v_and_or_b32 %0, %3, %4, %5\n\t"
            "v_med3_u32 %2, %1, %2, %0\n\t"
            "v_min_u32 %1, %1, %0"
            : "=&v"(key), "+v"(b1[r]), "+v"(b2[r])
            : "v"(d[r]), "v"(vmask), "s"(stile));
      }
    }
    __builtin_amdgcn_s_barrier();
    if (c + 2 < 8) {
      int nc = c + 2;
#pragma unroll
      for (int i = 0; i < 4; i++)
        gload_lds16(gseg + (size_t)(nc * 1024 + i * 256 + tid) * 16,
                    lbase + (((nc & 1) * 1024 + i * 256 + tid) * 16));
    }
  }

  // convert tile-keys to full-index keys: idx = tile*32 + col (preserves order + tie-break)
#pragma unroll
  for (int r = 0; r < 16; r++) {
    uint32 t1 = b1[r], t2v = b2[r];
    b1[r] = (t1 & 0xFFFFE000u) | (((t1 & 0xFFu) << 5) | (uint32)col);
    b2[r] = (t2v & 0xFFFFE000u) | (((t2v & 0xFFu) << 5) | (uint32)col);
  }
  // merge top-2 across the 32 column-lanes (xor 1..16 stays within each half)
#pragma unroll
  for (int r = 0; r < 16; r++) {
#pragma unroll
    for (int m = 1; m <= 16; m <<= 1) {
      uint32 o1 = (uint32)__shfl_xor((int)b1[r], m, 64);
      uint32 o2 = (uint32)__shfl_xor((int)b2[r], m, 64);
      uint32 n1 = umin32(b1[r], o1);
      uint32 n2 = umin32(umax32(b1[r], o1), umin32(b2[r], o2));
      b1[r] = n1; b2[r] = n2;
    }
  }
  if (col == 0) {
#pragma unroll
    for (int r = 0; r < 16; r++) {
      int row = (r & 3) + 8 * (r >> 2) + 4 * half;
      keys[(size_t)seg * 131072 + (size_t)(qbase + row) * 2 + 0] = b1[r];
      keys[(size_t)seg * 131072 + (size_t)(qbase + row) * 2 + 1] = b2[r];
    }
  }
}

// ---------------- K3: merge segs, gather normals, signs, orientation partials ----------------
__global__ __launch_bounds__(256) void knn_finish(
    const uint32* __restrict__ keys,
    const float* __restrict__ sp, const float* __restrict__ sn,
    const float* __restrict__ offp, const float* __restrict__ nearp,
    const float* __restrict__ off_pred, const float* __restrict__ near_pred,
    float* __restrict__ part) {
  int q = blockIdx.x * 256 + threadIdx.x;
  bool isOff = q < M_QRY;
  const float* qp = isOff ? (offp + q * 3) : (nearp + (q - M_QRY) * 3);
  float qx = qp[0], qy = qp[1], qz = qp[2];
  uint32 m1 = 0xFFFFFFFFu, m2 = 0xFFFFFFFFu;
#pragma unroll
  for (int s = 0; s < 2; s++) {
    uint32 k1 = keys[(size_t)s * 131072 + (size_t)q * 2 + 0];
    uint32 k2 = keys[(size_t)s * 131072 + (size_t)q * 2 + 1];
    m2 = umin32(m2, umax32(m1, k1)); m1 = umin32(m1, k1);
    m2 = umin32(m2, umax32(m1, k2)); m1 = umin32(m1, k2);
  }
  int i1 = (int)(m1 & 8191u), i2 = (int)(m2 & 8191u);
  float d1 = (qx - sp[i1 * 3 + 0]) * sn[i1 * 3 + 0] +
             (qy - sp[i1 * 3 + 1]) * sn[i1 * 3 + 1] +
             (qz - sp[i1 * 3 + 2]) * sn[i1 * 3 + 2];
  float d2 = (qx - sp[i2 * 3 + 0]) * sn[i2 * 3 + 0] +
             (qy - sp[i2 * 3 + 1]) * sn[i2 * 3 + 1] +
             (qz - sp[i2 * 3 + 2]) * sn[i2 * 3 + 2];
  float m = d1 + d2;
  float sg = (m > 0.f) ? 1.f : ((m < 0.f) ? -1.f : 0.f);
  float pred = isOff ? off_pred[q] : near_pred[q - M_QRY];
  float contrib = fmaxf(0.f, -pred * sg);

  __shared__ float red[256];
  int t = threadIdx.x;
  red[t] = contrib;
  __syncthreads();
  for (int s = 128; s > 0; s >>= 1) {
    if (t < s) red[t] += red[t + s];
    __syncthreads();
  }
  if (t == 0) part[blockIdx.x] = red[0];
}

// ---------------- K4: layer-1 (3->256) + softplus, store k-major ----------------
__global__ __launch_bounds__(256) void mlp_l1(
    const float* __restrict__ p, const float* __restrict__ W1,
    const float* __restrict__ b1, float* __restrict__ h1T) {
  int j = blockIdx.x & 255;
  int row = (blockIdx.x >> 8) * 256 + threadIdx.x;
  float w0 = W1[j], w1 = W1[256 + j], w2 = W1[512 + j], bb = b1[j];
  float z = fmaf(p[row * 3 + 0], w0,
            fmaf(p[row * 3 + 1], w1,
            fmaf(p[row * 3 + 2], w2, bb)));
  float h = fmaxf(z, 0.f) + log1pf(expf(-fabsf(z)));
  h1T[j * N_SURF + row] = h;
}

// ---------------- K5: GEMM1 ----------------
#define BM 64
#define BN 64
#define BK 32
__global__ __launch_bounds__(256) void gemm1(
    const float* __restrict__ AT,   // h1T [256][8192]
    const float* __restrict__ W2,   // [256][256]
    const float* __restrict__ b2,
    const float* __restrict__ W3,   // [256]
    float* __restrict__ h2R,        // [8192][256]
    float* __restrict__ dz2T) {     // [256][8192]
  __shared__ float As[BK][BM];
  __shared__ float Bs[BK][BN];
  int row0 = blockIdx.x * BM;
  int col0 = blockIdx.y * BN;
  int tid = threadIdx.x;
  float acc[4][4] = {};
  for (int k0 = 0; k0 < HID; k0 += BK) {
    for (int c = tid; c < BK * BM / 4; c += 256) {
      int k = c >> 4, f = c & 15;
      *(float4*)&As[k][f * 4] = *(const float4*)&AT[(size_t)(k0 + k) * N_SURF + row0 + f * 4];
    }
    for (int c = tid; c < BK * BN / 4; c += 256) {
      int k = c >> 4, f = c & 15;
      *(float4*)&Bs[k][f * 4] = *(const float4*)&W2[(k0 + k) * HID + col0 + f * 4];
    }
    __syncthreads();
    int ty = tid >> 4, tx = tid & 15;
#pragma unroll
    for (int kk = 0; kk < BK; kk++) {
      float4 av = *(const float4*)&As[kk][ty * 4];
      float4 bv = *(const float4*)&Bs[kk][tx * 4];
      float a_[4] = {av.x, av.y, av.z, av.w};
      float b_[4] = {bv.x, bv.y, bv.z, bv.w};
#pragma unroll
      for (int i = 0; i < 4; i++)
#pragma unroll
        for (int j = 0; j < 4; j++)
          acc[i][j] = fmaf(a_[i], b_[j], acc[i][j]);
    }
    __syncthreads();
  }
  int ty = tid >> 4, tx = tid & 15;
  int r = row0 + ty * 4, c = col0 + tx * 4;
  float h2v[4][4];
#pragma unroll
  for (int i = 0; i < 4; i++) {
    float4 hv;
#pragma unroll
    for (int j = 0; j < 4; j++) {
      float z = acc[i][j] + b2[c + j];
      float h = fmaxf(z, 0.f) + log1pf(expf(-fabsf(z)));
      h2v[i][j] = h;
      (&hv.x)[j] = h;
    }
    *(float4*)&h2R[(size_t)(r + i) * HID + c] = hv;
  }
#pragma unroll
  for (int j = 0; j < 4; j++) {
    float w3 = W3[c + j];
    float4 d;
#pragma unroll
    for (int i = 0; i < 4; i++) (&d.x)[i] = w3 * (1.f - expf(-h2v[i][j]));
    *(float4*)&dz2T[(size_t)(c + j) * N_SURF + r] = d;
  }
}

// ---------------- K6: head ----------------
__global__ __launch_bounds__(256) void head(
    const float* __restrict__ h2R, const float* __restrict__ W3,
    const float* __restrict__ b3, float* __restrict__ sdf_part) {
  int wave = threadIdx.x >> 6, lane = threadIdx.x & 63;
  int row = blockIdx.x * 4 + wave;
  float4 h = *(const float4*)&h2R[(size_t)row * HID + lane * 4];
  float4 w = *(const float4*)&W3[lane * 4];
  float s = h.x * w.x + h.y * w.y + h.z * w.z + h.w * w.w;
  for (int off = 32; off > 0; off >>= 1) s += __shfl_down(s, off);
  __shared__ float red[4];
  if (lane == 0) {
    float pred = s + b3[0];
    red[wave] = pred * pred;
  }
  __syncthreads();
  if (threadIdx.x == 0)
    sdf_part[blockIdx.x] = red[0] + red[1] + red[2] + red[3];
}

// ---------------- K7: GEMM2 ----------------
__global__ __launch_bounds__(256) void gemm2(
    const float* __restrict__ AT,   // dz2T [256][8192]
    const float* __restrict__ W2,   // [256][256]
    const float* __restrict__ h1T,  // [256][8192]
    const float* __restrict__ W1,   // [3][256]
    const float* __restrict__ sn,   // [8192][3]
    float* __restrict__ eg_part) {  // [256][2]
  const int BM2 = 32, BN2 = 256, BK2 = 32;
  __shared__ float As[BK2][BM2];
  __shared__ float Bs[BK2][BN2];
  __shared__ float red[96][33];
  __shared__ float gsum[96];
  __shared__ float ee[32], gg[32];
  int row0 = blockIdx.x * BM2;
  int tid = threadIdx.x;
  float acc[4][8] = {};
  for (int k0 = 0; k0 < HID; k0 += BK2) {
    {
      int k = tid >> 3, f = tid & 7;
      *(float4*)&As[k][f * 4] = *(const float4*)&AT[(size_t)(k0 + k) * N_SURF + row0 + f * 4];
    }
#pragma unroll
    for (int f = 0; f < 8; f++) {
      float4 w = *(const float4*)&W2[tid * HID + k0 + f * 4];
      Bs[f * 4 + 0][tid] = w.x;
      Bs[f * 4 + 1][tid] = w.y;
      Bs[f * 4 + 2][tid] = w.z;
      Bs[f * 4 + 3][tid] = w.w;
    }
    __syncthreads();
    int rg = tid >> 5, cg = tid & 31;
#pragma unroll
    for (int kk = 0; kk < BK2; kk++) {
      float4 av = *(const float4*)&As[kk][rg * 4];
      float4 b0 = *(const float4*)&Bs[kk][cg * 4];
      float4 b1v = *(const float4*)&Bs[kk][128 + cg * 4];
      float a_[4] = {av.x, av.y, av.z, av.w};
      float b_[8] = {b0.x, b0.y, b0.z, b0.w, b1v.x, b1v.y, b1v.z, b1v.w};
#pragma unroll
      for (int i = 0; i < 4; i++)
#pragma unroll
        for (int j = 0; j < 8; j++)
          acc[i][j] = fmaf(a_[i], b_[j], acc[i][j]);
    }
    __syncthreads();
  }
  int rg = tid >> 5, cg = tid & 31;
  float g[4][3] = {};
#pragma unroll
  for (int i = 0; i < 4; i++) {
    int row = row0 + rg * 4 + i;
#pragma unroll
    for (int jj = 0; jj < 8; jj++) {
      int colj = (jj < 4) ? (cg * 4 + jj) : (128 + cg * 4 + (jj - 4));
      float h1 = h1T[(size_t)colj * N_SURF + row];
      float s1 = 1.f - expf(-h1);
      float dz1 = acc[i][jj] * s1;
      g[i][0] = fmaf(dz1, W1[colj], g[i][0]);
      g[i][1] = fmaf(dz1, W1[256 + colj], g[i][1]);
      g[i][2] = fmaf(dz1, W1[512 + colj], g[i][2]);
    }
  }
#pragma unroll
  for (int i = 0; i < 4; i++)
#pragma unroll
    for (int k = 0; k < 3; k++) red[(rg * 4 + i) * 3 + k][cg] = g[i][k];
  __syncthreads();
  if (tid < 96) {
    float s = 0.f;
#pragma unroll
    for (int c2 = 0; c2 < 32; c2++) s += red[tid][c2];
    gsum[tid] = s;
  }
  __syncthreads();
  if (tid < 32) {
    float g0 = gsum[tid * 3 + 0], g1 = gsum[tid * 3 + 1], g2 = gsum[tid * 3 + 2];
    int row = row0 + tid;
    float n0 = sn[row * 3 + 0], n1 = sn[row * 3 + 1], n2 = sn[row * 3 + 2];
    float nrm = sqrtf(g0 * g0 + g1 * g1 + g2 * g2);
    ee[tid] = (nrm - 1.f) * (nrm - 1.f);
    gg[tid] = (g0 - n0) * (g0 - n0) + (g1 - n1) * (g1 - n1) + (g2 - n2) * (g2 - n2);
  }
  __syncthreads();
  if (tid == 0) {
    float a = 0.f, b = 0.f;
    for (int i2 = 0; i2 < 32; i2++) { a += ee[i2]; b += gg[i2]; }
    eg_part[blockIdx.x * 2 + 0] = a;
    eg_part[blockIdx.x * 2 + 1] = b;
  }
}

// ---------------- K8: final reduce ----------------
__global__ __launch_bounds__(256) void finalize(
    const float* __restrict__ sdf_part,
    const float* __restrict__ ori_part,
    const float* __restrict__ eg_part,
    float* __restrict__ out) {
  __shared__ float red[256];
  int t = threadIdx.x;
  float s_sdf = 0.f;
  for (int i = t; i < 2048; i += 256) s_sdf += sdf_part[i];
  float s_ori = (t < 128) ? ori_part[t] : 0.f;
  float s_near = (t < 128) ? ori_part[128 + t] : 0.f;
  float s_eik = eg_part[t * 2 + 0];
  float s_gn = eg_part[t * 2 + 1];

  float S[5];
  float vals[5] = {s_sdf, s_ori, s_near, s_eik, s_gn};
  for (int v = 0; v < 5; v++) {
    red[t] = vals[v];
    __syncthreads();
    for (int s = 128; s > 0; s >>= 1) {
      if (t < s) red[t] += red[t + s];
      __syncthreads();
    }
    S[v] = red[0];
    __syncthreads();
  }
  if (t == 0) {
    float sdf = S[0] / 8192.f;
    float ori = S[1] / 32768.f;
    float nearo = S[2] / 32768.f;
    float eik = S[3] / 8192.f;
    float gn = S[4] / 24576.f;
    out[0] = 7000.f * sdf + 600.f * eik + 500.f * ori + 10.f * nearo + 200.f * gn;
    out[1] = sdf;
    out[2] = eik;
    out[3] = ori;
    out[4] = nearo;
    out[5] = gn;
  }
}

extern "C" void kernel_launch(void* const* d_in, const int* in_sizes, int n_in,
                              void* d_out, int out_size, void* d_ws, size_t ws_size,
                              hipStream_t stream) {
  const float* sp       = (const float*)d_in[0];
  const float* sn       = (const float*)d_in[1];
  const float* offp     = (const float*)d_in[2];
  const float* nearp    = (const float*)d_in[3];
  const float* off_pred = (const float*)d_in[4];
  const float* near_pred= (const float*)d_in[5];
  const float* W1 = (const float*)d_in[6];
  const float* b1 = (const float*)d_in[7];
  const float* W2 = (const float*)d_in[8];
  const float* b2 = (const float*)d_in[9];
  const float* W3 = (const float*)d_in[10];
  const float* b3 = (const float*)d_in[11];

  float* ws = (float*)d_ws;
  float* h1T       = ws;                          // [0, 2097152)
  uint32* keys     = (uint32*)ws;                 // alias (262144 u32), dead before mlp_l1
  float* dz2T      = ws + 2097152;                // [2097152, 4194304)
  _Float16* AqG    = (_Float16*)(ws + 2097152);   // alias, dead before gemm1
  _Float16* BsG    = (_Float16*)(ws + 2621440);   // alias
  float* c0G       = ws + 2686976;                // alias
  float* h2R       = ws + 4194304;                // [4194304, 6291456)
  float* sdf_part  = ws + 6291456;                // 2048
  float* ori_part  = sdf_part + 2048;             // 256
  float* eg_part   = ori_part + 256;              // 512
  float* out = (float*)d_out;

  prep<<<288, 256, 0, stream>>>(sp, offp, nearp, AqG, BsG, c0G);
  scan_knn2<<<1024, 256, 0, stream>>>((const float4*)BsG, (const float4*)AqG, c0G, keys);
  knn_finish<<<256, 256, 0, stream>>>(keys, sp, sn, offp, nearp, off_pred, near_pred, ori_part);
  mlp_l1<<<8192, 256, 0, stream>>>(sp, W1, b1, h1T);
  dim3 g1(128, 4);
  gemm1<<<g1, 256, 0, stream>>>(h1T, W2, b2, W3, h2R, dz2T);
  head<<<2048, 256, 0, stream>>>(h2R, W3, b3, sdf_part);
  gemm2<<<256, 256, 0, stream>>>(dz2T, W2, h1T, W1, sn, eg_part);
  finalize<<<1, 256, 0, stream>>>(sdf_part, ori_part, eg_part, out);
}

// Round 4
// 142.800 us; speedup vs baseline: 1.7662x; 1.0933x over previous
//
#include <hip/hip_runtime.h>
#include <math.h>

typedef unsigned int uint32;

#define N_SURF 8192
#define M_QRY  32768
#define M_TOT  65536
#define HID    256

using f16x8  = __attribute__((ext_vector_type(8)))  _Float16;
using f32x16 = __attribute__((ext_vector_type(16))) float;

static __device__ __forceinline__ uint32 umin32(uint32 a, uint32 b) { return a < b ? a : b; }
static __device__ __forceinline__ uint32 umax32(uint32 a, uint32 b) { return a > b ? a : b; }

__device__ __forceinline__ void gload_lds16(const void* g, void* l) {
  __builtin_amdgcn_global_load_lds(
      (const __attribute__((address_space(1))) unsigned int*)g,
      (__attribute__((address_space(3))) unsigned int*)l, 16, 0, 0);
}

// ---- ws layout (floats) ----
// [0)        h1T   [2097152]   (keys[262144 u32] aliases [0,262144) — dead before mlp_l1)
// [2097152)  dz2T  [2097152]   (AqG f16[M][16] = 524288 fl @2097152; BsG = 65536 fl @2621440;
//                               c0G = 65536 fl @2686976 — all dead before gemm1)
// [4194304)  pred_part [8192][4] = 32768 fl
// [6291456)  ori_part[256]  eg_part[512] @6291712

// ---------------- K1: prep — split coords to f16 hi/lo feature vectors ----------------
__global__ __launch_bounds__(256) void prep(
    const float* __restrict__ sp,
    const float* __restrict__ offp, const float* __restrict__ nearp,
    _Float16* __restrict__ AqG, _Float16* __restrict__ BsG,
    float* __restrict__ c0G) {
  int tid = threadIdx.x;
  if (blockIdx.x < 256) {
    int q = blockIdx.x * 256 + tid;
    const float* p = (q < M_QRY) ? (offp + q * 3) : (nearp + (q - M_QRY) * 3);
    float x = p[0], y = p[1], z = p[2];
    _Float16 hx = (_Float16)x, hy = (_Float16)y, hz = (_Float16)z;
    _Float16 lx = (_Float16)(x - (float)hx);
    _Float16 ly = (_Float16)(y - (float)hy);
    _Float16 lz = (_Float16)(z - (float)hz);
    float tx = (float)hx + (float)lx, ty = (float)hy + (float)ly, tz = (float)hz + (float)lz;
    _Float16 av[16] = {hx, hy, hz, lx, ly, lz, hx, hy, hz, lx, ly, lz,
                       (_Float16)1.0f, (_Float16)1.0f, (_Float16)1.0f, (_Float16)0.0f};
    float4* dst = (float4*)&AqG[(size_t)q * 16];
    dst[0] = *(float4*)&av[0];
    dst[1] = *(float4*)&av[8];
    c0G[q] = 0.5f * (tx * tx + ty * ty + tz * tz);
  } else {
    int i = (blockIdx.x - 256) * 256 + tid;   // 0..8191
    float x = sp[i * 3 + 0], y = sp[i * 3 + 1], z = sp[i * 3 + 2];
    _Float16 hx = (_Float16)x, hy = (_Float16)y, hz = (_Float16)z;
    _Float16 lx = (_Float16)(x - (float)hx);
    _Float16 ly = (_Float16)(y - (float)hy);
    _Float16 lz = (_Float16)(z - (float)hz);
    float tx = (float)hx + (float)lx, ty = (float)hy + (float)ly, tz = (float)hz + (float)lz;
    float w = 0.5f * (tx * tx + ty * ty + tz * tz);
    _Float16 wh = (_Float16)w;
    float r1 = w - (float)wh;
    _Float16 wl = (_Float16)r1;
    _Float16 wll = (_Float16)(r1 - (float)wl);
    _Float16 nhx = -hx, nhy = -hy, nhz = -hz, nlx = -lx, nly = -ly, nlz = -lz;
    _Float16 b0[8] = {nhx, nhy, nhz, nhx, nhy, nhz, nlx, nly};            // k0..7
    _Float16 b1v[8] = {nlz, nlx, nly, nlz, wh, wl, wll, (_Float16)0.0f};  // k8..15
    int tile = i >> 5, pcol = i & 31;
    *(float4*)&BsG[(size_t)((tile * 2 + 0) * 32 + pcol) * 8] = *(float4*)&b0[0];
    *(float4*)&BsG[(size_t)((tile * 2 + 1) * 32 + pcol) * 8] = *(float4*)&b1v[0];
  }
}

// ---------------- K2: MFMA 2-NN scan, segmented, top-1-per-lane tracker ----------------
// grid 1024 = 2 segs x 512 q-blocks; block = 4 waves; wave owns 32 queries,
// scans its segment's 4096 points. LDS: 2 x 16KB chunk dbuf (512 points each).
// Per (lane, r) we track only the min key (candidates of one col-class);
// the cross-lane butterfly recovers exact top-1 and top-2-unless-colliding
// (collision prob ~1/64 overall; loss impact << tolerance).
__global__ __launch_bounds__(256, 4) void scan_knn2(
    const float4* __restrict__ BsG,    // 8192*2 16B units, frag order
    const float4* __restrict__ AqG,    // 65536*2 16B units
    const float* __restrict__ c0G,
    uint32* __restrict__ keys) {       // [2][65536][2]
  __shared__ float4 Bsh[2048];         // 32KB
  int tid = threadIdx.x;
  int lane = tid & 63, wid = tid >> 6;
  int col = lane & 31, half = lane >> 5;
  int seg = blockIdx.x >> 9;           // 0..1
  int qb  = blockIdx.x & 511;
  int qbase = qb * 128 + wid * 32;

  f16x8 afrag = ((const f16x8*)AqG)[(qbase + col) * 2 + half];
  f32x16 c0f;
#pragma unroll
  for (int r = 0; r < 16; r++) {
    int row = (r & 3) + 8 * (r >> 2) + 4 * half;
    c0f[r] = c0G[qbase + row];
  }
  uint32 b1[16];
#pragma unroll
  for (int r = 0; r < 16; r++) b1[r] = 0xFFFFFFFFu;

  const char* gseg = (const char*)(BsG + (size_t)seg * 8192);
  char* lbase = (char*)&Bsh[0];
  // prologue: stage chunks 0,1 (4 x 16B per thread per chunk)
#pragma unroll
  for (int i = 0; i < 4; i++)
    gload_lds16(gseg + (size_t)(0 * 1024 + i * 256 + tid) * 16,
                lbase + ((0 * 1024 + i * 256 + tid) * 16));
#pragma unroll
  for (int i = 0; i < 4; i++)
    gload_lds16(gseg + (size_t)(1 * 1024 + i * 256 + tid) * 16,
                lbase + ((1024 + i * 256 + tid) * 16));

  uint32 vmask = 0xFFFFE000u;          // keep in VGPR for v_and_or_b32
  int tseg = seg * 128;                // global tile base of this segment
#pragma unroll 1
  for (int c = 0; c < 8; c++) {
    if (c < 7) asm volatile("s_waitcnt vmcnt(4)" ::: "memory");
    else       asm volatile("s_waitcnt vmcnt(0)" ::: "memory");
    __builtin_amdgcn_s_barrier();
    const f16x8* bbuf = (const f16x8*)&Bsh[(c & 1) * 1024];
    int tbase = tseg + c * 16;
#pragma unroll 4
    for (int t2 = 0; t2 < 16; t2++) {
      f16x8 bfrag = bbuf[t2 * 64 + lane];
      f32x16 d = __builtin_amdgcn_mfma_f32_32x32x16_f16(afrag, bfrag, c0f, 0, 0, 0);
      int stile = tbase + t2;          // wave-uniform -> SGPR
#pragma unroll
      for (int r = 0; r < 16; r++) {
        uint32 key;
        asm("v_and_or_b32 %0, %2, %3, %4\n\t"
            "v_min_u32 %1, %1, %0"
            : "=&v"(key), "+v"(b1[r])
            : "v"(d[r]), "v"(vmask), "s"(stile));
      }
    }
    __builtin_amdgcn_s_barrier();
    if (c + 2 < 8) {
      int nc = c + 2;
#pragma unroll
      for (int i = 0; i < 4; i++)
        gload_lds16(gseg + (size_t)(nc * 1024 + i * 256 + tid) * 16,
                    lbase + (((nc & 1) * 1024 + i * 256 + tid) * 16));
    }
  }

  // convert tile-keys to full-index keys: idx = tile*32 + col
#pragma unroll
  for (int r = 0; r < 16; r++) {
    uint32 t1 = b1[r];
    b1[r] = (t1 & 0xFFFFE000u) | (((t1 & 0xFFu) << 5) | (uint32)col);
  }
  // merge per-lane minima across the 32 column-lanes into exact top-1 +
  // (almost always exact) top-2; xor 1..16 stays within each half.
  uint32 b2[16];
#pragma unroll
  for (int r = 0; r < 16; r++) b2[r] = 0xFFFFFFFFu;
#pragma unroll
  for (int r = 0; r < 16; r++) {
#pragma unroll
    for (int m = 1; m <= 16; m <<= 1) {
      uint32 o1 = (uint32)__shfl_xor((int)b1[r], m, 64);
      uint32 o2 = (uint32)__shfl_xor((int)b2[r], m, 64);
      uint32 n1 = umin32(b1[r], o1);
      uint32 n2 = umin32(umax32(b1[r], o1), umin32(b2[r], o2));
      b1[r] = n1; b2[r] = n2;
    }
  }
  if (col == 0) {
#pragma unroll
    for (int r = 0; r < 16; r++) {
      int row = (r & 3) + 8 * (r >> 2) + 4 * half;
      keys[(size_t)seg * 131072 + (size_t)(qbase + row) * 2 + 0] = b1[r];
      keys[(size_t)seg * 131072 + (size_t)(qbase + row) * 2 + 1] = b2[r];
    }
  }
}

// ---------------- K3: merge segs, gather normals, signs, orientation partials ----------------
__global__ __launch_bounds__(256) void knn_finish(
    const uint32* __restrict__ keys,
    const float* __restrict__ sp, const float* __restrict__ sn,
    const float* __restrict__ offp, const float* __restrict__ nearp,
    const float* __restrict__ off_pred, const float* __restrict__ near_pred,
    float* __restrict__ part) {
  int q = blockIdx.x * 256 + threadIdx.x;
  bool isOff = q < M_QRY;
  const float* qp = isOff ? (offp + q * 3) : (nearp + (q - M_QRY) * 3);
  float qx = qp[0], qy = qp[1], qz = qp[2];
  uint32 m1 = 0xFFFFFFFFu, m2 = 0xFFFFFFFFu;
#pragma unroll
  for (int s = 0; s < 2; s++) {
    uint32 k1 = keys[(size_t)s * 131072 + (size_t)q * 2 + 0];
    uint32 k2 = keys[(size_t)s * 131072 + (size_t)q * 2 + 1];
    m2 = umin32(m2, umax32(m1, k1)); m1 = umin32(m1, k1);
    m2 = umin32(m2, umax32(m1, k2)); m1 = umin32(m1, k2);
  }
  int i1 = (int)(m1 & 8191u), i2 = (int)(m2 & 8191u);
  float d1 = (qx - sp[i1 * 3 + 0]) * sn[i1 * 3 + 0] +
             (qy - sp[i1 * 3 + 1]) * sn[i1 * 3 + 1] +
             (qz - sp[i1 * 3 + 2]) * sn[i1 * 3 + 2];
  float d2 = (qx - sp[i2 * 3 + 0]) * sn[i2 * 3 + 0] +
             (qy - sp[i2 * 3 + 1]) * sn[i2 * 3 + 1] +
             (qz - sp[i2 * 3 + 2]) * sn[i2 * 3 + 2];
  float m = d1 + d2;
  float sg = (m > 0.f) ? 1.f : ((m < 0.f) ? -1.f : 0.f);
  float pred = isOff ? off_pred[q] : near_pred[q - M_QRY];
  float contrib = fmaxf(0.f, -pred * sg);

  __shared__ float red[256];
  int t = threadIdx.x;
  red[t] = contrib;
  __syncthreads();
  for (int s = 128; s > 0; s >>= 1) {
    if (t < s) red[t] += red[t + s];
    __syncthreads();
  }
  if (t == 0) part[blockIdx.x] = red[0];
}

// ---------------- K4: layer-1 (3->256) + softplus, store k-major ----------------
__global__ __launch_bounds__(256) void mlp_l1(
    const float* __restrict__ p, const float* __restrict__ W1,
    const float* __restrict__ b1, float* __restrict__ h1T) {
  int j = blockIdx.x & 255;
  int row = (blockIdx.x >> 8) * 256 + threadIdx.x;
  float w0 = W1[j], w1 = W1[256 + j], w2 = W1[512 + j], bb = b1[j];
  float z = fmaf(p[row * 3 + 0], w0,
            fmaf(p[row * 3 + 1], w1,
            fmaf(p[row * 3 + 2], w2, bb)));
  float h = fmaxf(z, 0.f) + log1pf(expf(-fabsf(z)));
  h1T[j * N_SURF + row] = h;
}

// ---------------- K5: GEMM1 (fused head: pred partials, no h2R) ----------------
#define BM 64
#define BN 64
#define BK 32
__global__ __launch_bounds__(256) void gemm1(
    const float* __restrict__ AT,   // h1T [256][8192]
    const float* __restrict__ W2,   // [256][256]
    const float* __restrict__ b2,
    const float* __restrict__ W3,   // [256]
    float* __restrict__ pred_part,  // [8192][4]
    float* __restrict__ dz2T) {     // [256][8192]
  __shared__ float As[BK][BM];
  __shared__ float Bs[BK][BN];
  __shared__ float predred[64][17];
  int row0 = blockIdx.x * BM;
  int col0 = blockIdx.y * BN;
  int tid = threadIdx.x;
  float acc[4][4] = {};
  for (int k0 = 0; k0 < HID; k0 += BK) {
    for (int c = tid; c < BK * BM / 4; c += 256) {
      int k = c >> 4, f = c & 15;
      *(float4*)&As[k][f * 4] = *(const float4*)&AT[(size_t)(k0 + k) * N_SURF + row0 + f * 4];
    }
    for (int c = tid; c < BK * BN / 4; c += 256) {
      int k = c >> 4, f = c & 15;
      *(float4*)&Bs[k][f * 4] = *(const float4*)&W2[(k0 + k) * HID + col0 + f * 4];
    }
    __syncthreads();
    int ty = tid >> 4, tx = tid & 15;
#pragma unroll
    for (int kk = 0; kk < BK; kk++) {
      float4 av = *(const float4*)&As[kk][ty * 4];
      float4 bv = *(const float4*)&Bs[kk][tx * 4];
      float a_[4] = {av.x, av.y, av.z, av.w};
      float b_[4] = {bv.x, bv.y, bv.z, bv.w};
#pragma unroll
      for (int i = 0; i < 4; i++)
#pragma unroll
        for (int j = 0; j < 4; j++)
          acc[i][j] = fmaf(a_[i], b_[j], acc[i][j]);
    }
    __syncthreads();
  }
  int ty = tid >> 4, tx = tid & 15;
  int r = row0 + ty * 4, c = col0 + tx * 4;
  float h2v[4][4];
  float psum[4] = {0.f, 0.f, 0.f, 0.f};
#pragma unroll
  for (int i = 0; i < 4; i++) {
#pragma unroll
    for (int j = 0; j < 4; j++) {
      float z = acc[i][j] + b2[c + j];
      float h = fmaxf(z, 0.f) + log1pf(expf(-fabsf(z)));
      h2v[i][j] = h;
      psum[i] += h * W3[c + j];
    }
  }
#pragma unroll
  for (int j = 0; j < 4; j++) {
    float w3 = W3[c + j];
    float4 d;
#pragma unroll
    for (int i = 0; i < 4; i++) (&d.x)[i] = w3 * (1.f - expf(-h2v[i][j]));
    *(float4*)&dz2T[(size_t)(c + j) * N_SURF + r] = d;
  }
#pragma unroll
  for (int i = 0; i < 4; i++) predred[ty * 4 + i][tx] = psum[i];
  __syncthreads();
  if (tid < 64) {
    float s = 0.f;
#pragma unroll
    for (int t16 = 0; t16 < 16; t16++) s += predred[tid][t16];
    pred_part[(size_t)(row0 + tid) * 4 + blockIdx.y] = s;
  }
}

// ---------------- K7: GEMM2 ----------------
__global__ __launch_bounds__(256) void gemm2(
    const float* __restrict__ AT,   // dz2T [256][8192]
    const float* __restrict__ W2,   // [256][256]
    const float* __restrict__ h1T,  // [256][8192]
    const float* __restrict__ W1,   // [3][256]
    const float* __restrict__ sn,   // [8192][3]
    float* __restrict__ eg_part) {  // [256][2]
  const int BM2 = 32, BN2 = 256, BK2 = 32;
  __shared__ float As[BK2][BM2];
  __shared__ float Bs[BK2][BN2];
  __shared__ float red[96][33];
  __shared__ float gsum[96];
  __shared__ float ee[32], gg[32];
  int row0 = blockIdx.x * BM2;
  int tid = threadIdx.x;
  float acc[4][8] = {};
  for (int k0 = 0; k0 < HID; k0 += BK2) {
    {
      int k = tid >> 3, f = tid & 7;
      *(float4*)&As[k][f * 4] = *(const float4*)&AT[(size_t)(k0 + k) * N_SURF + row0 + f * 4];
    }
#pragma unroll
    for (int f = 0; f < 8; f++) {
      float4 w = *(const float4*)&W2[tid * HID + k0 + f * 4];
      Bs[f * 4 + 0][tid] = w.x;
      Bs[f * 4 + 1][tid] = w.y;
      Bs[f * 4 + 2][tid] = w.z;
      Bs[f * 4 + 3][tid] = w.w;
    }
    __syncthreads();
    int rg = tid >> 5, cg = tid & 31;
#pragma unroll
    for (int kk = 0; kk < BK2; kk++) {
      float4 av = *(const float4*)&As[kk][rg * 4];
      float4 b0 = *(const float4*)&Bs[kk][cg * 4];
      float4 b1v = *(const float4*)&Bs[kk][128 + cg * 4];
      float a_[4] = {av.x, av.y, av.z, av.w};
      float b_[8] = {b0.x, b0.y, b0.z, b0.w, b1v.x, b1v.y, b1v.z, b1v.w};
#pragma unroll
      for (int i = 0; i < 4; i++)
#pragma unroll
        for (int j = 0; j < 8; j++)
          acc[i][j] = fmaf(a_[i], b_[j], acc[i][j]);
    }
    __syncthreads();
  }
  int rg = tid >> 5, cg = tid & 31;
  float g[4][3] = {};
#pragma unroll
  for (int i = 0; i < 4; i++) {
    int row = row0 + rg * 4 + i;
#pragma unroll
    for (int jj = 0; jj < 8; jj++) {
      int colj = (jj < 4) ? (cg * 4 + jj) : (128 + cg * 4 + (jj - 4));
      float h1 = h1T[(size_t)colj * N_SURF + row];
      float s1 = 1.f - expf(-h1);
      float dz1 = acc[i][jj] * s1;
      g[i][0] = fmaf(dz1, W1[colj], g[i][0]);
      g[i][1] = fmaf(dz1, W1[256 + colj], g[i][1]);
      g[i][2] = fmaf(dz1, W1[512 + colj], g[i][2]);
    }
  }
#pragma unroll
  for (int i = 0; i < 4; i++)
#pragma unroll
    for (int k = 0; k < 3; k++) red[(rg * 4 + i) * 3 + k][cg] = g[i][k];
  __syncthreads();
  if (tid < 96) {
    float s = 0.f;
#pragma unroll
    for (int c2 = 0; c2 < 32; c2++) s += red[tid][c2];
    gsum[tid] = s;
  }
  __syncthreads();
  if (tid < 32) {
    float g0 = gsum[tid * 3 + 0], g1 = gsum[tid * 3 + 1], g2 = gsum[tid * 3 + 2];
    int row = row0 + tid;
    float n0 = sn[row * 3 + 0], n1 = sn[row * 3 + 1], n2 = sn[row * 3 + 2];
    float nrm = sqrtf(g0 * g0 + g1 * g1 + g2 * g2);
    ee[tid] = (nrm - 1.f) * (nrm - 1.f);
    gg[tid] = (g0 - n0) * (g0 - n0) + (g1 - n1) * (g1 - n1) + (g2 - n2) * (g2 - n2);
  }
  __syncthreads();
  if (tid == 0) {
    float a = 0.f, b = 0.f;
    for (int i2 = 0; i2 < 32; i2++) { a += ee[i2]; b += gg[i2]; }
    eg_part[blockIdx.x * 2 + 0] = a;
    eg_part[blockIdx.x * 2 + 1] = b;
  }
}

// ---------------- K8: final reduce (sdf from pred partials) ----------------
__global__ __launch_bounds__(256) void finalize(
    const float* __restrict__ pred_part,  // [8192][4]
    const float* __restrict__ b3,
    const float* __restrict__ ori_part,   // 256 (128 off, 128 near)
    const float* __restrict__ eg_part,    // 512
    float* __restrict__ out) {
  __shared__ float red[256];
  int t = threadIdx.x;
  float bb = b3[0];
  float s_sdf = 0.f;
  for (int i = t; i < 8192; i += 256) {
    float4 pp = *(const float4*)&pred_part[(size_t)i * 4];
    float p = pp.x + pp.y + pp.z + pp.w + bb;
    s_sdf += p * p;
  }
  float s_ori = (t < 128) ? ori_part[t] : 0.f;
  float s_near = (t < 128) ? ori_part[128 + t] : 0.f;
  float s_eik = eg_part[t * 2 + 0];
  float s_gn = eg_part[t * 2 + 1];

  float S[5];
  float vals[5] = {s_sdf, s_ori, s_near, s_eik, s_gn};
  for (int v = 0; v < 5; v++) {
    red[t] = vals[v];
    __syncthreads();
    for (int s = 128; s > 0; s >>= 1) {
      if (t < s) red[t] += red[t + s];
      __syncthreads();
    }
    S[v] = red[0];
    __syncthreads();
  }
  if (t == 0) {
    float sdf = S[0] / 8192.f;
    float ori = S[1] / 32768.f;
    float nearo = S[2] / 32768.f;
    float eik = S[3] / 8192.f;
    float gn = S[4] / 24576.f;
    out[0] = 7000.f * sdf + 600.f * eik + 500.f * ori + 10.f * nearo + 200.f * gn;
    out[1] = sdf;
    out[2] = eik;
    out[3] = ori;
    out[4] = nearo;
    out[5] = gn;
  }
}

extern "C" void kernel_launch(void* const* d_in, const int* in_sizes, int n_in,
                              void* d_out, int out_size, void* d_ws, size_t ws_size,
                              hipStream_t stream) {
  const float* sp       = (const float*)d_in[0];
  const float* sn       = (const float*)d_in[1];
  const float* offp     = (const float*)d_in[2];
  const float* nearp    = (const float*)d_in[3];
  const float* off_pred = (const float*)d_in[4];
  const float* near_pred= (const float*)d_in[5];
  const float* W1 = (const float*)d_in[6];
  const float* b1 = (const float*)d_in[7];
  const float* W2 = (const float*)d_in[8];
  const float* b2 = (const float*)d_in[9];
  const float* W3 = (const float*)d_in[10];
  const float* b3 = (const float*)d_in[11];

  float* ws = (float*)d_ws;
  float* h1T       = ws;                          // [0, 2097152)
  uint32* keys     = (uint32*)ws;                 // alias (262144 u32), dead before mlp_l1
  float* dz2T      = ws + 2097152;                // [2097152, 4194304)
  _Float16* AqG    = (_Float16*)(ws + 2097152);   // alias, dead before gemm1
  _Float16* BsG    = (_Float16*)(ws + 2621440);   // alias
  float* c0G       = ws + 2686976;                // alias
  float* pred_part = ws + 4194304;                // [8192][4]
  float* ori_part  = ws + 6291456;                // 256
  float* eg_part   = ori_part + 256;              // 512
  float* out = (float*)d_out;

  prep<<<288, 256, 0, stream>>>(sp, offp, nearp, AqG, BsG, c0G);
  scan_knn2<<<1024, 256, 0, stream>>>((const float4*)BsG, (const float4*)AqG, c0G, keys);
  knn_finish<<<256, 256, 0, stream>>>(keys, sp, sn, offp, nearp, off_pred, near_pred, ori_part);
  mlp_l1<<<8192, 256, 0, stream>>>(sp, W1, b1, h1T);
  dim3 g1(128, 4);
  gemm1<<<g1, 256, 0, stream>>>(h1T, W2, b2, W3, pred_part, dz2T);
  gemm2<<<256, 256, 0, stream>>>(dz2T, W2, h1T, W1, sn, eg_part);
  finalize<<<1, 256, 0, stream>>>(pred_part, b3, ori_part, eg_part, out);
}

// Round 6
// 114.224 us; speedup vs baseline: 2.2080x; 1.2502x over previous
//
#include <hip/hip_runtime.h>
#include <math.h>

typedef unsigned int uint32;

#define N_SURF 8192
#define M_QRY  32768
#define M_TOT  65536
#define HID    256

using f16x8  = __attribute__((ext_vector_type(8)))  _Float16;
using f32x16 = __attribute__((ext_vector_type(16))) float;

static __device__ __forceinline__ uint32 umin32(uint32 a, uint32 b) { return a < b ? a : b; }
static __device__ __forceinline__ uint32 umax32(uint32 a, uint32 b) { return a > b ? a : b; }

__device__ __forceinline__ void gload_lds16(const void* g, void* l) {
  __builtin_amdgcn_global_load_lds(
      (const __attribute__((address_space(1))) unsigned int*)g,
      (__attribute__((address_space(3))) unsigned int*)l, 16, 0, 0);
}

#define RMAP(r, half) (((r) & 3) + 8 * ((r) >> 2) + 4 * (half))

// ---- ws layout (float offsets) ----
// phase1 (dead after knn_finish): keys u32[262144] @0 ; AqG f16[1048576] @262144 ;
//   BsG f16[131072] @786432 ; c0G f32[65536] @851968
// phase2: h1f_hi f16[2097152] @0 ; h1f_lo @1048576 ; h1C f16[2097152] @2097152 ;
//   dz2f_hi @3145728 ; dz2f_lo @4194304 ;
//   w2f_hi @5242880 (32768 fl each!) ; w2f_lo @5275648 ; w2tf_hi @5308416 ;
//   w2tf_lo @5341184 ; pred_part [8192][8] @5373952 ; g_part [8][8192][3] @5439488
// persistent: ori_part[256] @5636096 ; eg2[64] @5636352

// ---------------- K1: prep — split coords to f16 hi/lo feature vectors ----------------
__global__ __launch_bounds__(256) void prep(
    const float* __restrict__ sp,
    const float* __restrict__ offp, const float* __restrict__ nearp,
    _Float16* __restrict__ AqG, _Float16* __restrict__ BsG,
    float* __restrict__ c0G) {
  int tid = threadIdx.x;
  if (blockIdx.x < 256) {
    int q = blockIdx.x * 256 + tid;
    const float* p = (q < M_QRY) ? (offp + q * 3) : (nearp + (q - M_QRY) * 3);
    float x = p[0], y = p[1], z = p[2];
    _Float16 hx = (_Float16)x, hy = (_Float16)y, hz = (_Float16)z;
    _Float16 lx = (_Float16)(x - (float)hx);
    _Float16 ly = (_Float16)(y - (float)hy);
    _Float16 lz = (_Float16)(z - (float)hz);
    float tx = (float)hx + (float)lx, ty = (float)hy + (float)ly, tz = (float)hz + (float)lz;
    _Float16 av[16] = {hx, hy, hz, lx, ly, lz, hx, hy, hz, lx, ly, lz,
                       (_Float16)1.0f, (_Float16)1.0f, (_Float16)1.0f, (_Float16)0.0f};
    float4* dst = (float4*)&AqG[(size_t)q * 16];
    dst[0] = *(float4*)&av[0];
    dst[1] = *(float4*)&av[8];
    c0G[q] = 0.5f * (tx * tx + ty * ty + tz * tz);
  } else {
    int i = (blockIdx.x - 256) * 256 + tid;   // 0..8191
    float x = sp[i * 3 + 0], y = sp[i * 3 + 1], z = sp[i * 3 + 2];
    _Float16 hx = (_Float16)x, hy = (_Float16)y, hz = (_Float16)z;
    _Float16 lx = (_Float16)(x - (float)hx);
    _Float16 ly = (_Float16)(y - (float)hy);
    _Float16 lz = (_Float16)(z - (float)hz);
    float tx = (float)hx + (float)lx, ty = (float)hy + (float)ly, tz = (float)hz + (float)lz;
    float w = 0.5f * (tx * tx + ty * ty + tz * tz);
    _Float16 wh = (_Float16)w;
    float r1 = w - (float)wh;
    _Float16 wl = (_Float16)r1;
    _Float16 wll = (_Float16)(r1 - (float)wl);
    _Float16 nhx = -hx, nhy = -hy, nhz = -hz, nlx = -lx, nly = -ly, nlz = -lz;
    _Float16 b0[8] = {nhx, nhy, nhz, nhx, nhy, nhz, nlx, nly};            // k0..7
    _Float16 b1v[8] = {nlz, nlx, nly, nlz, wh, wl, wll, (_Float16)0.0f};  // k8..15
    int tile = i >> 5, pcol = i & 31;
    *(float4*)&BsG[(size_t)((tile * 2 + 0) * 32 + pcol) * 8] = *(float4*)&b0[0];
    *(float4*)&BsG[(size_t)((tile * 2 + 1) * 32 + pcol) * 8] = *(float4*)&b1v[0];
  }
}

// ---------------- K2: MFMA 2-NN scan (paired tiles + VGPR-pinned acc) ----------------
__global__ __launch_bounds__(256, 4) void scan_knn2(
    const float4* __restrict__ BsG,    // 8192*2 16B units, frag order
    const float4* __restrict__ AqG,    // 65536*2 16B units
    const float* __restrict__ c0G,
    uint32* __restrict__ keys) {       // [2][65536][2]
  __shared__ float4 Bsh[2048];         // 32KB
  int tid = threadIdx.x;
  int lane = tid & 63, wid = tid >> 6;
  int col = lane & 31, half = lane >> 5;
  int seg = blockIdx.x >> 9;           // 0..1
  int qb  = blockIdx.x & 511;
  int qbase = qb * 128 + wid * 32;

  f16x8 afrag = ((const f16x8*)AqG)[(qbase + col) * 2 + half];
  f32x16 c0f;
#pragma unroll
  for (int r = 0; r < 16; r++) c0f[r] = c0G[qbase + RMAP(r, half)];
  asm("" : "+v"(c0f));                 // pin C operand in arch VGPRs
  uint32 b1[16];
#pragma unroll
  for (int r = 0; r < 16; r++) b1[r] = 0xFFFFFFFFu;

  const char* gseg = (const char*)(BsG + (size_t)seg * 8192);
  char* lbase = (char*)&Bsh[0];
#pragma unroll
  for (int i = 0; i < 4; i++)
    gload_lds16(gseg + (size_t)(0 * 1024 + i * 256 + tid) * 16,
                lbase + ((0 * 1024 + i * 256 + tid) * 16));
#pragma unroll
  for (int i = 0; i < 4; i++)
    gload_lds16(gseg + (size_t)(1 * 1024 + i * 256 + tid) * 16,
                lbase + ((1024 + i * 256 + tid) * 16));

  uint32 vmask = 0xFFFFE000u;
  int tseg = seg * 128;
#pragma unroll 1
  for (int c = 0; c < 8; c++) {
    if (c < 7) asm volatile("s_waitcnt vmcnt(4)" ::: "memory");
    else       asm volatile("s_waitcnt vmcnt(0)" ::: "memory");
    __builtin_amdgcn_s_barrier();
    const f16x8* bbuf = (const f16x8*)&Bsh[(c & 1) * 1024];
    int tbase = tseg + c * 16;
#pragma unroll 1
    for (int t2 = 0; t2 < 16; t2 += 2) {
      f16x8 bfA = bbuf[t2 * 64 + lane];
      f16x8 bfB = bbuf[(t2 + 1) * 64 + lane];
      f32x16 dA = __builtin_amdgcn_mfma_f32_32x32x16_f16(afrag, bfA, c0f, 0, 0, 0);
      asm("" : "+v"(dA));              // pin D in arch VGPRs (kill accvgpr moves)
      f32x16 dB = __builtin_amdgcn_mfma_f32_32x32x16_f16(afrag, bfB, c0f, 0, 0, 0);
      asm("" : "+v"(dB));
      int sA = tbase + t2, sB = tbase + t2 + 1;
#pragma unroll
      for (int r = 0; r < 16; r++) {
        uint32 kA, kB;
        asm("v_and_or_b32 %0, %3, %5, %6\n\t"
            "v_and_or_b32 %1, %4, %5, %7\n\t"
            "v_min3_u32 %2, %2, %0, %1"
            : "=&v"(kA), "=&v"(kB), "+v"(b1[r])
            : "v"(dA[r]), "v"(dB[r]), "v"(vmask), "s"(sA), "s"(sB));
      }
    }
    __builtin_amdgcn_s_barrier();
    if (c + 2 < 8) {
      int nc = c + 2;
#pragma unroll
      for (int i = 0; i < 4; i++)
        gload_lds16(gseg + (size_t)(nc * 1024 + i * 256 + tid) * 16,
                    lbase + (((nc & 1) * 1024 + i * 256 + tid) * 16));
    }
  }

  // tile-keys -> full-index keys: idx = tile*32 + col
#pragma unroll
  for (int r = 0; r < 16; r++) {
    uint32 t1 = b1[r];
    b1[r] = (t1 & 0xFFFFE000u) | (((t1 & 0xFFu) << 5) | (uint32)col);
  }
  uint32 b2[16];
#pragma unroll
  for (int r = 0; r < 16; r++) b2[r] = 0xFFFFFFFFu;
#pragma unroll
  for (int r = 0; r < 16; r++) {
#pragma unroll
    for (int m = 1; m <= 16; m <<= 1) {
      uint32 o1 = (uint32)__shfl_xor((int)b1[r], m, 64);
      uint32 o2 = (uint32)__shfl_xor((int)b2[r], m, 64);
      uint32 n1 = umin32(b1[r], o1);
      uint32 n2 = umin32(umax32(b1[r], o1), umin32(b2[r], o2));
      b1[r] = n1; b2[r] = n2;
    }
  }
  if (col == 0) {
#pragma unroll
    for (int r = 0; r < 16; r++) {
      int row = RMAP(r, half);
      keys[(size_t)seg * 131072 + (size_t)(qbase + row) * 2 + 0] = b1[r];
      keys[(size_t)seg * 131072 + (size_t)(qbase + row) * 2 + 1] = b2[r];
    }
  }
}

// ---------------- K3: merge segs, signs, orientation partials ----------------
__global__ __launch_bounds__(256) void knn_finish(
    const uint32* __restrict__ keys,
    const float* __restrict__ sp, const float* __restrict__ sn,
    const float* __restrict__ offp, const float* __restrict__ nearp,
    const float* __restrict__ off_pred, const float* __restrict__ near_pred,
    float* __restrict__ part) {
  int q = blockIdx.x * 256 + threadIdx.x;
  bool isOff = q < M_QRY;
  const float* qp = isOff ? (offp + q * 3) : (nearp + (q - M_QRY) * 3);
  float qx = qp[0], qy = qp[1], qz = qp[2];
  uint32 m1 = 0xFFFFFFFFu, m2 = 0xFFFFFFFFu;
#pragma unroll
  for (int s = 0; s < 2; s++) {
    uint32 k1 = keys[(size_t)s * 131072 + (size_t)q * 2 + 0];
    uint32 k2 = keys[(size_t)s * 131072 + (size_t)q * 2 + 1];
    m2 = umin32(m2, umax32(m1, k1)); m1 = umin32(m1, k1);
    m2 = umin32(m2, umax32(m1, k2)); m1 = umin32(m1, k2);
  }
  int i1 = (int)(m1 & 8191u), i2 = (int)(m2 & 8191u);
  float d1 = (qx - sp[i1 * 3 + 0]) * sn[i1 * 3 + 0] +
             (qy - sp[i1 * 3 + 1]) * sn[i1 * 3 + 1] +
             (qz - sp[i1 * 3 + 2]) * sn[i1 * 3 + 2];
  float d2 = (qx - sp[i2 * 3 + 0]) * sn[i2 * 3 + 0] +
             (qy - sp[i2 * 3 + 1]) * sn[i2 * 3 + 1] +
             (qz - sp[i2 * 3 + 2]) * sn[i2 * 3 + 2];
  float m = d1 + d2;
  float sg = (m > 0.f) ? 1.f : ((m < 0.f) ? -1.f : 0.f);
  float pred = isOff ? off_pred[q] : near_pred[q - M_QRY];
  float contrib = fmaxf(0.f, -pred * sg);

  __shared__ float red[256];
  int t = threadIdx.x;
  red[t] = contrib;
  __syncthreads();
  for (int s = 128; s > 0; s >>= 1) {
    if (t < s) red[t] += red[t + s];
    __syncthreads();
  }
  if (t == 0) part[blockIdx.x] = red[0];
}

// ---------------- K4: W2 / W2^T fragment packs (hi/lo f16) ----------------
__global__ __launch_bounds__(256) void prep_w2(
    const float* __restrict__ W2,
    _Float16* __restrict__ w2f_hi, _Float16* __restrict__ w2f_lo,
    _Float16* __restrict__ w2tf_hi, _Float16* __restrict__ w2tf_lo) {
  int u = blockIdx.x * 256 + threadIdx.x;  // 0..16383
  int uu = u & 8191;
  int lane = uu & 63, su = uu >> 6;
  int cb = su >> 4, s = su & 15;
  int nl = lane & 31, hf = lane >> 5;
  float v[8];
  if (u < 8192) {
#pragma unroll
    for (int e = 0; e < 8; e++) v[e] = W2[(s * 16 + hf * 8 + e) * 256 + cb * 32 + nl];
  } else {
#pragma unroll
    for (int e = 0; e < 8; e++) v[e] = W2[(cb * 32 + nl) * 256 + s * 16 + hf * 8 + e];
  }
  _Float16 hi[8], lo[8];
#pragma unroll
  for (int e = 0; e < 8; e++) {
    _Float16 h = (_Float16)v[e];
    hi[e] = h; lo[e] = (_Float16)(v[e] - (float)h);
  }
  _Float16* dh = (u < 8192) ? w2f_hi : w2tf_hi;
  _Float16* dl = (u < 8192) ? w2f_lo : w2tf_lo;
  *(float4*)&dh[(size_t)uu * 8] = *(float4*)hi;
  *(float4*)&dl[(size_t)uu * 8] = *(float4*)lo;
}

// ---------------- K5: layer-1 — h1 fragments (hi/lo) + h1C row-major f16 ----------------
__global__ __launch_bounds__(256) void mlp_l1(
    const float* __restrict__ sp, const float* __restrict__ W1,
    const float* __restrict__ b1,
    _Float16* __restrict__ h1f_hi, _Float16* __restrict__ h1f_lo,
    _Float16* __restrict__ h1C) {
  int rb = blockIdx.x;
  int tid = threadIdx.x;
  int row = rb * 32 + (tid >> 3);
  int oct = tid & 7;
  float px = sp[row * 3 + 0], py = sp[row * 3 + 1], pz = sp[row * 3 + 2];
#pragma unroll
  for (int it = 0; it < 4; ++it) {
    int j0 = it * 64 + oct * 8;
    _Float16 hh[8], hl[8];
#pragma unroll
    for (int e = 0; e < 8; e++) {
      int j = j0 + e;
      float z = fmaf(px, W1[j], fmaf(py, W1[256 + j], fmaf(pz, W1[512 + j], b1[j])));
      float h = fmaxf(z, 0.f) + log1pf(expf(-fabsf(z)));
      _Float16 hi = (_Float16)h;
      hh[e] = hi; hl[e] = (_Float16)(h - (float)hi);
    }
    int s = it * 4 + (oct >> 1), hf = oct & 1;
    size_t uidx = ((size_t)(rb * 16 + s)) * 64 + (row & 31) + 32 * hf;
    *(float4*)&h1f_hi[uidx * 8] = *(float4*)hh;
    *(float4*)&h1f_lo[uidx * 8] = *(float4*)hl;
    *(float4*)&h1C[(size_t)row * 256 + j0] = *(float4*)hh;
  }
}

// ---------------- K6: GEMM1 (MFMA split-f16): z2 -> h2, pred partials, dz2 frags ----------------
__global__ __launch_bounds__(256) void gemm1(
    const _Float16* __restrict__ h1f_hi, const _Float16* __restrict__ h1f_lo,
    const _Float16* __restrict__ w2f_hi, const _Float16* __restrict__ w2f_lo,
    const float* __restrict__ b2, const float* __restrict__ W3,
    float* __restrict__ pred_part,        // [8192][8]
    _Float16* __restrict__ dz2f_hi, _Float16* __restrict__ dz2f_lo) {
  __shared__ _Float16 tlds[4][2][32][40];  // 20KB, per-wave transpose buffers
  int tid = threadIdx.x, lane = tid & 63, wid = tid >> 6;
  int id = blockIdx.x * 4 + wid;
  int rb = id >> 3, cb = id & 7;
  int nl = lane & 31, half = lane >> 5;
  f32x16 acc = {};
#pragma unroll
  for (int s = 0; s < 16; s++) {
    f16x8 ah = *(const f16x8*)&h1f_hi[(((size_t)rb * 16 + s) * 64 + lane) * 8];
    f16x8 al = *(const f16x8*)&h1f_lo[(((size_t)rb * 16 + s) * 64 + lane) * 8];
    f16x8 bh = *(const f16x8*)&w2f_hi[(((size_t)cb * 16 + s) * 64 + lane) * 8];
    f16x8 bl = *(const f16x8*)&w2f_lo[(((size_t)cb * 16 + s) * 64 + lane) * 8];
    acc = __builtin_amdgcn_mfma_f32_32x32x16_f16(ah, bh, acc, 0, 0, 0);
    acc = __builtin_amdgcn_mfma_f32_32x32x16_f16(al, bh, acc, 0, 0, 0);
    acc = __builtin_amdgcn_mfma_f32_32x32x16_f16(ah, bl, acc, 0, 0, 0);
  }
  int n = cb * 32 + nl;
  float b2n = b2[n], w3n = W3[n];
  float psum[16];
  _Float16 dh[16], dl[16];
#pragma unroll
  for (int r = 0; r < 16; r++) {
    float z = acc[r] + b2n;
    float h2 = fmaxf(z, 0.f) + log1pf(expf(-fabsf(z)));
    psum[r] = h2 * w3n;
    float dz2 = w3n * (1.f - expf(-h2));
    _Float16 hd = (_Float16)dz2;
    dh[r] = hd; dl[r] = (_Float16)(dz2 - (float)hd);
  }
  // reduce psum over the 32 lanes of each half
#pragma unroll
  for (int r = 0; r < 16; r++) {
#pragma unroll
    for (int m = 1; m <= 16; m <<= 1) psum[r] += __shfl_xor(psum[r], m, 64);
  }
  if (nl == 0) {
#pragma unroll
    for (int r = 0; r < 16; r++)
      pred_part[(size_t)(rb * 32 + RMAP(r, half)) * 8 + cb] = psum[r];
  }
  // transpose dz2 (32 rows x 32 n) into A-frag layout via per-wave LDS
#pragma unroll
  for (int r = 0; r < 16; r++) {
    int rw = RMAP(r, half);
    tlds[wid][0][rw][nl] = dh[r];
    tlds[wid][1][rw][nl] = dl[r];
  }
  asm volatile("s_waitcnt lgkmcnt(0)" ::: "memory");
  __builtin_amdgcn_sched_barrier(0);
  f16x8 x0h = *(const f16x8*)&tlds[wid][0][nl][half * 8];
  f16x8 x1h = *(const f16x8*)&tlds[wid][0][nl][16 + half * 8];
  f16x8 x0l = *(const f16x8*)&tlds[wid][1][nl][half * 8];
  f16x8 x1l = *(const f16x8*)&tlds[wid][1][nl][16 + half * 8];
  size_t u0 = ((size_t)rb * 16 + 2 * cb) * 64 + lane;
  size_t u1 = ((size_t)rb * 16 + 2 * cb + 1) * 64 + lane;
  *(float4*)&dz2f_hi[u0 * 8] = *(float4*)&x0h;
  *(float4*)&dz2f_hi[u1 * 8] = *(float4*)&x1h;
  *(float4*)&dz2f_lo[u0 * 8] = *(float4*)&x0l;
  *(float4*)&dz2f_lo[u1 * 8] = *(float4*)&x1l;
}

// ---------------- K7: GEMM2 (MFMA split-f16): dh1 -> dz1 -> grad partials ----------------
__global__ __launch_bounds__(256) void gemm2(
    const _Float16* __restrict__ dz2f_hi, const _Float16* __restrict__ dz2f_lo,
    const _Float16* __restrict__ w2tf_hi, const _Float16* __restrict__ w2tf_lo,
    const _Float16* __restrict__ h1C, const float* __restrict__ W1,
    float* __restrict__ g_part) {       // [8][8192][3]
  int tid = threadIdx.x, lane = tid & 63, wid = tid >> 6;
  int id = blockIdx.x * 4 + wid;
  int rb = id >> 3, cb2 = id & 7;
  int nl = lane & 31, half = lane >> 5;
  f32x16 acc = {};
#pragma unroll
  for (int s = 0; s < 16; s++) {
    f16x8 ah = *(const f16x8*)&dz2f_hi[(((size_t)rb * 16 + s) * 64 + lane) * 8];
    f16x8 al = *(const f16x8*)&dz2f_lo[(((size_t)rb * 16 + s) * 64 + lane) * 8];
    f16x8 bh = *(const f16x8*)&w2tf_hi[(((size_t)cb2 * 16 + s) * 64 + lane) * 8];
    f16x8 bl = *(const f16x8*)&w2tf_lo[(((size_t)cb2 * 16 + s) * 64 + lane) * 8];
    acc = __builtin_amdgcn_mfma_f32_32x32x16_f16(ah, bh, acc, 0, 0, 0);
    acc = __builtin_amdgcn_mfma_f32_32x32x16_f16(al, bh, acc, 0, 0, 0);
    acc = __builtin_amdgcn_mfma_f32_32x32x16_f16(ah, bl, acc, 0, 0, 0);
  }
  int j = cb2 * 32 + nl;
  float w10 = W1[j], w11 = W1[256 + j], w12 = W1[512 + j];
  float gx[16], gy[16], gz[16];
#pragma unroll
  for (int r = 0; r < 16; r++) {
    int row = rb * 32 + RMAP(r, half);
    float h1 = (float)h1C[(size_t)row * 256 + j];
    float s1 = 1.f - expf(-h1);
    float dz1 = acc[r] * s1;
    gx[r] = dz1 * w10; gy[r] = dz1 * w11; gz[r] = dz1 * w12;
  }
#pragma unroll
  for (int r = 0; r < 16; r++) {
#pragma unroll
    for (int m = 1; m <= 16; m <<= 1) {
      gx[r] += __shfl_xor(gx[r], m, 64);
      gy[r] += __shfl_xor(gy[r], m, 64);
      gz[r] += __shfl_xor(gz[r], m, 64);
    }
  }
  if (nl == 0) {
#pragma unroll
    for (int r = 0; r < 16; r++) {
      int row = rb * 32 + RMAP(r, half);
      size_t base = ((size_t)cb2 * 8192 + row) * 3;
      g_part[base + 0] = gx[r];
      g_part[base + 1] = gy[r];
      g_part[base + 2] = gz[r];
    }
  }
}

// ---------------- K8: eikonal + grad-normal partials ----------------
__global__ __launch_bounds__(256) void eikgn(
    const float* __restrict__ g_part, const float* __restrict__ sn,
    float* __restrict__ eg2) {          // [32][2]
  int row = blockIdx.x * 256 + threadIdx.x;
  float gx = 0.f, gy = 0.f, gz = 0.f;
#pragma unroll
  for (int cb = 0; cb < 8; cb++) {
    size_t base = ((size_t)cb * 8192 + row) * 3;
    gx += g_part[base + 0]; gy += g_part[base + 1]; gz += g_part[base + 2];
  }
  float n0 = sn[row * 3 + 0], n1 = sn[row * 3 + 1], n2 = sn[row * 3 + 2];
  float nrm = sqrtf(gx * gx + gy * gy + gz * gz);
  float ee = (nrm - 1.f) * (nrm - 1.f);
  float gg = (gx - n0) * (gx - n0) + (gy - n1) * (gy - n1) + (gz - n2) * (gz - n2);
  __shared__ float red[256];
  int t = threadIdx.x;
  red[t] = ee; __syncthreads();
  for (int s = 128; s > 0; s >>= 1) { if (t < s) red[t] += red[t + s]; __syncthreads(); }
  float se = red[0]; __syncthreads();
  red[t] = gg; __syncthreads();
  for (int s = 128; s > 0; s >>= 1) { if (t < s) red[t] += red[t + s]; __syncthreads(); }
  if (t == 0) { eg2[blockIdx.x * 2 + 0] = se; eg2[blockIdx.x * 2 + 1] = red[0]; }
}

// ---------------- K9: final reduce ----------------
__global__ __launch_bounds__(256) void finalize(
    const float* __restrict__ pred_part,  // [8192][8]
    const float* __restrict__ b3,
    const float* __restrict__ ori_part,   // 256
    const float* __restrict__ eg2,        // 64
    float* __restrict__ out) {
  __shared__ float red[256];
  int t = threadIdx.x;
  float bb = b3[0];
  float s_sdf = 0.f;
  for (int i = t; i < 8192; i += 256) {
    float4 a = *(const float4*)&pred_part[(size_t)i * 8];
    float4 b = *(const float4*)&pred_part[(size_t)i * 8 + 4];
    float p = a.x + a.y + a.z + a.w + b.x + b.y + b.z + b.w + bb;
    s_sdf += p * p;
  }
  float s_ori = (t < 128) ? ori_part[t] : 0.f;
  float s_near = (t < 128) ? ori_part[128 + t] : 0.f;
  float s_eik = (t < 32) ? eg2[t * 2 + 0] : 0.f;
  float s_gn = (t < 32) ? eg2[t * 2 + 1] : 0.f;

  float S[5];
  float vals[5] = {s_sdf, s_ori, s_near, s_eik, s_gn};
  for (int v = 0; v < 5; v++) {
    red[t] = vals[v];
    __syncthreads();
    for (int s = 128; s > 0; s >>= 1) {
      if (t < s) red[t] += red[t + s];
      __syncthreads();
    }
    S[v] = red[0];
    __syncthreads();
  }
  if (t == 0) {
    float sdf = S[0] / 8192.f;
    float ori = S[1] / 32768.f;
    float nearo = S[2] / 32768.f;
    float eik = S[3] / 8192.f;
    float gn = S[4] / 24576.f;
    out[0] = 7000.f * sdf + 600.f * eik + 500.f * ori + 10.f * nearo + 200.f * gn;
    out[1] = sdf;
    out[2] = eik;
    out[3] = ori;
    out[4] = nearo;
    out[5] = gn;
  }
}

extern "C" void kernel_launch(void* const* d_in, const int* in_sizes, int n_in,
                              void* d_out, int out_size, void* d_ws, size_t ws_size,
                              hipStream_t stream) {
  const float* sp       = (const float*)d_in[0];
  const float* sn       = (const float*)d_in[1];
  const float* offp     = (const float*)d_in[2];
  const float* nearp    = (const float*)d_in[3];
  const float* off_pred = (const float*)d_in[4];
  const float* near_pred= (const float*)d_in[5];
  const float* W1 = (const float*)d_in[6];
  const float* b1 = (const float*)d_in[7];
  const float* W2 = (const float*)d_in[8];
  const float* b2 = (const float*)d_in[9];
  const float* W3 = (const float*)d_in[10];
  const float* b3 = (const float*)d_in[11];

  float* ws = (float*)d_ws;
  // phase 1 (dead after knn_finish)
  uint32* keys     = (uint32*)ws;                 // 262144 u32
  _Float16* AqG    = (_Float16*)(ws + 262144);    // 1048576 f16
  _Float16* BsG    = (_Float16*)(ws + 786432);    // 131072 f16
  float* c0G       = ws + 851968;                 // 65536
  // phase 2 (aliases phase 1)
  _Float16* h1f_hi = (_Float16*)ws;               // @0      (2097152 f16)
  _Float16* h1f_lo = (_Float16*)(ws + 1048576);   //         (2097152 f16)
  _Float16* h1C    = (_Float16*)(ws + 2097152);   //         (2097152 f16)
  _Float16* dz2f_hi= (_Float16*)(ws + 3145728);   //         (2097152 f16)
  _Float16* dz2f_lo= (_Float16*)(ws + 4194304);   //         (2097152 f16)
  _Float16* w2f_hi = (_Float16*)(ws + 5242880);   //         (65536 f16 = 32768 fl)
  _Float16* w2f_lo = (_Float16*)(ws + 5275648);
  _Float16* w2tf_hi= (_Float16*)(ws + 5308416);
  _Float16* w2tf_lo= (_Float16*)(ws + 5341184);
  float* pred_part = ws + 5373952;                // [8192][8] = 65536 fl
  float* g_part    = ws + 5439488;                // [8][8192][3] = 196608 fl
  // persistent
  float* ori_part  = ws + 5636096;                // 256
  float* eg2       = ws + 5636352;                // 64
  float* out = (float*)d_out;

  prep<<<288, 256, 0, stream>>>(sp, offp, nearp, AqG, BsG, c0G);
  scan_knn2<<<1024, 256, 0, stream>>>((const float4*)BsG, (const float4*)AqG, c0G, keys);
  knn_finish<<<256, 256, 0, stream>>>(keys, sp, sn, offp, nearp, off_pred, near_pred, ori_part);
  prep_w2<<<64, 256, 0, stream>>>(W2, w2f_hi, w2f_lo, w2tf_hi, w2tf_lo);
  mlp_l1<<<256, 256, 0, stream>>>(sp, W1, b1, h1f_hi, h1f_lo, h1C);
  gemm1<<<512, 256, 0, stream>>>(h1f_hi, h1f_lo, w2f_hi, w2f_lo, b2, W3,
                                 pred_part, dz2f_hi, dz2f_lo);
  gemm2<<<512, 256, 0, stream>>>(dz2f_hi, dz2f_lo, w2tf_hi, w2tf_lo, h1C, W1, g_part);
  eikgn<<<32, 256, 0, stream>>>(g_part, sn, eg2);
  finalize<<<1, 256, 0, stream>>>(pred_part, b3, ori_part, eg2, out);
}

// Round 7
// 110.432 us; speedup vs baseline: 2.2838x; 1.0343x over previous
//
#include <hip/hip_runtime.h>
#include <math.h>

typedef unsigned int uint32;

#define N_SURF 8192
#define M_QRY  32768
#define M_TOT  65536
#define HID    256

using f16x8  = __attribute__((ext_vector_type(8)))  _Float16;
using f32x16 = __attribute__((ext_vector_type(16))) float;

static __device__ __forceinline__ uint32 umin32(uint32 a, uint32 b) { return a < b ? a : b; }
static __device__ __forceinline__ uint32 umax32(uint32 a, uint32 b) { return a > b ? a : b; }

#define RMAP(r, half) (((r) & 3) + 8 * ((r) >> 2) + 4 * (half))

// ---- ws layout (float offsets) ----
// phase1 (dead after knn_finish): keys u32[262144] @0 ; AqG f16[1048576] @262144 ;
//   BsG f16[131072] @786432 ; c0G f32[65536] @851968
// phase2 (aliases phase1): h1f_hi f16 @0 ; h1f_lo @1048576 ; h1C @2097152 ;
//   dz2f_hi @3145728 ; dz2f_lo @4194304 ; w2f_hi @5242880 ; w2f_lo @5275648 ;
//   w2tf_hi @5308416 ; w2tf_lo @5341184 ; pred_part @5373952 ; g_part @5439488
// persistent: ori_part @5636096 ; eg2 @5636352
// NOTE: mlp_l1 outputs (h1f/h1C) overlap phase1's AqG/BsG/c0G region?  h1f_hi
// spans [0,1048576) fl — overlaps keys[0,262144) and AqG — but prep_all runs
// BEFORE scan... so mlp_l1 (inside prep_all) must NOT alias scan inputs.
// h1f_hi/lo+h1C span [0, 3145728) fl which contains keys/AqG/BsG/c0G — CONFLICT.
// Fix: move mlp_l1 outputs above phase1: h1 region starts @917504 (after c0G).
// Revised phase2 map (all after c0G end @917504):
//   h1f_hi @917504 ; h1f_lo @1966080 ; h1C @3014656 ; dz2f_hi @4063232 ;
//   dz2f_lo @5111808 ; w2f_hi @6160384 ; w2f_lo @6193152 ; w2tf_hi @6225920 ;
//   w2tf_lo @6258688 ; pred_part @6291456 ; g_part @63570  (see launcher)

// ---------------- K1: prep_all — queries, surface frags, W2 frags, layer-1 ----------------
__global__ __launch_bounds__(256) void prep_all(
    const float* __restrict__ sp,
    const float* __restrict__ offp, const float* __restrict__ nearp,
    const float* __restrict__ W1, const float* __restrict__ b1,
    const float* __restrict__ W2,
    _Float16* __restrict__ AqG, _Float16* __restrict__ BsG,
    float* __restrict__ c0G,
    _Float16* __restrict__ w2f_hi, _Float16* __restrict__ w2f_lo,
    _Float16* __restrict__ w2tf_hi, _Float16* __restrict__ w2tf_lo,
    _Float16* __restrict__ h1f_hi, _Float16* __restrict__ h1f_lo,
    _Float16* __restrict__ h1C) {
  int bid = blockIdx.x, tid = threadIdx.x;
  if (bid < 256) {                    // ---- query features ----
    int q = bid * 256 + tid;
    const float* p = (q < M_QRY) ? (offp + q * 3) : (nearp + (q - M_QRY) * 3);
    float x = p[0], y = p[1], z = p[2];
    _Float16 hx = (_Float16)x, hy = (_Float16)y, hz = (_Float16)z;
    _Float16 lx = (_Float16)(x - (float)hx);
    _Float16 ly = (_Float16)(y - (float)hy);
    _Float16 lz = (_Float16)(z - (float)hz);
    float tx = (float)hx + (float)lx, ty = (float)hy + (float)ly, tz = (float)hz + (float)lz;
    _Float16 av[16] = {hx, hy, hz, lx, ly, lz, hx, hy, hz, lx, ly, lz,
                       (_Float16)1.0f, (_Float16)1.0f, (_Float16)1.0f, (_Float16)0.0f};
    float4* dst = (float4*)&AqG[(size_t)q * 16];
    dst[0] = *(float4*)&av[0];
    dst[1] = *(float4*)&av[8];
    c0G[q] = 0.5f * (tx * tx + ty * ty + tz * tz);
  } else if (bid < 288) {             // ---- surface point features ----
    int i = (bid - 256) * 256 + tid;  // 0..8191
    float x = sp[i * 3 + 0], y = sp[i * 3 + 1], z = sp[i * 3 + 2];
    _Float16 hx = (_Float16)x, hy = (_Float16)y, hz = (_Float16)z;
    _Float16 lx = (_Float16)(x - (float)hx);
    _Float16 ly = (_Float16)(y - (float)hy);
    _Float16 lz = (_Float16)(z - (float)hz);
    float tx = (float)hx + (float)lx, ty = (float)hy + (float)ly, tz = (float)hz + (float)lz;
    float w = 0.5f * (tx * tx + ty * ty + tz * tz);
    _Float16 wh = (_Float16)w;
    float r1 = w - (float)wh;
    _Float16 wl = (_Float16)r1;
    _Float16 wll = (_Float16)(r1 - (float)wl);
    _Float16 nhx = -hx, nhy = -hy, nhz = -hz, nlx = -lx, nly = -ly, nlz = -lz;
    _Float16 b0[8] = {nhx, nhy, nhz, nhx, nhy, nhz, nlx, nly};            // k0..7
    _Float16 b1v[8] = {nlz, nlx, nly, nlz, wh, wl, wll, (_Float16)0.0f};  // k8..15
    int tile = i >> 5, pcol = i & 31;
    *(float4*)&BsG[(size_t)((tile * 2 + 0) * 32 + pcol) * 8] = *(float4*)&b0[0];
    *(float4*)&BsG[(size_t)((tile * 2 + 1) * 32 + pcol) * 8] = *(float4*)&b1v[0];
  } else if (bid < 352) {             // ---- W2 / W2^T fragment packs ----
    int u = (bid - 288) * 256 + tid;  // 0..16383
    int uu = u & 8191;
    int lane = uu & 63, su = uu >> 6;
    int cb = su >> 4, s = su & 15;
    int nl = lane & 31, hf = lane >> 5;
    float v[8];
    if (u < 8192) {
#pragma unroll
      for (int e = 0; e < 8; e++) v[e] = W2[(s * 16 + hf * 8 + e) * 256 + cb * 32 + nl];
    } else {
#pragma unroll
      for (int e = 0; e < 8; e++) v[e] = W2[(cb * 32 + nl) * 256 + s * 16 + hf * 8 + e];
    }
    _Float16 hi[8], lo[8];
#pragma unroll
    for (int e = 0; e < 8; e++) {
      _Float16 h = (_Float16)v[e];
      hi[e] = h; lo[e] = (_Float16)(v[e] - (float)h);
    }
    _Float16* dh = (u < 8192) ? w2f_hi : w2tf_hi;
    _Float16* dl = (u < 8192) ? w2f_lo : w2tf_lo;
    *(float4*)&dh[(size_t)uu * 8] = *(float4*)hi;
    *(float4*)&dl[(size_t)uu * 8] = *(float4*)lo;
  } else {                            // ---- layer-1 h1 frags + h1C ----
    int rb = bid - 352;               // 0..255
    int row = rb * 32 + (tid >> 3);
    int oct = tid & 7;
    float px = sp[row * 3 + 0], py = sp[row * 3 + 1], pz = sp[row * 3 + 2];
#pragma unroll
    for (int it = 0; it < 4; ++it) {
      int j0 = it * 64 + oct * 8;
      _Float16 hh[8], hl[8];
#pragma unroll
      for (int e = 0; e < 8; e++) {
        int j = j0 + e;
        float z = fmaf(px, W1[j], fmaf(py, W1[256 + j], fmaf(pz, W1[512 + j], b1[j])));
        float h = fmaxf(z, 0.f) + log1pf(expf(-fabsf(z)));
        _Float16 hi = (_Float16)h;
        hh[e] = hi; hl[e] = (_Float16)(h - (float)hi);
      }
      int s = it * 4 + (oct >> 1), hf = oct & 1;
      size_t uidx = ((size_t)(rb * 16 + s)) * 64 + (row & 31) + 32 * hf;
      *(float4*)&h1f_hi[uidx * 8] = *(float4*)hh;
      *(float4*)&h1f_lo[uidx * 8] = *(float4*)hl;
      *(float4*)&h1C[(size_t)row * 256 + j0] = *(float4*)hh;
    }
  }
}

// ---------------- K2: MFMA 2-NN scan — direct-from-L2, no LDS, no barriers ----------------
// grid 1024 = 2 segs x 512 q-blocks; wave owns 32 queries, scans 4096 points
// (128 tiles) streaming B-fragments straight to VGPRs, 8-tile double buffer.
__global__ __launch_bounds__(256) void scan_knn3(
    const float4* __restrict__ BsG,
    const float4* __restrict__ AqG,
    const float* __restrict__ c0G,
    uint32* __restrict__ keys) {       // [2][65536][2]
  int tid = threadIdx.x;
  int lane = tid & 63, wid = tid >> 6;
  int col = lane & 31, half = lane >> 5;
  int seg = blockIdx.x >> 9;
  int qb  = blockIdx.x & 511;
  int qbase = qb * 128 + wid * 32;

  f16x8 afrag = ((const f16x8*)AqG)[(qbase + col) * 2 + half];
  f32x16 c0f;
#pragma unroll
  for (int r = 0; r < 16; r++) c0f[r] = c0G[qbase + RMAP(r, half)];
  asm("" : "+v"(c0f));
  uint32 b1[16];
#pragma unroll
  for (int r = 0; r < 16; r++) b1[r] = 0xFFFFFFFFu;

  const f16x8* bs = ((const f16x8*)BsG) + (size_t)seg * 8192 + lane;
  uint32 vmask = 0xFFFFE000u;
  int tseg = seg * 128;

  f16x8 A[8], B[8];
#pragma unroll
  for (int j = 0; j < 8; j++) A[j] = bs[(size_t)j * 64];

#pragma unroll 1
  for (int it = 0; it < 8; it++) {
    int t0 = it * 16;
    // prefetch next 8 tiles while computing A
#pragma unroll
    for (int j = 0; j < 8; j++) B[j] = bs[(size_t)(t0 + 8 + j) * 64];
#pragma unroll
    for (int j = 0; j < 8; j += 2) {
      f32x16 dA = __builtin_amdgcn_mfma_f32_32x32x16_f16(afrag, A[j], c0f, 0, 0, 0);
      asm("" : "+v"(dA));
      f32x16 dB = __builtin_amdgcn_mfma_f32_32x32x16_f16(afrag, A[j + 1], c0f, 0, 0, 0);
      asm("" : "+v"(dB));
      int sA = tseg + t0 + j, sB = tseg + t0 + j + 1;
#pragma unroll
      for (int r = 0; r < 16; r++) {
        uint32 kA, kB;
        asm("v_and_or_b32 %0, %3, %5, %6\n\t"
            "v_and_or_b32 %1, %4, %5, %7\n\t"
            "v_min3_u32 %2, %2, %0, %1"
            : "=&v"(kA), "=&v"(kB), "+v"(b1[r])
            : "v"(dA[r]), "v"(dB[r]), "v"(vmask), "s"(sA), "s"(sB));
      }
    }
    if (it < 7) {
#pragma unroll
      for (int j = 0; j < 8; j++) A[j] = bs[(size_t)(t0 + 16 + j) * 64];
    }
#pragma unroll
    for (int j = 0; j < 8; j += 2) {
      f32x16 dA = __builtin_amdgcn_mfma_f32_32x32x16_f16(afrag, B[j], c0f, 0, 0, 0);
      asm("" : "+v"(dA));
      f32x16 dB = __builtin_amdgcn_mfma_f32_32x32x16_f16(afrag, B[j + 1], c0f, 0, 0, 0);
      asm("" : "+v"(dB));
      int sA = tseg + t0 + 8 + j, sB = tseg + t0 + 8 + j + 1;
#pragma unroll
      for (int r = 0; r < 16; r++) {
        uint32 kA, kB;
        asm("v_and_or_b32 %0, %3, %5, %6\n\t"
            "v_and_or_b32 %1, %4, %5, %7\n\t"
            "v_min3_u32 %2, %2, %0, %1"
            : "=&v"(kA), "=&v"(kB), "+v"(b1[r])
            : "v"(dA[r]), "v"(dB[r]), "v"(vmask), "s"(sA), "s"(sB));
      }
    }
  }

  // tile-keys -> full-index keys: idx = tile*32 + col
#pragma unroll
  for (int r = 0; r < 16; r++) {
    uint32 t1 = b1[r];
    b1[r] = (t1 & 0xFFFFE000u) | (((t1 & 0xFFu) << 5) | (uint32)col);
  }
  uint32 b2[16];
#pragma unroll
  for (int r = 0; r < 16; r++) b2[r] = 0xFFFFFFFFu;
#pragma unroll
  for (int r = 0; r < 16; r++) {
#pragma unroll
    for (int m = 1; m <= 16; m <<= 1) {
      uint32 o1 = (uint32)__shfl_xor((int)b1[r], m, 64);
      uint32 o2 = (uint32)__shfl_xor((int)b2[r], m, 64);
      uint32 n1 = umin32(b1[r], o1);
      uint32 n2 = umin32(umax32(b1[r], o1), umin32(b2[r], o2));
      b1[r] = n1; b2[r] = n2;
    }
  }
  if (col == 0) {
#pragma unroll
    for (int r = 0; r < 16; r++) {
      int row = RMAP(r, half);
      keys[(size_t)seg * 131072 + (size_t)(qbase + row) * 2 + 0] = b1[r];
      keys[(size_t)seg * 131072 + (size_t)(qbase + row) * 2 + 1] = b2[r];
    }
  }
}

// ---------------- K3: merge segs, signs, orientation partials ----------------
__global__ __launch_bounds__(256) void knn_finish(
    const uint32* __restrict__ keys,
    const float* __restrict__ sp, const float* __restrict__ sn,
    const float* __restrict__ offp, const float* __restrict__ nearp,
    const float* __restrict__ off_pred, const float* __restrict__ near_pred,
    float* __restrict__ part) {
  int q = blockIdx.x * 256 + threadIdx.x;
  bool isOff = q < M_QRY;
  const float* qp = isOff ? (offp + q * 3) : (nearp + (q - M_QRY) * 3);
  float qx = qp[0], qy = qp[1], qz = qp[2];
  uint32 m1 = 0xFFFFFFFFu, m2 = 0xFFFFFFFFu;
#pragma unroll
  for (int s = 0; s < 2; s++) {
    uint32 k1 = keys[(size_t)s * 131072 + (size_t)q * 2 + 0];
    uint32 k2 = keys[(size_t)s * 131072 + (size_t)q * 2 + 1];
    m2 = umin32(m2, umax32(m1, k1)); m1 = umin32(m1, k1);
    m2 = umin32(m2, umax32(m1, k2)); m1 = umin32(m1, k2);
  }
  int i1 = (int)(m1 & 8191u), i2 = (int)(m2 & 8191u);
  float d1 = (qx - sp[i1 * 3 + 0]) * sn[i1 * 3 + 0] +
             (qy - sp[i1 * 3 + 1]) * sn[i1 * 3 + 1] +
             (qz - sp[i1 * 3 + 2]) * sn[i1 * 3 + 2];
  float d2 = (qx - sp[i2 * 3 + 0]) * sn[i2 * 3 + 0] +
             (qy - sp[i2 * 3 + 1]) * sn[i2 * 3 + 1] +
             (qz - sp[i2 * 3 + 2]) * sn[i2 * 3 + 2];
  float m = d1 + d2;
  float sg = (m > 0.f) ? 1.f : ((m < 0.f) ? -1.f : 0.f);
  float pred = isOff ? off_pred[q] : near_pred[q - M_QRY];
  float contrib = fmaxf(0.f, -pred * sg);

  __shared__ float red[256];
  int t = threadIdx.x;
  red[t] = contrib;
  __syncthreads();
  for (int s = 128; s > 0; s >>= 1) {
    if (t < s) red[t] += red[t + s];
    __syncthreads();
  }
  if (t == 0) part[blockIdx.x] = red[0];
}

// ---------------- K4: GEMM1 (MFMA split-f16): z2 -> h2, pred partials, dz2 frags ----------------
__global__ __launch_bounds__(256) void gemm1(
    const _Float16* __restrict__ h1f_hi, const _Float16* __restrict__ h1f_lo,
    const _Float16* __restrict__ w2f_hi, const _Float16* __restrict__ w2f_lo,
    const float* __restrict__ b2, const float* __restrict__ W3,
    float* __restrict__ pred_part,        // [8192][8]
    _Float16* __restrict__ dz2f_hi, _Float16* __restrict__ dz2f_lo) {
  __shared__ _Float16 tlds[4][2][32][40];
  int tid = threadIdx.x, lane = tid & 63, wid = tid >> 6;
  int id = blockIdx.x * 4 + wid;
  int rb = id >> 3, cb = id & 7;
  int nl = lane & 31, half = lane >> 5;
  f32x16 acc = {};
#pragma unroll
  for (int s = 0; s < 16; s++) {
    f16x8 ah = *(const f16x8*)&h1f_hi[(((size_t)rb * 16 + s) * 64 + lane) * 8];
    f16x8 al = *(const f16x8*)&h1f_lo[(((size_t)rb * 16 + s) * 64 + lane) * 8];
    f16x8 bh = *(const f16x8*)&w2f_hi[(((size_t)cb * 16 + s) * 64 + lane) * 8];
    f16x8 bl = *(const f16x8*)&w2f_lo[(((size_t)cb * 16 + s) * 64 + lane) * 8];
    acc = __builtin_amdgcn_mfma_f32_32x32x16_f16(ah, bh, acc, 0, 0, 0);
    acc = __builtin_amdgcn_mfma_f32_32x32x16_f16(al, bh, acc, 0, 0, 0);
    acc = __builtin_amdgcn_mfma_f32_32x32x16_f16(ah, bl, acc, 0, 0, 0);
  }
  int n = cb * 32 + nl;
  float b2n = b2[n], w3n = W3[n];
  float psum[16];
  _Float16 dh[16], dl[16];
#pragma unroll
  for (int r = 0; r < 16; r++) {
    float z = acc[r] + b2n;
    float h2 = fmaxf(z, 0.f) + log1pf(expf(-fabsf(z)));
    psum[r] = h2 * w3n;
    float dz2 = w3n * (1.f - expf(-h2));
    _Float16 hd = (_Float16)dz2;
    dh[r] = hd; dl[r] = (_Float16)(dz2 - (float)hd);
  }
#pragma unroll
  for (int r = 0; r < 16; r++) {
#pragma unroll
    for (int m = 1; m <= 16; m <<= 1) psum[r] += __shfl_xor(psum[r], m, 64);
  }
  if (nl == 0) {
#pragma unroll
    for (int r = 0; r < 16; r++)
      pred_part[(size_t)(rb * 32 + RMAP(r, half)) * 8 + cb] = psum[r];
  }
#pragma unroll
  for (int r = 0; r < 16; r++) {
    int rw = RMAP(r, half);
    tlds[wid][0][rw][nl] = dh[r];
    tlds[wid][1][rw][nl] = dl[r];
  }
  asm volatile("s_waitcnt lgkmcnt(0)" ::: "memory");
  __builtin_amdgcn_sched_barrier(0);
  f16x8 x0h = *(const f16x8*)&tlds[wid][0][nl][half * 8];
  f16x8 x1h = *(const f16x8*)&tlds[wid][0][nl][16 + half * 8];
  f16x8 x0l = *(const f16x8*)&tlds[wid][1][nl][half * 8];
  f16x8 x1l = *(const f16x8*)&tlds[wid][1][nl][16 + half * 8];
  size_t u0 = ((size_t)rb * 16 + 2 * cb) * 64 + lane;
  size_t u1 = ((size_t)rb * 16 + 2 * cb + 1) * 64 + lane;
  *(float4*)&dz2f_hi[u0 * 8] = *(float4*)&x0h;
  *(float4*)&dz2f_hi[u1 * 8] = *(float4*)&x1h;
  *(float4*)&dz2f_lo[u0 * 8] = *(float4*)&x0l;
  *(float4*)&dz2f_lo[u1 * 8] = *(float4*)&x1l;
}

// ---------------- K5: GEMM2 (MFMA split-f16): dh1 -> dz1 -> grad partials ----------------
__global__ __launch_bounds__(256) void gemm2(
    const _Float16* __restrict__ dz2f_hi, const _Float16* __restrict__ dz2f_lo,
    const _Float16* __restrict__ w2tf_hi, const _Float16* __restrict__ w2tf_lo,
    const _Float16* __restrict__ h1C, const float* __restrict__ W1,
    float* __restrict__ g_part) {       // [8][8192][3]
  int tid = threadIdx.x, lane = tid & 63, wid = tid >> 6;
  int id = blockIdx.x * 4 + wid;
  int rb = id >> 3, cb2 = id & 7;
  int nl = lane & 31, half = lane >> 5;
  f32x16 acc = {};
#pragma unroll
  for (int s = 0; s < 16; s++) {
    f16x8 ah = *(const f16x8*)&dz2f_hi[(((size_t)rb * 16 + s) * 64 + lane) * 8];
    f16x8 al = *(const f16x8*)&dz2f_lo[(((size_t)rb * 16 + s) * 64 + lane) * 8];
    f16x8 bh = *(const f16x8*)&w2tf_hi[(((size_t)cb2 * 16 + s) * 64 + lane) * 8];
    f16x8 bl = *(const f16x8*)&w2tf_lo[(((size_t)cb2 * 16 + s) * 64 + lane) * 8];
    acc = __builtin_amdgcn_mfma_f32_32x32x16_f16(ah, bh, acc, 0, 0, 0);
    acc = __builtin_amdgcn_mfma_f32_32x32x16_f16(al, bh, acc, 0, 0, 0);
    acc = __builtin_amdgcn_mfma_f32_32x32x16_f16(ah, bl, acc, 0, 0, 0);
  }
  int j = cb2 * 32 + nl;
  float w10 = W1[j], w11 = W1[256 + j], w12 = W1[512 + j];
  float gx[16], gy[16], gz[16];
#pragma unroll
  for (int r = 0; r < 16; r++) {
    int row = rb * 32 + RMAP(r, half);
    float h1 = (float)h1C[(size_t)row * 256 + j];
    float s1 = 1.f - expf(-h1);
    float dz1 = acc[r] * s1;
    gx[r] = dz1 * w10; gy[r] = dz1 * w11; gz[r] = dz1 * w12;
  }
#pragma unroll
  for (int r = 0; r < 16; r++) {
#pragma unroll
    for (int m = 1; m <= 16; m <<= 1) {
      gx[r] += __shfl_xor(gx[r], m, 64);
      gy[r] += __shfl_xor(gy[r], m, 64);
      gz[r] += __shfl_xor(gz[r], m, 64);
    }
  }
  if (nl == 0) {
#pragma unroll
    for (int r = 0; r < 16; r++) {
      int row = rb * 32 + RMAP(r, half);
      size_t base = ((size_t)cb2 * 8192 + row) * 3;
      g_part[base + 0] = gx[r];
      g_part[base + 1] = gy[r];
      g_part[base + 2] = gz[r];
    }
  }
}

// ---------------- K6: eikonal + grad-normal partials ----------------
__global__ __launch_bounds__(256) void eikgn(
    const float* __restrict__ g_part, const float* __restrict__ sn,
    float* __restrict__ eg2) {          // [32][2]
  int row = blockIdx.x * 256 + threadIdx.x;
  float gx = 0.f, gy = 0.f, gz = 0.f;
#pragma unroll
  for (int cb = 0; cb < 8; cb++) {
    size_t base = ((size_t)cb * 8192 + row) * 3;
    gx += g_part[base + 0]; gy += g_part[base + 1]; gz += g_part[base + 2];
  }
  float n0 = sn[row * 3 + 0], n1 = sn[row * 3 + 1], n2 = sn[row * 3 + 2];
  float nrm = sqrtf(gx * gx + gy * gy + gz * gz);
  float ee = (nrm - 1.f) * (nrm - 1.f);
  float gg = (gx - n0) * (gx - n0) + (gy - n1) * (gy - n1) + (gz - n2) * (gz - n2);
  __shared__ float red[256];
  int t = threadIdx.x;
  red[t] = ee; __syncthreads();
  for (int s = 128; s > 0; s >>= 1) { if (t < s) red[t] += red[t + s]; __syncthreads(); }
  float se = red[0]; __syncthreads();
  red[t] = gg; __syncthreads();
  for (int s = 128; s > 0; s >>= 1) { if (t < s) red[t] += red[t + s]; __syncthreads(); }
  if (t == 0) { eg2[blockIdx.x * 2 + 0] = se; eg2[blockIdx.x * 2 + 1] = red[0]; }
}

// ---------------- K7: final reduce ----------------
__global__ __launch_bounds__(256) void finalize(
    const float* __restrict__ pred_part,  // [8192][8]
    const float* __restrict__ b3,
    const float* __restrict__ ori_part,   // 256
    const float* __restrict__ eg2,        // 64
    float* __restrict__ out) {
  __shared__ float red[256];
  int t = threadIdx.x;
  float bb = b3[0];
  float s_sdf = 0.f;
  for (int i = t; i < 8192; i += 256) {
    float4 a = *(const float4*)&pred_part[(size_t)i * 8];
    float4 b = *(const float4*)&pred_part[(size_t)i * 8 + 4];
    float p = a.x + a.y + a.z + a.w + b.x + b.y + b.z + b.w + bb;
    s_sdf += p * p;
  }
  float s_ori = (t < 128) ? ori_part[t] : 0.f;
  float s_near = (t < 128) ? ori_part[128 + t] : 0.f;
  float s_eik = (t < 32) ? eg2[t * 2 + 0] : 0.f;
  float s_gn = (t < 32) ? eg2[t * 2 + 1] : 0.f;

  float S[5];
  float vals[5] = {s_sdf, s_ori, s_near, s_eik, s_gn};
  for (int v = 0; v < 5; v++) {
    red[t] = vals[v];
    __syncthreads();
    for (int s = 128; s > 0; s >>= 1) {
      if (t < s) red[t] += red[t + s];
      __syncthreads();
    }
    S[v] = red[0];
    __syncthreads();
  }
  if (t == 0) {
    float sdf = S[0] / 8192.f;
    float ori = S[1] / 32768.f;
    float nearo = S[2] / 32768.f;
    float eik = S[3] / 8192.f;
    float gn = S[4] / 24576.f;
    out[0] = 7000.f * sdf + 600.f * eik + 500.f * ori + 10.f * nearo + 200.f * gn;
    out[1] = sdf;
    out[2] = eik;
    out[3] = ori;
    out[4] = nearo;
    out[5] = gn;
  }
}

extern "C" void kernel_launch(void* const* d_in, const int* in_sizes, int n_in,
                              void* d_out, int out_size, void* d_ws, size_t ws_size,
                              hipStream_t stream) {
  const float* sp       = (const float*)d_in[0];
  const float* sn       = (const float*)d_in[1];
  const float* offp     = (const float*)d_in[2];
  const float* nearp    = (const float*)d_in[3];
  const float* off_pred = (const float*)d_in[4];
  const float* near_pred= (const float*)d_in[5];
  const float* W1 = (const float*)d_in[6];
  const float* b1 = (const float*)d_in[7];
  const float* W2 = (const float*)d_in[8];
  const float* b2 = (const float*)d_in[9];
  const float* W3 = (const float*)d_in[10];
  const float* b3 = (const float*)d_in[11];

  float* ws = (float*)d_ws;
  // phase 1 (scan inputs; dead after knn_finish)
  uint32* keys     = (uint32*)ws;                 // 262144 u32 @0
  _Float16* AqG    = (_Float16*)(ws + 262144);    // 1048576 f16
  _Float16* BsG    = (_Float16*)(ws + 786432);    // 131072 f16
  float* c0G       = ws + 851968;                 // 65536 fl, ends @917504
  // phase 2 — written by prep_all BEFORE scan runs, so placed AFTER phase 1
  _Float16* h1f_hi = (_Float16*)(ws + 917504);    // 2097152 f16 (1048576 fl)
  _Float16* h1f_lo = (_Float16*)(ws + 1966080);
  _Float16* h1C    = (_Float16*)(ws + 3014656);
  _Float16* dz2f_hi= (_Float16*)(ws + 4063232);
  _Float16* dz2f_lo= (_Float16*)(ws + 5111808);
  _Float16* w2f_hi = (_Float16*)(ws + 6160384);   // 65536 f16 (32768 fl)
  _Float16* w2f_lo = (_Float16*)(ws + 6193152);
  _Float16* w2tf_hi= (_Float16*)(ws + 6225920);
  _Float16* w2tf_lo= (_Float16*)(ws + 6258688);
  float* pred_part = ws + 6291456;                // [8192][8] = 65536 fl
  float* g_part    = ws + 6356992;                // [8][8192][3] = 196608 fl
  float* ori_part  = ws + 6553600;                // 256
  float* eg2       = ws + 6553856;                // 64
  float* out = (float*)d_out;

  prep_all<<<608, 256, 0, stream>>>(sp, offp, nearp, W1, b1, W2,
                                    AqG, BsG, c0G,
                                    w2f_hi, w2f_lo, w2tf_hi, w2tf_lo,
                                    h1f_hi, h1f_lo, h1C);
  scan_knn3<<<1024, 256, 0, stream>>>((const float4*)BsG, (const float4*)AqG, c0G, keys);
  knn_finish<<<256, 256, 0, stream>>>(keys, sp, sn, offp, nearp, off_pred, near_pred, ori_part);
  gemm1<<<512, 256, 0, stream>>>(h1f_hi, h1f_lo, w2f_hi, w2f_lo, b2, W3,
                                 pred_part, dz2f_hi, dz2f_lo);
  gemm2<<<512, 256, 0, stream>>>(dz2f_hi, dz2f_lo, w2tf_hi, w2tf_lo, h1C, W1, g_part);
  eikgn<<<32, 256, 0, stream>>>(g_part, sn, eg2);
  finalize<<<1, 256, 0, stream>>>(pred_part, b3, ori_part, eg2, out);
}

// Round 8
// 93.198 us; speedup vs baseline: 2.7061x; 1.1849x over previous
//
#include <hip/hip_runtime.h>
#include <math.h>

typedef unsigned int uint32;

#define N_SURF 8192
#define M_QRY  32768
#define M_TOT  65536
#define HID    256

using f16x8  = __attribute__((ext_vector_type(8)))  _Float16;
using f32x16 = __attribute__((ext_vector_type(16))) float;

static __device__ __forceinline__ uint32 umin32(uint32 a, uint32 b) { return a < b ? a : b; }
static __device__ __forceinline__ uint32 umax32(uint32 a, uint32 b) { return a > b ? a : b; }

__device__ __forceinline__ void gload_lds16(const void* g, void* l) {
  __builtin_amdgcn_global_load_lds(
      (const __attribute__((address_space(1))) unsigned int*)g,
      (__attribute__((address_space(3))) unsigned int*)l, 16, 0, 0);
}

#define RMAP(r, half) (((r) & 3) + 8 * ((r) >> 2) + 4 * (half))

// ---- ws layout (float offsets) ----
// keys u32[524288] @0                      (4 segs x 65536 x 2)
// AqG  f16[1048576] @524288
// BsG  f16[131072]  @1048576
// c0G  f32[65536]   @1114112
// h1f_hi @1179648 ; h1f_lo @2228224 ; h1C @3276800 ; dz2f_hi @4325376 ;
// dz2f_lo @5373952 ; w2f_hi @6422528 ; w2f_lo @6455296 ; w2tf_hi @6488064 ;
// w2tf_lo @6520832 ; sdf_part[256] @6553600 ; ori_part[256] @6553856 ;
// eg2[512] @6554112

// ---------------- K1: prep_all — queries, surface frags, W2 frags, layer-1 ----------------
__global__ __launch_bounds__(256) void prep_all(
    const float* __restrict__ sp,
    const float* __restrict__ offp, const float* __restrict__ nearp,
    const float* __restrict__ W1, const float* __restrict__ b1,
    const float* __restrict__ W2,
    _Float16* __restrict__ AqG, _Float16* __restrict__ BsG,
    float* __restrict__ c0G,
    _Float16* __restrict__ w2f_hi, _Float16* __restrict__ w2f_lo,
    _Float16* __restrict__ w2tf_hi, _Float16* __restrict__ w2tf_lo,
    _Float16* __restrict__ h1f_hi, _Float16* __restrict__ h1f_lo,
    _Float16* __restrict__ h1C) {
  int bid = blockIdx.x, tid = threadIdx.x;
  if (bid < 256) {                    // ---- query features ----
    int q = bid * 256 + tid;
    const float* p = (q < M_QRY) ? (offp + q * 3) : (nearp + (q - M_QRY) * 3);
    float x = p[0], y = p[1], z = p[2];
    _Float16 hx = (_Float16)x, hy = (_Float16)y, hz = (_Float16)z;
    _Float16 lx = (_Float16)(x - (float)hx);
    _Float16 ly = (_Float16)(y - (float)hy);
    _Float16 lz = (_Float16)(z - (float)hz);
    float tx = (float)hx + (float)lx, ty = (float)hy + (float)ly, tz = (float)hz + (float)lz;
    _Float16 av[16] = {hx, hy, hz, lx, ly, lz, hx, hy, hz, lx, ly, lz,
                       (_Float16)1.0f, (_Float16)1.0f, (_Float16)1.0f, (_Float16)0.0f};
    float4* dst = (float4*)&AqG[(size_t)q * 16];
    dst[0] = *(float4*)&av[0];
    dst[1] = *(float4*)&av[8];
    c0G[q] = 0.5f * (tx * tx + ty * ty + tz * tz);
  } else if (bid < 288) {             // ---- surface point features ----
    int i = (bid - 256) * 256 + tid;  // 0..8191
    float x = sp[i * 3 + 0], y = sp[i * 3 + 1], z = sp[i * 3 + 2];
    _Float16 hx = (_Float16)x, hy = (_Float16)y, hz = (_Float16)z;
    _Float16 lx = (_Float16)(x - (float)hx);
    _Float16 ly = (_Float16)(y - (float)hy);
    _Float16 lz = (_Float16)(z - (float)hz);
    float tx = (float)hx + (float)lx, ty = (float)hy + (float)ly, tz = (float)hz + (float)lz;
    float w = 0.5f * (tx * tx + ty * ty + tz * tz);
    _Float16 wh = (_Float16)w;
    float r1 = w - (float)wh;
    _Float16 wl = (_Float16)r1;
    _Float16 wll = (_Float16)(r1 - (float)wl);
    _Float16 nhx = -hx, nhy = -hy, nhz = -hz, nlx = -lx, nly = -ly, nlz = -lz;
    _Float16 b0[8] = {nhx, nhy, nhz, nhx, nhy, nhz, nlx, nly};            // k0..7
    _Float16 b1v[8] = {nlz, nlx, nly, nlz, wh, wl, wll, (_Float16)0.0f};  // k8..15
    int tile = i >> 5, pcol = i & 31;
    *(float4*)&BsG[(size_t)((tile * 2 + 0) * 32 + pcol) * 8] = *(float4*)&b0[0];
    *(float4*)&BsG[(size_t)((tile * 2 + 1) * 32 + pcol) * 8] = *(float4*)&b1v[0];
  } else if (bid < 352) {             // ---- W2 / W2^T fragment packs ----
    int u = (bid - 288) * 256 + tid;  // 0..16383
    int uu = u & 8191;
    int lane = uu & 63, su = uu >> 6;
    int cb = su >> 4, s = su & 15;
    int nl = lane & 31, hf = lane >> 5;
    float v[8];
    if (u < 8192) {
#pragma unroll
      for (int e = 0; e < 8; e++) v[e] = W2[(s * 16 + hf * 8 + e) * 256 + cb * 32 + nl];
    } else {
#pragma unroll
      for (int e = 0; e < 8; e++) v[e] = W2[(cb * 32 + nl) * 256 + s * 16 + hf * 8 + e];
    }
    _Float16 hi[8], lo[8];
#pragma unroll
    for (int e = 0; e < 8; e++) {
      _Float16 h = (_Float16)v[e];
      hi[e] = h; lo[e] = (_Float16)(v[e] - (float)h);
    }
    _Float16* dh = (u < 8192) ? w2f_hi : w2tf_hi;
    _Float16* dl = (u < 8192) ? w2f_lo : w2tf_lo;
    *(float4*)&dh[(size_t)uu * 8] = *(float4*)hi;
    *(float4*)&dl[(size_t)uu * 8] = *(float4*)lo;
  } else {                            // ---- layer-1 h1 frags + h1C ----
    int rb = bid - 352;               // 0..255
    int row = rb * 32 + (tid >> 3);
    int oct = tid & 7;
    float px = sp[row * 3 + 0], py = sp[row * 3 + 1], pz = sp[row * 3 + 2];
#pragma unroll
    for (int it = 0; it < 4; ++it) {
      int j0 = it * 64 + oct * 8;
      _Float16 hh[8], hl[8];
#pragma unroll
      for (int e = 0; e < 8; e++) {
        int j = j0 + e;
        float z = fmaf(px, W1[j], fmaf(py, W1[256 + j], fmaf(pz, W1[512 + j], b1[j])));
        float h = fmaxf(z, 0.f) + log1pf(expf(-fabsf(z)));
        _Float16 hi = (_Float16)h;
        hh[e] = hi; hl[e] = (_Float16)(h - (float)hi);
      }
      int s = it * 4 + (oct >> 1), hf = oct & 1;
      size_t uidx = ((size_t)(rb * 16 + s)) * 64 + (row & 31) + 32 * hf;
      *(float4*)&h1f_hi[uidx * 8] = *(float4*)hh;
      *(float4*)&h1f_lo[uidx * 8] = *(float4*)hl;
      *(float4*)&h1C[(size_t)row * 256 + j0] = *(float4*)hh;
    }
  }
}

// ---------------- K2: MFMA 2-NN scan — 4 segs x 2048 pts, LDS dbuf ----------------
// grid 2048 = 4 segs x 512 q-blocks; block = 4 waves; wave owns 32 queries,
// scans its segment's 2048 points as 4 chunks of 512 pts (16KB LDS each, dbuf).
__global__ __launch_bounds__(256) void scan_knn2(
    const float4* __restrict__ BsG,    // 8192*2 16B units, frag order
    const float4* __restrict__ AqG,
    const float* __restrict__ c0G,
    uint32* __restrict__ keys) {       // [4][65536][2]
  __shared__ float4 Bsh[2048];         // 32KB (2 x 1024 units)
  int tid = threadIdx.x;
  int lane = tid & 63, wid = tid >> 6;
  int col = lane & 31, half = lane >> 5;
  int seg = blockIdx.x >> 9;           // 0..3
  int qb  = blockIdx.x & 511;
  int qbase = qb * 128 + wid * 32;

  f16x8 afrag = ((const f16x8*)AqG)[(qbase + col) * 2 + half];
  f32x16 c0f;
#pragma unroll
  for (int r = 0; r < 16; r++) c0f[r] = c0G[qbase + RMAP(r, half)];
  asm("" : "+v"(c0f));                 // pin C operand
  uint32 b1[16];
#pragma unroll
  for (int r = 0; r < 16; r++) b1[r] = 0xFFFFFFFFu;

  const char* gseg = (const char*)(BsG + (size_t)seg * 4096);  // 2048 pts = 4096 units
  char* lbase = (char*)&Bsh[0];
  // prologue: stage chunks 0,1 (4 x 16B per thread per chunk)
#pragma unroll
  for (int i = 0; i < 4; i++)
    gload_lds16(gseg + (size_t)(0 * 1024 + i * 256 + tid) * 16,
                lbase + ((0 * 1024 + i * 256 + tid) * 16));
#pragma unroll
  for (int i = 0; i < 4; i++)
    gload_lds16(gseg + (size_t)(1 * 1024 + i * 256 + tid) * 16,
                lbase + ((1024 + i * 256 + tid) * 16));

  uint32 vmask = 0xFFFFE000u;
  int tseg = seg * 64;                 // global tile base (64 tiles per segment)
#pragma unroll 1
  for (int c = 0; c < 4; c++) {
    if (c < 3) asm volatile("s_waitcnt vmcnt(4)" ::: "memory");
    else       asm volatile("s_waitcnt vmcnt(0)" ::: "memory");
    __builtin_amdgcn_s_barrier();
    const f16x8* bbuf = (const f16x8*)&Bsh[(c & 1) * 1024];
    int tbase = tseg + c * 16;
#pragma unroll 1
    for (int t2 = 0; t2 < 16; t2 += 2) {
      f16x8 bfA = bbuf[t2 * 64 + lane];
      f16x8 bfB = bbuf[(t2 + 1) * 64 + lane];
      f32x16 dA = __builtin_amdgcn_mfma_f32_32x32x16_f16(afrag, bfA, c0f, 0, 0, 0);
      asm("" : "+v"(dA));
      f32x16 dB = __builtin_amdgcn_mfma_f32_32x32x16_f16(afrag, bfB, c0f, 0, 0, 0);
      asm("" : "+v"(dB));
      int sA = tbase + t2, sB = tbase + t2 + 1;
#pragma unroll
      for (int r = 0; r < 16; r++) {
        uint32 kA, kB;
        asm("v_and_or_b32 %0, %3, %5, %6\n\t"
            "v_and_or_b32 %1, %4, %5, %7\n\t"
            "v_min3_u32 %2, %2, %0, %1"
            : "=&v"(kA), "=&v"(kB), "+v"(b1[r])
            : "v"(dA[r]), "v"(dB[r]), "v"(vmask), "s"(sA), "s"(sB));
      }
    }
    __builtin_amdgcn_s_barrier();
    if (c + 2 < 4) {
      int nc = c + 2;
#pragma unroll
      for (int i = 0; i < 4; i++)
        gload_lds16(gseg + (size_t)(nc * 1024 + i * 256 + tid) * 16,
                    lbase + (((nc & 1) * 1024 + i * 256 + tid) * 16));
    }
  }

  // tile-keys -> full-index keys: idx = tile*32 + col
#pragma unroll
  for (int r = 0; r < 16; r++) {
    uint32 t1 = b1[r];
    b1[r] = (t1 & 0xFFFFE000u) | (((t1 & 0xFFu) << 5) | (uint32)col);
  }
  uint32 b2[16];
#pragma unroll
  for (int r = 0; r < 16; r++) b2[r] = 0xFFFFFFFFu;
#pragma unroll
  for (int r = 0; r < 16; r++) {
#pragma unroll
    for (int m = 1; m <= 16; m <<= 1) {
      uint32 o1 = (uint32)__shfl_xor((int)b1[r], m, 64);
      uint32 o2 = (uint32)__shfl_xor((int)b2[r], m, 64);
      uint32 n1 = umin32(b1[r], o1);
      uint32 n2 = umin32(umax32(b1[r], o1), umin32(b2[r], o2));
      b1[r] = n1; b2[r] = n2;
    }
  }
  if (col == 0) {
#pragma unroll
    for (int r = 0; r < 16; r++) {
      int row = RMAP(r, half);
      keys[(size_t)seg * 131072 + (size_t)(qbase + row) * 2 + 0] = b1[r];
      keys[(size_t)seg * 131072 + (size_t)(qbase + row) * 2 + 1] = b2[r];
    }
  }
}

// ---------------- K3: merge 4 segs, signs, orientation partials ----------------
__global__ __launch_bounds__(256) void knn_finish(
    const uint32* __restrict__ keys,
    const float* __restrict__ sp, const float* __restrict__ sn,
    const float* __restrict__ offp, const float* __restrict__ nearp,
    const float* __restrict__ off_pred, const float* __restrict__ near_pred,
    float* __restrict__ part) {
  int q = blockIdx.x * 256 + threadIdx.x;
  bool isOff = q < M_QRY;
  const float* qp = isOff ? (offp + q * 3) : (nearp + (q - M_QRY) * 3);
  float qx = qp[0], qy = qp[1], qz = qp[2];
  uint32 m1 = 0xFFFFFFFFu, m2 = 0xFFFFFFFFu;
#pragma unroll
  for (int s = 0; s < 4; s++) {
    uint32 k1 = keys[(size_t)s * 131072 + (size_t)q * 2 + 0];
    uint32 k2 = keys[(size_t)s * 131072 + (size_t)q * 2 + 1];
    m2 = umin32(m2, umax32(m1, k1)); m1 = umin32(m1, k1);
    m2 = umin32(m2, umax32(m1, k2)); m1 = umin32(m1, k2);
  }
  int i1 = (int)(m1 & 8191u), i2 = (int)(m2 & 8191u);
  float d1 = (qx - sp[i1 * 3 + 0]) * sn[i1 * 3 + 0] +
             (qy - sp[i1 * 3 + 1]) * sn[i1 * 3 + 1] +
             (qz - sp[i1 * 3 + 2]) * sn[i1 * 3 + 2];
  float d2 = (qx - sp[i2 * 3 + 0]) * sn[i2 * 3 + 0] +
             (qy - sp[i2 * 3 + 1]) * sn[i2 * 3 + 1] +
             (qz - sp[i2 * 3 + 2]) * sn[i2 * 3 + 2];
  float m = d1 + d2;
  float sg = (m > 0.f) ? 1.f : ((m < 0.f) ? -1.f : 0.f);
  float pred = isOff ? off_pred[q] : near_pred[q - M_QRY];
  float contrib = fmaxf(0.f, -pred * sg);

  __shared__ float red[256];
  int t = threadIdx.x;
  red[t] = contrib;
  __syncthreads();
  for (int s = 128; s > 0; s >>= 1) {
    if (t < s) red[t] += red[t + s];
    __syncthreads();
  }
  if (t == 0) part[blockIdx.x] = red[0];
}

// ---------------- K4: GEMM1 fused — block owns 32 rows x all 256 cols ----------------
// 512 thr = 8 waves; wave = one 32-col block. In-block pred completion -> sdf_part.
__global__ __launch_bounds__(512) void gemm1(
    const _Float16* __restrict__ h1f_hi, const _Float16* __restrict__ h1f_lo,
    const _Float16* __restrict__ w2f_hi, const _Float16* __restrict__ w2f_lo,
    const float* __restrict__ b2, const float* __restrict__ W3,
    const float* __restrict__ b3,
    float* __restrict__ sdf_part,         // [256]
    _Float16* __restrict__ dz2f_hi, _Float16* __restrict__ dz2f_lo) {
  __shared__ _Float16 tlds[8][2][32][40]; // 40KB
  __shared__ float predb[8][32];          // [cb][row32]
  int tid = threadIdx.x, lane = tid & 63, wid = tid >> 6;
  int rb = blockIdx.x;                    // 0..255
  int cb = wid;                           // 0..7
  int nl = lane & 31, half = lane >> 5;
  f32x16 acc = {};
#pragma unroll
  for (int s = 0; s < 16; s++) {
    f16x8 ah = *(const f16x8*)&h1f_hi[(((size_t)rb * 16 + s) * 64 + lane) * 8];
    f16x8 al = *(const f16x8*)&h1f_lo[(((size_t)rb * 16 + s) * 64 + lane) * 8];
    f16x8 bh = *(const f16x8*)&w2f_hi[(((size_t)cb * 16 + s) * 64 + lane) * 8];
    f16x8 bl = *(const f16x8*)&w2f_lo[(((size_t)cb * 16 + s) * 64 + lane) * 8];
    acc = __builtin_amdgcn_mfma_f32_32x32x16_f16(ah, bh, acc, 0, 0, 0);
    acc = __builtin_amdgcn_mfma_f32_32x32x16_f16(al, bh, acc, 0, 0, 0);
    acc = __builtin_amdgcn_mfma_f32_32x32x16_f16(ah, bl, acc, 0, 0, 0);
  }
  int n = cb * 32 + nl;
  float b2n = b2[n], w3n = W3[n];
  float psum[16];
  _Float16 dh[16], dl[16];
#pragma unroll
  for (int r = 0; r < 16; r++) {
    float z = acc[r] + b2n;
    float h2 = fmaxf(z, 0.f) + log1pf(expf(-fabsf(z)));
    psum[r] = h2 * w3n;
    float dz2 = w3n * (1.f - expf(-h2));
    _Float16 hd = (_Float16)dz2;
    dh[r] = hd; dl[r] = (_Float16)(dz2 - (float)hd);
  }
#pragma unroll
  for (int r = 0; r < 16; r++) {
#pragma unroll
    for (int m = 1; m <= 16; m <<= 1) psum[r] += __shfl_xor(psum[r], m, 64);
  }
  if (nl == 0) {
#pragma unroll
    for (int r = 0; r < 16; r++) predb[cb][RMAP(r, half)] = psum[r];
  }
  // transpose dz2 (32 rows x 32 n) into A-frag layout via per-wave LDS
#pragma unroll
  for (int r = 0; r < 16; r++) {
    int rw = RMAP(r, half);
    tlds[wid][0][rw][nl] = dh[r];
    tlds[wid][1][rw][nl] = dl[r];
  }
  asm volatile("s_waitcnt lgkmcnt(0)" ::: "memory");
  __builtin_amdgcn_sched_barrier(0);
  f16x8 x0h = *(const f16x8*)&tlds[wid][0][nl][half * 8];
  f16x8 x1h = *(const f16x8*)&tlds[wid][0][nl][16 + half * 8];
  f16x8 x0l = *(const f16x8*)&tlds[wid][1][nl][half * 8];
  f16x8 x1l = *(const f16x8*)&tlds[wid][1][nl][16 + half * 8];
  size_t u0 = ((size_t)rb * 16 + 2 * cb) * 64 + lane;
  size_t u1 = ((size_t)rb * 16 + 2 * cb + 1) * 64 + lane;
  *(float4*)&dz2f_hi[u0 * 8] = *(float4*)&x0h;
  *(float4*)&dz2f_hi[u1 * 8] = *(float4*)&x1h;
  *(float4*)&dz2f_lo[u0 * 8] = *(float4*)&x0l;
  *(float4*)&dz2f_lo[u1 * 8] = *(float4*)&x1l;
  __syncthreads();
  if (tid < 64) {
    int row32 = tid & 31;
    float p = b3[0];
#pragma unroll
    for (int c8 = 0; c8 < 8; c8++) p += predb[c8][row32];
    float sq = (tid < 32) ? p * p : 0.f;
    for (int off = 32; off > 0; off >>= 1) sq += __shfl_down(sq, off);
    if (tid == 0) sdf_part[rb] = sq;
  }
}

// ---------------- K5: GEMM2 fused — block owns 32 rows, inlined eik+gradn ----------------
__global__ __launch_bounds__(512) void gemm2(
    const _Float16* __restrict__ dz2f_hi, const _Float16* __restrict__ dz2f_lo,
    const _Float16* __restrict__ w2tf_hi, const _Float16* __restrict__ w2tf_lo,
    const _Float16* __restrict__ h1C, const float* __restrict__ W1,
    const float* __restrict__ sn,
    float* __restrict__ eg2) {            // [256][2]
  __shared__ float gb[8][32][3];          // 3KB
  int tid = threadIdx.x, lane = tid & 63, wid = tid >> 6;
  int rb = blockIdx.x;                    // 0..255
  int cb2 = wid;                          // 0..7
  int nl = lane & 31, half = lane >> 5;
  f32x16 acc = {};
#pragma unroll
  for (int s = 0; s < 16; s++) {
    f16x8 ah = *(const f16x8*)&dz2f_hi[(((size_t)rb * 16 + s) * 64 + lane) * 8];
    f16x8 al = *(const f16x8*)&dz2f_lo[(((size_t)rb * 16 + s) * 64 + lane) * 8];
    f16x8 bh = *(const f16x8*)&w2tf_hi[(((size_t)cb2 * 16 + s) * 64 + lane) * 8];
    f16x8 bl = *(const f16x8*)&w2tf_lo[(((size_t)cb2 * 16 + s) * 64 + lane) * 8];
    acc = __builtin_amdgcn_mfma_f32_32x32x16_f16(ah, bh, acc, 0, 0, 0);
    acc = __builtin_amdgcn_mfma_f32_32x32x16_f16(al, bh, acc, 0, 0, 0);
    acc = __builtin_amdgcn_mfma_f32_32x32x16_f16(ah, bl, acc, 0, 0, 0);
  }
  int j = cb2 * 32 + nl;
  float w10 = W1[j], w11 = W1[256 + j], w12 = W1[512 + j];
  float gx[16], gy[16], gz[16];
#pragma unroll
  for (int r = 0; r < 16; r++) {
    int row = rb * 32 + RMAP(r, half);
    float h1 = (float)h1C[(size_t)row * 256 + j];
    float s1 = 1.f - expf(-h1);
    float dz1 = acc[r] * s1;
    gx[r] = dz1 * w10; gy[r] = dz1 * w11; gz[r] = dz1 * w12;
  }
#pragma unroll
  for (int r = 0; r < 16; r++) {
#pragma unroll
    for (int m = 1; m <= 16; m <<= 1) {
      gx[r] += __shfl_xor(gx[r], m, 64);
      gy[r] += __shfl_xor(gy[r], m, 64);
      gz[r] += __shfl_xor(gz[r], m, 64);
    }
  }
  if (nl == 0) {
#pragma unroll
    for (int r = 0; r < 16; r++) {
      int row32 = RMAP(r, half);
      gb[cb2][row32][0] = gx[r];
      gb[cb2][row32][1] = gy[r];
      gb[cb2][row32][2] = gz[r];
    }
  }
  __syncthreads();
  if (tid < 64) {
    int row32 = tid & 31;
    float sgx = 0.f, sgy = 0.f, sgz = 0.f;
#pragma unroll
    for (int c8 = 0; c8 < 8; c8++) {
      sgx += gb[c8][row32][0];
      sgy += gb[c8][row32][1];
      sgz += gb[c8][row32][2];
    }
    int row = rb * 32 + row32;
    float n0 = sn[row * 3 + 0], n1 = sn[row * 3 + 1], n2 = sn[row * 3 + 2];
    float nrm = sqrtf(sgx * sgx + sgy * sgy + sgz * sgz);
    float ee = (nrm - 1.f) * (nrm - 1.f);
    float gg = (sgx - n0) * (sgx - n0) + (sgy - n1) * (sgy - n1) + (sgz - n2) * (sgz - n2);
    float vee = (tid < 32) ? ee : 0.f;
    float vgg = (tid < 32) ? gg : 0.f;
    for (int off = 32; off > 0; off >>= 1) {
      vee += __shfl_down(vee, off);
      vgg += __shfl_down(vgg, off);
    }
    if (tid == 0) { eg2[rb * 2 + 0] = vee; eg2[rb * 2 + 1] = vgg; }
  }
}

// ---------------- K6: final reduce (tiny) ----------------
__global__ __launch_bounds__(256) void finalize(
    const float* __restrict__ sdf_part,   // 256
    const float* __restrict__ ori_part,   // 256
    const float* __restrict__ eg2,        // 512
    float* __restrict__ out) {
  __shared__ float red[256];
  int t = threadIdx.x;
  float s_sdf = sdf_part[t];
  float s_ori = (t < 128) ? ori_part[t] : 0.f;
  float s_near = (t < 128) ? ori_part[128 + t] : 0.f;
  float s_eik = eg2[t * 2 + 0];
  float s_gn = eg2[t * 2 + 1];

  float S[5];
  float vals[5] = {s_sdf, s_ori, s_near, s_eik, s_gn};
  for (int v = 0; v < 5; v++) {
    red[t] = vals[v];
    __syncthreads();
    for (int s = 128; s > 0; s >>= 1) {
      if (t < s) red[t] += red[t + s];
      __syncthreads();
    }
    S[v] = red[0];
    __syncthreads();
  }
  if (t == 0) {
    float sdf = S[0] / 8192.f;
    float ori = S[1] / 32768.f;
    float nearo = S[2] / 32768.f;
    float eik = S[3] / 8192.f;
    float gn = S[4] / 24576.f;
    out[0] = 7000.f * sdf + 600.f * eik + 500.f * ori + 10.f * nearo + 200.f * gn;
    out[1] = sdf;
    out[2] = eik;
    out[3] = ori;
    out[4] = nearo;
    out[5] = gn;
  }
}

extern "C" void kernel_launch(void* const* d_in, const int* in_sizes, int n_in,
                              void* d_out, int out_size, void* d_ws, size_t ws_size,
                              hipStream_t stream) {
  const float* sp       = (const float*)d_in[0];
  const float* sn       = (const float*)d_in[1];
  const float* offp     = (const float*)d_in[2];
  const float* nearp    = (const float*)d_in[3];
  const float* off_pred = (const float*)d_in[4];
  const float* near_pred= (const float*)d_in[5];
  const float* W1 = (const float*)d_in[6];
  const float* b1 = (const float*)d_in[7];
  const float* W2 = (const float*)d_in[8];
  const float* b2 = (const float*)d_in[9];
  const float* W3 = (const float*)d_in[10];
  const float* b3 = (const float*)d_in[11];

  float* ws = (float*)d_ws;
  uint32* keys     = (uint32*)ws;                 // 524288 u32 @0
  _Float16* AqG    = (_Float16*)(ws + 524288);    // 1048576 f16
  _Float16* BsG    = (_Float16*)(ws + 1048576);   // 131072 f16
  float* c0G       = ws + 1114112;                // 65536 fl
  _Float16* h1f_hi = (_Float16*)(ws + 1179648);   // 2097152 f16 each
  _Float16* h1f_lo = (_Float16*)(ws + 2228224);
  _Float16* h1C    = (_Float16*)(ws + 3276800);
  _Float16* dz2f_hi= (_Float16*)(ws + 4325376);
  _Float16* dz2f_lo= (_Float16*)(ws + 5373952);
  _Float16* w2f_hi = (_Float16*)(ws + 6422528);   // 65536 f16 each
  _Float16* w2f_lo = (_Float16*)(ws + 6455296);
  _Float16* w2tf_hi= (_Float16*)(ws + 6488064);
  _Float16* w2tf_lo= (_Float16*)(ws + 6520832);
  float* sdf_part  = ws + 6553600;                // 256
  float* ori_part  = ws + 6553856;                // 256
  float* eg2       = ws + 6554112;                // 512
  float* out = (float*)d_out;

  prep_all<<<608, 256, 0, stream>>>(sp, offp, nearp, W1, b1, W2,
                                    AqG, BsG, c0G,
                                    w2f_hi, w2f_lo, w2tf_hi, w2tf_lo,
                                    h1f_hi, h1f_lo, h1C);
  scan_knn2<<<2048, 256, 0, stream>>>((const float4*)BsG, (const float4*)AqG, c0G, keys);
  knn_finish<<<256, 256, 0, stream>>>(keys, sp, sn, offp, nearp, off_pred, near_pred, ori_part);
  gemm1<<<256, 512, 0, stream>>>(h1f_hi, h1f_lo, w2f_hi, w2f_lo, b2, W3, b3,
                                 sdf_part, dz2f_hi, dz2f_lo);
  gemm2<<<256, 512, 0, stream>>>(dz2f_hi, dz2f_lo, w2tf_hi, w2tf_lo, h1C, W1, sn, eg2);
  finalize<<<1, 256, 0, stream>>>(sdf_part, ori_part, eg2, out);
}

// Round 9
// 83.278 us; speedup vs baseline: 3.0285x; 1.1191x over previous
//
#include <hip/hip_runtime.h>
#include <math.h>

typedef unsigned int uint32;

#define N_SURF 8192
#define M_QRY  32768
#define M_TOT  65536
#define HID    256

using f16x8  = __attribute__((ext_vector_type(8)))  _Float16;
using f32x16 = __attribute__((ext_vector_type(16))) float;

static __device__ __forceinline__ uint32 umin32(uint32 a, uint32 b) { return a < b ? a : b; }
static __device__ __forceinline__ uint32 umax32(uint32 a, uint32 b) { return a > b ? a : b; }

__device__ __forceinline__ void gload_lds16(const void* g, void* l) {
  __builtin_amdgcn_global_load_lds(
      (const __attribute__((address_space(1))) unsigned int*)g,
      (__attribute__((address_space(3))) unsigned int*)l, 16, 0, 0);
}

// MFMA with destination forced into ARCH VGPRs (gfx950 unified file) so the
// integer tracker reads plain v-regs with zero v_accvgpr_read traffic.
static __device__ __forceinline__ f32x16 mfma_v(f16x8 a, f16x8 b, f32x16 c) {
  f32x16 d;
  asm("v_mfma_f32_32x32x16_f16 %0, %1, %2, %3"
      : "=&v"(d) : "v"(a), "v"(b), "v"(c));
  return d;
}

#define RMAP(r, half) (((r) & 3) + 8 * ((r) >> 2) + 4 * (half))

// ---- ws layout (float offsets) ----
// keys u32[524288] @0 ; AqG f16[1048576] @524288 ; BsG f16[131072] @1048576 ;
// c0G f32[65536] @1114112 ; h1f_hi @1179648 ; h1f_lo @2228224 ; h1C @3276800 ;
// w2f_hi @6422528 ; w2f_lo @6455296 ; w2tf_hi @6488064 ; w2tf_lo @6520832 ;
// sdf_part[256] @6553600 ; ori_part[256] @6553856 ; eg2[512] @6554112

// ---------------- K1: prep_all — queries, surface frags, W2 frags, layer-1 ----------------
__global__ __launch_bounds__(256) void prep_all(
    const float* __restrict__ sp,
    const float* __restrict__ offp, const float* __restrict__ nearp,
    const float* __restrict__ W1, const float* __restrict__ b1,
    const float* __restrict__ W2,
    _Float16* __restrict__ AqG, _Float16* __restrict__ BsG,
    float* __restrict__ c0G,
    _Float16* __restrict__ w2f_hi, _Float16* __restrict__ w2f_lo,
    _Float16* __restrict__ w2tf_hi, _Float16* __restrict__ w2tf_lo,
    _Float16* __restrict__ h1f_hi, _Float16* __restrict__ h1f_lo,
    _Float16* __restrict__ h1C) {
  int bid = blockIdx.x, tid = threadIdx.x;
  if (bid < 256) {                    // ---- query features ----
    int q = bid * 256 + tid;
    const float* p = (q < M_QRY) ? (offp + q * 3) : (nearp + (q - M_QRY) * 3);
    float x = p[0], y = p[1], z = p[2];
    _Float16 hx = (_Float16)x, hy = (_Float16)y, hz = (_Float16)z;
    _Float16 lx = (_Float16)(x - (float)hx);
    _Float16 ly = (_Float16)(y - (float)hy);
    _Float16 lz = (_Float16)(z - (float)hz);
    float tx = (float)hx + (float)lx, ty = (float)hy + (float)ly, tz = (float)hz + (float)lz;
    _Float16 av[16] = {hx, hy, hz, lx, ly, lz, hx, hy, hz, lx, ly, lz,
                       (_Float16)1.0f, (_Float16)1.0f, (_Float16)1.0f, (_Float16)0.0f};
    float4* dst = (float4*)&AqG[(size_t)q * 16];
    dst[0] = *(float4*)&av[0];
    dst[1] = *(float4*)&av[8];
    c0G[q] = 0.5f * (tx * tx + ty * ty + tz * tz);
  } else if (bid < 288) {             // ---- surface point features ----
    int i = (bid - 256) * 256 + tid;  // 0..8191
    float x = sp[i * 3 + 0], y = sp[i * 3 + 1], z = sp[i * 3 + 2];
    _Float16 hx = (_Float16)x, hy = (_Float16)y, hz = (_Float16)z;
    _Float16 lx = (_Float16)(x - (float)hx);
    _Float16 ly = (_Float16)(y - (float)hy);
    _Float16 lz = (_Float16)(z - (float)hz);
    float tx = (float)hx + (float)lx, ty = (float)hy + (float)ly, tz = (float)hz + (float)lz;
    float w = 0.5f * (tx * tx + ty * ty + tz * tz);
    _Float16 wh = (_Float16)w;
    float r1 = w - (float)wh;
    _Float16 wl = (_Float16)r1;
    _Float16 wll = (_Float16)(r1 - (float)wl);
    _Float16 nhx = -hx, nhy = -hy, nhz = -hz, nlx = -lx, nly = -ly, nlz = -lz;
    _Float16 b0[8] = {nhx, nhy, nhz, nhx, nhy, nhz, nlx, nly};            // k0..7
    _Float16 b1v[8] = {nlz, nlx, nly, nlz, wh, wl, wll, (_Float16)0.0f};  // k8..15
    int tile = i >> 5, pcol = i & 31;
    *(float4*)&BsG[(size_t)((tile * 2 + 0) * 32 + pcol) * 8] = *(float4*)&b0[0];
    *(float4*)&BsG[(size_t)((tile * 2 + 1) * 32 + pcol) * 8] = *(float4*)&b1v[0];
  } else if (bid < 352) {             // ---- W2 / W2^T fragment packs ----
    int u = (bid - 288) * 256 + tid;  // 0..16383
    int uu = u & 8191;
    int lane = uu & 63, su = uu >> 6;
    int cb = su >> 4, s = su & 15;
    int nl = lane & 31, hf = lane >> 5;
    float v[8];
    if (u < 8192) {
#pragma unroll
      for (int e = 0; e < 8; e++) v[e] = W2[(s * 16 + hf * 8 + e) * 256 + cb * 32 + nl];
    } else {
#pragma unroll
      for (int e = 0; e < 8; e++) v[e] = W2[(cb * 32 + nl) * 256 + s * 16 + hf * 8 + e];
    }
    _Float16 hi[8], lo[8];
#pragma unroll
    for (int e = 0; e < 8; e++) {
      _Float16 h = (_Float16)v[e];
      hi[e] = h; lo[e] = (_Float16)(v[e] - (float)h);
    }
    _Float16* dh = (u < 8192) ? w2f_hi : w2tf_hi;
    _Float16* dl = (u < 8192) ? w2f_lo : w2tf_lo;
    *(float4*)&dh[(size_t)uu * 8] = *(float4*)hi;
    *(float4*)&dl[(size_t)uu * 8] = *(float4*)lo;
  } else {                            // ---- layer-1 h1 frags + h1C ----
    int rb = bid - 352;               // 0..255
    int row = rb * 32 + (tid >> 3);
    int oct = tid & 7;
    float px = sp[row * 3 + 0], py = sp[row * 3 + 1], pz = sp[row * 3 + 2];
#pragma unroll
    for (int it = 0; it < 4; ++it) {
      int j0 = it * 64 + oct * 8;
      _Float16 hh[8], hl[8];
#pragma unroll
      for (int e = 0; e < 8; e++) {
        int j = j0 + e;
        float z = fmaf(px, W1[j], fmaf(py, W1[256 + j], fmaf(pz, W1[512 + j], b1[j])));
        float h = fmaxf(z, 0.f) + log1pf(expf(-fabsf(z)));
        _Float16 hi = (_Float16)h;
        hh[e] = hi; hl[e] = (_Float16)(h - (float)hi);
      }
      int s = it * 4 + (oct >> 1), hf = oct & 1;
      size_t uidx = ((size_t)(rb * 16 + s)) * 64 + (row & 31) + 32 * hf;
      *(float4*)&h1f_hi[uidx * 8] = *(float4*)hh;
      *(float4*)&h1f_lo[uidx * 8] = *(float4*)hl;
      *(float4*)&h1C[(size_t)row * 256 + j0] = *(float4*)hh;
    }
  }
}

// ---------------- K2: MFMA 2-NN scan — asm-v MFMA + pipelined tracker ----------------
// grid 2048 = 4 segs x 512 q-blocks; block = 4 waves; wave owns 32 queries,
// scans its segment's 2048 points as 4 chunks of 512 pts (16KB LDS each, dbuf).
#define TRACK2(d0v, d1v, s0v, s1v)                                        \
  _Pragma("unroll")                                                       \
  for (int r = 0; r < 16; r++) {                                          \
    uint32 kA, kB;                                                        \
    asm("v_and_or_b32 %0, %3, %5, %6\n\t"                                 \
        "v_and_or_b32 %1, %4, %5, %7\n\t"                                 \
        "v_min3_u32 %2, %2, %0, %1"                                       \
        : "=&v"(kA), "=&v"(kB), "+v"(b1[r])                               \
        : "v"(d0v[r]), "v"(d1v[r]), "v"(vmask), "s"(s0v), "s"(s1v));      \
  }

__global__ __launch_bounds__(256) void scan_knn2(
    const float4* __restrict__ BsG,    // 8192*2 16B units, frag order
    const float4* __restrict__ AqG,
    const float* __restrict__ c0G,
    uint32* __restrict__ keys) {       // [4][65536][2]
  __shared__ __align__(16) float4 Bsh[2048];  // 32KB (2 x 1024 units)
  int tid = threadIdx.x;
  int lane = tid & 63, wid = tid >> 6;
  int col = lane & 31, half = lane >> 5;
  int seg = blockIdx.x >> 9;           // 0..3
  int qb  = blockIdx.x & 511;
  int qbase = qb * 128 + wid * 32;

  f16x8 afrag = ((const f16x8*)AqG)[(qbase + col) * 2 + half];
  f32x16 c0f;
#pragma unroll
  for (int r = 0; r < 16; r++) c0f[r] = c0G[qbase + RMAP(r, half)];
  uint32 b1[16];
#pragma unroll
  for (int r = 0; r < 16; r++) b1[r] = 0xFFFFFFFFu;

  const char* gseg = (const char*)(BsG + (size_t)seg * 4096);  // 2048 pts
  char* lbase = (char*)&Bsh[0];
#pragma unroll
  for (int i = 0; i < 4; i++)
    gload_lds16(gseg + (size_t)(0 * 1024 + i * 256 + tid) * 16,
                lbase + ((0 * 1024 + i * 256 + tid) * 16));
#pragma unroll
  for (int i = 0; i < 4; i++)
    gload_lds16(gseg + (size_t)(1 * 1024 + i * 256 + tid) * 16,
                lbase + ((1024 + i * 256 + tid) * 16));

  uint32 vmask = 0xFFFFE000u;
  int tseg = seg * 64;                 // global tile base (64 tiles / segment)
#pragma unroll 1
  for (int c = 0; c < 4; c++) {
    if (c < 3) asm volatile("s_waitcnt vmcnt(4)" ::: "memory");
    else       asm volatile("s_waitcnt vmcnt(0)" ::: "memory");
    __builtin_amdgcn_s_barrier();
    const f16x8* bbuf = (const f16x8*)&Bsh[(c & 1) * 1024];
    int tbase = tseg + c * 16;
    // software-pipelined: track pair p-1 after issuing pair p's MFMAs
    f16x8 f0 = bbuf[0 * 64 + lane];
    f16x8 f1 = bbuf[1 * 64 + lane];
    f32x16 dc0 = mfma_v(afrag, f0, c0f);
    f32x16 dc1 = mfma_v(afrag, f1, c0f);
#pragma unroll
    for (int p = 1; p < 8; p++) {
      f16x8 n0 = bbuf[(2 * p) * 64 + lane];
      f16x8 n1 = bbuf[(2 * p + 1) * 64 + lane];
      f32x16 e0 = mfma_v(afrag, n0, c0f);
      f32x16 e1 = mfma_v(afrag, n1, c0f);
      int s0 = tbase + 2 * (p - 1), s1 = s0 + 1;
      TRACK2(dc0, dc1, s0, s1);
      dc0 = e0; dc1 = e1;
    }
    {
      int s0 = tbase + 14, s1 = tbase + 15;
      TRACK2(dc0, dc1, s0, s1);
    }
    __builtin_amdgcn_s_barrier();
    if (c + 2 < 4) {
      int nc = c + 2;
#pragma unroll
      for (int i = 0; i < 4; i++)
        gload_lds16(gseg + (size_t)(nc * 1024 + i * 256 + tid) * 16,
                    lbase + (((nc & 1) * 1024 + i * 256 + tid) * 16));
    }
  }

  // tile-keys -> full-index keys: idx = tile*32 + col
#pragma unroll
  for (int r = 0; r < 16; r++) {
    uint32 t1 = b1[r];
    b1[r] = (t1 & 0xFFFFE000u) | (((t1 & 0xFFu) << 5) | (uint32)col);
  }
  uint32 b2[16];
#pragma unroll
  for (int r = 0; r < 16; r++) b2[r] = 0xFFFFFFFFu;
#pragma unroll
  for (int r = 0; r < 16; r++) {
#pragma unroll
    for (int m = 1; m <= 16; m <<= 1) {
      uint32 o1 = (uint32)__shfl_xor((int)b1[r], m, 64);
      uint32 o2 = (uint32)__shfl_xor((int)b2[r], m, 64);
      uint32 n1 = umin32(b1[r], o1);
      uint32 n2 = umin32(umax32(b1[r], o1), umin32(b2[r], o2));
      b1[r] = n1; b2[r] = n2;
    }
  }
  if (col == 0) {
#pragma unroll
    for (int r = 0; r < 16; r++) {
      int row = RMAP(r, half);
      keys[(size_t)seg * 131072 + (size_t)(qbase + row) * 2 + 0] = b1[r];
      keys[(size_t)seg * 131072 + (size_t)(qbase + row) * 2 + 1] = b2[r];
    }
  }
}

// ---------------- K3: merge 4 segs, signs, orientation partials ----------------
__global__ __launch_bounds__(256) void knn_finish(
    const uint32* __restrict__ keys,
    const float* __restrict__ sp, const float* __restrict__ sn,
    const float* __restrict__ offp, const float* __restrict__ nearp,
    const float* __restrict__ off_pred, const float* __restrict__ near_pred,
    float* __restrict__ part) {
  int q = blockIdx.x * 256 + threadIdx.x;
  bool isOff = q < M_QRY;
  const float* qp = isOff ? (offp + q * 3) : (nearp + (q - M_QRY) * 3);
  float qx = qp[0], qy = qp[1], qz = qp[2];
  uint32 m1 = 0xFFFFFFFFu, m2 = 0xFFFFFFFFu;
#pragma unroll
  for (int s = 0; s < 4; s++) {
    uint32 k1 = keys[(size_t)s * 131072 + (size_t)q * 2 + 0];
    uint32 k2 = keys[(size_t)s * 131072 + (size_t)q * 2 + 1];
    m2 = umin32(m2, umax32(m1, k1)); m1 = umin32(m1, k1);
    m2 = umin32(m2, umax32(m1, k2)); m1 = umin32(m1, k2);
  }
  int i1 = (int)(m1 & 8191u), i2 = (int)(m2 & 8191u);
  float d1 = (qx - sp[i1 * 3 + 0]) * sn[i1 * 3 + 0] +
             (qy - sp[i1 * 3 + 1]) * sn[i1 * 3 + 1] +
             (qz - sp[i1 * 3 + 2]) * sn[i1 * 3 + 2];
  float d2 = (qx - sp[i2 * 3 + 0]) * sn[i2 * 3 + 0] +
             (qy - sp[i2 * 3 + 1]) * sn[i2 * 3 + 1] +
             (qz - sp[i2 * 3 + 2]) * sn[i2 * 3 + 2];
  float m = d1 + d2;
  float sg = (m > 0.f) ? 1.f : ((m < 0.f) ? -1.f : 0.f);
  float pred = isOff ? off_pred[q] : near_pred[q - M_QRY];
  float contrib = fmaxf(0.f, -pred * sg);

  __shared__ float red[256];
  int t = threadIdx.x;
  red[t] = contrib;
  __syncthreads();
  for (int s = 128; s > 0; s >>= 1) {
    if (t < s) red[t] += red[t + s];
    __syncthreads();
  }
  if (t == 0) part[blockIdx.x] = red[0];
}

// ---------------- K4: fused GEMM1+GEMM2 — dz2 passes through LDS ----------------
// 512 thr = 8 waves; block owns 32 rows. Phase 1: z2->h2, pred partials, dz2
// frags into tlds. Phase 2: dh1 -> dz1 -> grad; inlined sdf/eik/gradn reduce.
__global__ __launch_bounds__(512) void gemm_fused(
    const _Float16* __restrict__ h1f_hi, const _Float16* __restrict__ h1f_lo,
    const _Float16* __restrict__ w2f_hi, const _Float16* __restrict__ w2f_lo,
    const _Float16* __restrict__ w2tf_hi, const _Float16* __restrict__ w2tf_lo,
    const _Float16* __restrict__ h1C, const float* __restrict__ W1,
    const float* __restrict__ b2, const float* __restrict__ W3,
    const float* __restrict__ b3, const float* __restrict__ sn,
    float* __restrict__ sdf_part,         // [256]
    float* __restrict__ eg2) {            // [256][2]
  __shared__ __align__(16) _Float16 tlds[8][2][32][40]; // 40KB
  __shared__ float predb[8][32];
  __shared__ float gb[8][32][3];
  int tid = threadIdx.x, lane = tid & 63, wid = tid >> 6;
  int rb = blockIdx.x;                    // 0..255
  int nl = lane & 31, half = lane >> 5;

  // ---------- phase 1: z2 = h1 @ W2 ----------
  {
    int cb = wid;
    f32x16 acc = {};
#pragma unroll
    for (int s = 0; s < 16; s++) {
      f16x8 ah = *(const f16x8*)&h1f_hi[(((size_t)rb * 16 + s) * 64 + lane) * 8];
      f16x8 al = *(const f16x8*)&h1f_lo[(((size_t)rb * 16 + s) * 64 + lane) * 8];
      f16x8 bh = *(const f16x8*)&w2f_hi[(((size_t)cb * 16 + s) * 64 + lane) * 8];
      f16x8 bl = *(const f16x8*)&w2f_lo[(((size_t)cb * 16 + s) * 64 + lane) * 8];
      acc = __builtin_amdgcn_mfma_f32_32x32x16_f16(ah, bh, acc, 0, 0, 0);
      acc = __builtin_amdgcn_mfma_f32_32x32x16_f16(al, bh, acc, 0, 0, 0);
      acc = __builtin_amdgcn_mfma_f32_32x32x16_f16(ah, bl, acc, 0, 0, 0);
    }
    int n = cb * 32 + nl;
    float b2n = b2[n], w3n = W3[n];
    float psum[16];
    _Float16 dh[16], dl[16];
#pragma unroll
    for (int r = 0; r < 16; r++) {
      float z = acc[r] + b2n;
      float h2 = fmaxf(z, 0.f) + log1pf(expf(-fabsf(z)));
      psum[r] = h2 * w3n;
      float dz2 = w3n * (1.f - expf(-h2));
      _Float16 hd = (_Float16)dz2;
      dh[r] = hd; dl[r] = (_Float16)(dz2 - (float)hd);
    }
#pragma unroll
    for (int r = 0; r < 16; r++) {
#pragma unroll
      for (int m = 1; m <= 16; m <<= 1) psum[r] += __shfl_xor(psum[r], m, 64);
    }
    if (nl == 0) {
#pragma unroll
      for (int r = 0; r < 16; r++) predb[cb][RMAP(r, half)] = psum[r];
    }
#pragma unroll
    for (int r = 0; r < 16; r++) {
      int rw = RMAP(r, half);
      tlds[wid][0][rw][nl] = dh[r];
      tlds[wid][1][rw][nl] = dl[r];
    }
  }
  __syncthreads();

  // ---------- phase 2: dh1 = dz2 @ W2^T ; grad ----------
  {
    int cb2 = wid;
    f32x16 acc = {};
#pragma unroll
    for (int s = 0; s < 16; s++) {
      // dz2 A-frags from LDS: frag[s][lane] = tlds[s>>1][*][nl][(s&1)*16 + half*8]
      f16x8 ah = *(const f16x8*)&tlds[s >> 1][0][nl][(s & 1) * 16 + half * 8];
      f16x8 al = *(const f16x8*)&tlds[s >> 1][1][nl][(s & 1) * 16 + half * 8];
      f16x8 bh = *(const f16x8*)&w2tf_hi[(((size_t)cb2 * 16 + s) * 64 + lane) * 8];
      f16x8 bl = *(const f16x8*)&w2tf_lo[(((size_t)cb2 * 16 + s) * 64 + lane) * 8];
      acc = __builtin_amdgcn_mfma_f32_32x32x16_f16(ah, bh, acc, 0, 0, 0);
      acc = __builtin_amdgcn_mfma_f32_32x32x16_f16(al, bh, acc, 0, 0, 0);
      acc = __builtin_amdgcn_mfma_f32_32x32x16_f16(ah, bl, acc, 0, 0, 0);
    }
    int j = cb2 * 32 + nl;
    float w10 = W1[j], w11 = W1[256 + j], w12 = W1[512 + j];
    float gx[16], gy[16], gz[16];
#pragma unroll
    for (int r = 0; r < 16; r++) {
      int row = rb * 32 + RMAP(r, half);
      float h1 = (float)h1C[(size_t)row * 256 + j];
      float s1 = 1.f - expf(-h1);
      float dz1 = acc[r] * s1;
      gx[r] = dz1 * w10; gy[r] = dz1 * w11; gz[r] = dz1 * w12;
    }
#pragma unroll
    for (int r = 0; r < 16; r++) {
#pragma unroll
      for (int m = 1; m <= 16; m <<= 1) {
        gx[r] += __shfl_xor(gx[r], m, 64);
        gy[r] += __shfl_xor(gy[r], m, 64);
        gz[r] += __shfl_xor(gz[r], m, 64);
      }
    }
    if (nl == 0) {
#pragma unroll
      for (int r = 0; r < 16; r++) {
        int row32 = RMAP(r, half);
        gb[cb2][row32][0] = gx[r];
        gb[cb2][row32][1] = gy[r];
        gb[cb2][row32][2] = gz[r];
      }
    }
  }
  __syncthreads();

  if (tid < 64) {
    int row32 = tid & 31;
    float p = b3[0];
    float sgx = 0.f, sgy = 0.f, sgz = 0.f;
#pragma unroll
    for (int c8 = 0; c8 < 8; c8++) {
      p += predb[c8][row32];
      sgx += gb[c8][row32][0];
      sgy += gb[c8][row32][1];
      sgz += gb[c8][row32][2];
    }
    int row = rb * 32 + row32;
    float n0 = sn[row * 3 + 0], n1 = sn[row * 3 + 1], n2 = sn[row * 3 + 2];
    float nrm = sqrtf(sgx * sgx + sgy * sgy + sgz * sgz);
    float ee = (nrm - 1.f) * (nrm - 1.f);
    float gg = (sgx - n0) * (sgx - n0) + (sgy - n1) * (sgy - n1) + (sgz - n2) * (sgz - n2);
    float vee = (tid < 32) ? ee : 0.f;
    float vgg = (tid < 32) ? gg : 0.f;
    float vsq = (tid < 32) ? p * p : 0.f;
    for (int off = 32; off > 0; off >>= 1) {
      vee += __shfl_down(vee, off);
      vgg += __shfl_down(vgg, off);
      vsq += __shfl_down(vsq, off);
    }
    if (tid == 0) {
      sdf_part[rb] = vsq;
      eg2[rb * 2 + 0] = vee;
      eg2[rb * 2 + 1] = vgg;
    }
  }
}

// ---------------- K5: final reduce (tiny) ----------------
__global__ __launch_bounds__(256) void finalize(
    const float* __restrict__ sdf_part,   // 256
    const float* __restrict__ ori_part,   // 256
    const float* __restrict__ eg2,        // 512
    float* __restrict__ out) {
  __shared__ float red[256];
  int t = threadIdx.x;
  float s_sdf = sdf_part[t];
  float s_ori = (t < 128) ? ori_part[t] : 0.f;
  float s_near = (t < 128) ? ori_part[128 + t] : 0.f;
  float s_eik = eg2[t * 2 + 0];
  float s_gn = eg2[t * 2 + 1];

  float S[5];
  float vals[5] = {s_sdf, s_ori, s_near, s_eik, s_gn};
  for (int v = 0; v < 5; v++) {
    red[t] = vals[v];
    __syncthreads();
    for (int s = 128; s > 0; s >>= 1) {
      if (t < s) red[t] += red[t + s];
      __syncthreads();
    }
    S[v] = red[0];
    __syncthreads();
  }
  if (t == 0) {
    float sdf = S[0] / 8192.f;
    float ori = S[1] / 32768.f;
    float nearo = S[2] / 32768.f;
    float eik = S[3] / 8192.f;
    float gn = S[4] / 24576.f;
    out[0] = 7000.f * sdf + 600.f * eik + 500.f * ori + 10.f * nearo + 200.f * gn;
    out[1] = sdf;
    out[2] = eik;
    out[3] = ori;
    out[4] = nearo;
    out[5] = gn;
  }
}

extern "C" void kernel_launch(void* const* d_in, const int* in_sizes, int n_in,
                              void* d_out, int out_size, void* d_ws, size_t ws_size,
                              hipStream_t stream) {
  const float* sp       = (const float*)d_in[0];
  const float* sn       = (const float*)d_in[1];
  const float* offp     = (const float*)d_in[2];
  const float* nearp    = (const float*)d_in[3];
  const float* off_pred = (const float*)d_in[4];
  const float* near_pred= (const float*)d_in[5];
  const float* W1 = (const float*)d_in[6];
  const float* b1 = (const float*)d_in[7];
  const float* W2 = (const float*)d_in[8];
  const float* b2 = (const float*)d_in[9];
  const float* W3 = (const float*)d_in[10];
  const float* b3 = (const float*)d_in[11];

  float* ws = (float*)d_ws;
  uint32* keys     = (uint32*)ws;                 // 524288 u32 @0
  _Float16* AqG    = (_Float16*)(ws + 524288);    // 1048576 f16
  _Float16* BsG    = (_Float16*)(ws + 1048576);   // 131072 f16
  float* c0G       = ws + 1114112;                // 65536 fl
  _Float16* h1f_hi = (_Float16*)(ws + 1179648);   // 2097152 f16 each
  _Float16* h1f_lo = (_Float16*)(ws + 2228224);
  _Float16* h1C    = (_Float16*)(ws + 3276800);
  _Float16* w2f_hi = (_Float16*)(ws + 6422528);   // 65536 f16 each
  _Float16* w2f_lo = (_Float16*)(ws + 6455296);
  _Float16* w2tf_hi= (_Float16*)(ws + 6488064);
  _Float16* w2tf_lo= (_Float16*)(ws + 6520832);
  float* sdf_part  = ws + 6553600;                // 256
  float* ori_part  = ws + 6553856;                // 256
  float* eg2       = ws + 6554112;                // 512
  float* out = (float*)d_out;

  prep_all<<<608, 256, 0, stream>>>(sp, offp, nearp, W1, b1, W2,
                                    AqG, BsG, c0G,
                                    w2f_hi, w2f_lo, w2tf_hi, w2tf_lo,
                                    h1f_hi, h1f_lo, h1C);
  scan_knn2<<<2048, 256, 0, stream>>>((const float4*)BsG, (const float4*)AqG, c0G, keys);
  knn_finish<<<256, 256, 0, stream>>>(keys, sp, sn, offp, nearp, off_pred, near_pred, ori_part);
  gemm_fused<<<256, 512, 0, stream>>>(h1f_hi, h1f_lo, w2f_hi, w2f_lo,
                                      w2tf_hi, w2tf_lo, h1C, W1,
                                      b2, W3, b3, sn, sdf_part, eg2);
  finalize<<<1, 256, 0, stream>>>(sdf_part, ori_part, eg2, out);
}

// Round 10
// 83.068 us; speedup vs baseline: 3.0362x; 1.0025x over previous
//
#include <hip/hip_runtime.h>
#include <math.h>

typedef unsigned int uint32;

#define N_SURF 8192
#define M_QRY  32768
#define M_TOT  65536
#define HID    256

using f16x8  = __attribute__((ext_vector_type(8)))  _Float16;
using f32x16 = __attribute__((ext_vector_type(16))) float;

static __device__ __forceinline__ uint32 umin32(uint32 a, uint32 b) { return a < b ? a : b; }
static __device__ __forceinline__ uint32 umax32(uint32 a, uint32 b) { return a > b ? a : b; }

__device__ __forceinline__ void gload_lds16(const void* g, void* l) {
  __builtin_amdgcn_global_load_lds(
      (const __attribute__((address_space(1))) unsigned int*)g,
      (__attribute__((address_space(3))) unsigned int*)l, 16, 0, 0);
}

// MFMA with destination in plain "v"-class regs (gfx950 unified file) so the
// integer tracker reads results without v_accvgpr_read traffic.
static __device__ __forceinline__ f32x16 mfma_v(f16x8 a, f16x8 b, f32x16 c) {
  f32x16 d;
  asm("v_mfma_f32_32x32x16_f16 %0, %1, %2, %3"
      : "=&v"(d) : "v"(a), "v"(b), "v"(c));
  return d;
}

#define RMAP(r, half) (((r) & 3) + 8 * ((r) >> 2) + 4 * (half))

// ---- ws layout (float offsets) ----
// keys u32[524288] @0 ; AqG f16[1048576] @524288 ; BsG f16[131072] @1048576 ;
// c0G f32[65536] @1114112 ; h1f_hi @1179648 ; h1f_lo @2228224 ; h1C @3276800 ;
// w2f_hi @6422528 ; w2f_lo @6455296 ; w2tf_hi @6488064 ; w2tf_lo @6520832 ;
// sdf_part[256] @6553600 ; ori_part[256] @6553856 ; eg2[512] @6554112

// ---------------- K1: prep_all — queries, surface frags, W2 frags, layer-1 ----------------
__global__ __launch_bounds__(256) void prep_all(
    const float* __restrict__ sp,
    const float* __restrict__ offp, const float* __restrict__ nearp,
    const float* __restrict__ W1, const float* __restrict__ b1,
    const float* __restrict__ W2,
    _Float16* __restrict__ AqG, _Float16* __restrict__ BsG,
    float* __restrict__ c0G,
    _Float16* __restrict__ w2f_hi, _Float16* __restrict__ w2f_lo,
    _Float16* __restrict__ w2tf_hi, _Float16* __restrict__ w2tf_lo,
    _Float16* __restrict__ h1f_hi, _Float16* __restrict__ h1f_lo,
    _Float16* __restrict__ h1C) {
  int bid = blockIdx.x, tid = threadIdx.x;
  if (bid < 256) {                    // ---- query features ----
    int q = bid * 256 + tid;
    const float* p = (q < M_QRY) ? (offp + q * 3) : (nearp + (q - M_QRY) * 3);
    float x = p[0], y = p[1], z = p[2];
    _Float16 hx = (_Float16)x, hy = (_Float16)y, hz = (_Float16)z;
    _Float16 lx = (_Float16)(x - (float)hx);
    _Float16 ly = (_Float16)(y - (float)hy);
    _Float16 lz = (_Float16)(z - (float)hz);
    float tx = (float)hx + (float)lx, ty = (float)hy + (float)ly, tz = (float)hz + (float)lz;
    _Float16 av[16] = {hx, hy, hz, lx, ly, lz, hx, hy, hz, lx, ly, lz,
                       (_Float16)1.0f, (_Float16)1.0f, (_Float16)1.0f, (_Float16)0.0f};
    float4* dst = (float4*)&AqG[(size_t)q * 16];
    dst[0] = *(float4*)&av[0];
    dst[1] = *(float4*)&av[8];
    c0G[q] = 0.5f * (tx * tx + ty * ty + tz * tz);
  } else if (bid < 288) {             // ---- surface point features ----
    int i = (bid - 256) * 256 + tid;  // 0..8191
    float x = sp[i * 3 + 0], y = sp[i * 3 + 1], z = sp[i * 3 + 2];
    _Float16 hx = (_Float16)x, hy = (_Float16)y, hz = (_Float16)z;
    _Float16 lx = (_Float16)(x - (float)hx);
    _Float16 ly = (_Float16)(y - (float)hy);
    _Float16 lz = (_Float16)(z - (float)hz);
    float tx = (float)hx + (float)lx, ty = (float)hy + (float)ly, tz = (float)hz + (float)lz;
    float w = 0.5f * (tx * tx + ty * ty + tz * tz);
    _Float16 wh = (_Float16)w;
    float r1 = w - (float)wh;
    _Float16 wl = (_Float16)r1;
    _Float16 wll = (_Float16)(r1 - (float)wl);
    _Float16 nhx = -hx, nhy = -hy, nhz = -hz, nlx = -lx, nly = -ly, nlz = -lz;
    _Float16 b0[8] = {nhx, nhy, nhz, nhx, nhy, nhz, nlx, nly};            // k0..7
    _Float16 b1v[8] = {nlz, nlx, nly, nlz, wh, wl, wll, (_Float16)0.0f};  // k8..15
    int tile = i >> 5, pcol = i & 31;
    *(float4*)&BsG[(size_t)((tile * 2 + 0) * 32 + pcol) * 8] = *(float4*)&b0[0];
    *(float4*)&BsG[(size_t)((tile * 2 + 1) * 32 + pcol) * 8] = *(float4*)&b1v[0];
  } else if (bid < 352) {             // ---- W2 / W2^T fragment packs ----
    int u = (bid - 288) * 256 + tid;  // 0..16383
    int uu = u & 8191;
    int lane = uu & 63, su = uu >> 6;
    int cb = su >> 4, s = su & 15;
    int nl = lane & 31, hf = lane >> 5;
    float v[8];
    if (u < 8192) {
#pragma unroll
      for (int e = 0; e < 8; e++) v[e] = W2[(s * 16 + hf * 8 + e) * 256 + cb * 32 + nl];
    } else {
#pragma unroll
      for (int e = 0; e < 8; e++) v[e] = W2[(cb * 32 + nl) * 256 + s * 16 + hf * 8 + e];
    }
    _Float16 hi[8], lo[8];
#pragma unroll
    for (int e = 0; e < 8; e++) {
      _Float16 h = (_Float16)v[e];
      hi[e] = h; lo[e] = (_Float16)(v[e] - (float)h);
    }
    _Float16* dh = (u < 8192) ? w2f_hi : w2tf_hi;
    _Float16* dl = (u < 8192) ? w2f_lo : w2tf_lo;
    *(float4*)&dh[(size_t)uu * 8] = *(float4*)hi;
    *(float4*)&dl[(size_t)uu * 8] = *(float4*)lo;
  } else {                            // ---- layer-1 h1 frags + h1C ----
    int rb = bid - 352;               // 0..255
    int row = rb * 32 + (tid >> 3);
    int oct = tid & 7;
    float px = sp[row * 3 + 0], py = sp[row * 3 + 1], pz = sp[row * 3 + 2];
#pragma unroll
    for (int it = 0; it < 4; ++it) {
      int j0 = it * 64 + oct * 8;
      _Float16 hh[8], hl[8];
#pragma unroll
      for (int e = 0; e < 8; e++) {
        int j = j0 + e;
        float z = fmaf(px, W1[j], fmaf(py, W1[256 + j], fmaf(pz, W1[512 + j], b1[j])));
        float h = fmaxf(z, 0.f) + log1pf(expf(-fabsf(z)));
        _Float16 hi = (_Float16)h;
        hh[e] = hi; hl[e] = (_Float16)(h - (float)hi);
      }
      int s = it * 4 + (oct >> 1), hf = oct & 1;
      size_t uidx = ((size_t)(rb * 16 + s)) * 64 + (row & 31) + 32 * hf;
      *(float4*)&h1f_hi[uidx * 8] = *(float4*)hh;
      *(float4*)&h1f_lo[uidx * 8] = *(float4*)hl;
      *(float4*)&h1C[(size_t)row * 256 + j0] = *(float4*)hh;
    }
  }
}

// ---------------- K2: MFMA 2-NN scan — A/B alternating pairs, no rotation copies ----------------
#define TRACK2(d0v, d1v, s0v, s1v)                                        \
  _Pragma("unroll")                                                       \
  for (int r = 0; r < 16; r++) {                                          \
    uint32 kA, kB;                                                        \
    asm("v_and_or_b32 %0, %3, %5, %6\n\t"                                 \
        "v_and_or_b32 %1, %4, %5, %7\n\t"                                 \
        "v_min3_u32 %2, %2, %0, %1"                                       \
        : "=&v"(kA), "=&v"(kB), "+v"(b1[r])                               \
        : "v"(d0v[r]), "v"(d1v[r]), "v"(vmask), "s"(s0v), "s"(s1v));      \
  }

__global__ __launch_bounds__(256) void scan_knn2(
    const float4* __restrict__ BsG,    // 8192*2 16B units, frag order
    const float4* __restrict__ AqG,
    const float* __restrict__ c0G,
    uint32* __restrict__ keys) {       // [4][65536][2]
  __shared__ __align__(16) float4 Bsh[2048];  // 32KB (2 x 1024 units)
  int tid = threadIdx.x;
  int lane = tid & 63, wid = tid >> 6;
  int col = lane & 31, half = lane >> 5;
  int seg = blockIdx.x >> 9;           // 0..3
  int qb  = blockIdx.x & 511;
  int qbase = qb * 128 + wid * 32;

  f16x8 afrag = ((const f16x8*)AqG)[(qbase + col) * 2 + half];
  f32x16 c0f;
#pragma unroll
  for (int r = 0; r < 16; r++) c0f[r] = c0G[qbase + RMAP(r, half)];
  uint32 b1[16];
#pragma unroll
  for (int r = 0; r < 16; r++) b1[r] = 0xFFFFFFFFu;

  const char* gseg = (const char*)(BsG + (size_t)seg * 4096);  // 2048 pts
  char* lbase = (char*)&Bsh[0];
#pragma unroll
  for (int i = 0; i < 4; i++)
    gload_lds16(gseg + (size_t)(0 * 1024 + i * 256 + tid) * 16,
                lbase + ((0 * 1024 + i * 256 + tid) * 16));
#pragma unroll
  for (int i = 0; i < 4; i++)
    gload_lds16(gseg + (size_t)(1 * 1024 + i * 256 + tid) * 16,
                lbase + ((1024 + i * 256 + tid) * 16));

  uint32 vmask = 0xFFFFE000u;
  int tseg = seg * 64;                 // global tile base (64 tiles / segment)
#pragma unroll 1
  for (int c = 0; c < 4; c++) {
    if (c < 3) asm volatile("s_waitcnt vmcnt(4)" ::: "memory");
    else       asm volatile("s_waitcnt vmcnt(0)" ::: "memory");
    __builtin_amdgcn_s_barrier();
    const f16x8* bbuf = (const f16x8*)&Bsh[(c & 1) * 1024];
    int tbase = tseg + c * 16;
    // A holds even pairs (tiles 4g+0,4g+1), B holds odd pairs (tiles 4g+2,4g+3).
    f16x8 fA0 = bbuf[0 * 64 + lane];
    f16x8 fA1 = bbuf[1 * 64 + lane];
    f32x16 dA0 = mfma_v(afrag, fA0, c0f);
    f32x16 dA1 = mfma_v(afrag, fA1, c0f);
    f16x8 fB0 = bbuf[2 * 64 + lane];
    f16x8 fB1 = bbuf[3 * 64 + lane];
    f32x16 dB0 = mfma_v(afrag, fB0, c0f);
    f32x16 dB1 = mfma_v(afrag, fB1, c0f);
#pragma unroll
    for (int g = 0; g < 3; g++) {
      TRACK2(dA0, dA1, tbase + 4 * g + 0, tbase + 4 * g + 1);
      fA0 = bbuf[(4 * g + 4) * 64 + lane];
      fA1 = bbuf[(4 * g + 5) * 64 + lane];
      dA0 = mfma_v(afrag, fA0, c0f);
      dA1 = mfma_v(afrag, fA1, c0f);
      TRACK2(dB0, dB1, tbase + 4 * g + 2, tbase + 4 * g + 3);
      fB0 = bbuf[(4 * g + 6) * 64 + lane];
      fB1 = bbuf[(4 * g + 7) * 64 + lane];
      dB0 = mfma_v(afrag, fB0, c0f);
      dB1 = mfma_v(afrag, fB1, c0f);
    }
    TRACK2(dA0, dA1, tbase + 12, tbase + 13);
    TRACK2(dB0, dB1, tbase + 14, tbase + 15);
    __builtin_amdgcn_s_barrier();
    if (c + 2 < 4) {
      int nc = c + 2;
#pragma unroll
      for (int i = 0; i < 4; i++)
        gload_lds16(gseg + (size_t)(nc * 1024 + i * 256 + tid) * 16,
                    lbase + (((nc & 1) * 1024 + i * 256 + tid) * 16));
    }
  }

  // tile-keys -> full-index keys: idx = tile*32 + col
#pragma unroll
  for (int r = 0; r < 16; r++) {
    uint32 t1 = b1[r];
    b1[r] = (t1 & 0xFFFFE000u) | (((t1 & 0xFFu) << 5) | (uint32)col);
  }
  uint32 b2[16];
#pragma unroll
  for (int r = 0; r < 16; r++) b2[r] = 0xFFFFFFFFu;
#pragma unroll
  for (int r = 0; r < 16; r++) {
#pragma unroll
    for (int m = 1; m <= 16; m <<= 1) {
      uint32 o1 = (uint32)__shfl_xor((int)b1[r], m, 64);
      uint32 o2 = (uint32)__shfl_xor((int)b2[r], m, 64);
      uint32 n1 = umin32(b1[r], o1);
      uint32 n2 = umin32(umax32(b1[r], o1), umin32(b2[r], o2));
      b1[r] = n1; b2[r] = n2;
    }
  }
  if (col == 0) {
#pragma unroll
    for (int r = 0; r < 16; r++) {
      int row = RMAP(r, half);
      keys[(size_t)seg * 131072 + (size_t)(qbase + row) * 2 + 0] = b1[r];
      keys[(size_t)seg * 131072 + (size_t)(qbase + row) * 2 + 1] = b2[r];
    }
  }
}

// ---------------- K3: merge 4 segs, signs, orientation partials ----------------
__global__ __launch_bounds__(256) void knn_finish(
    const uint32* __restrict__ keys,
    const float* __restrict__ sp, const float* __restrict__ sn,
    const float* __restrict__ offp, const float* __restrict__ nearp,
    const float* __restrict__ off_pred, const float* __restrict__ near_pred,
    float* __restrict__ part) {
  int q = blockIdx.x * 256 + threadIdx.x;
  bool isOff = q < M_QRY;
  const float* qp = isOff ? (offp + q * 3) : (nearp + (q - M_QRY) * 3);
  float qx = qp[0], qy = qp[1], qz = qp[2];
  uint32 m1 = 0xFFFFFFFFu, m2 = 0xFFFFFFFFu;
#pragma unroll
  for (int s = 0; s < 4; s++) {
    uint32 k1 = keys[(size_t)s * 131072 + (size_t)q * 2 + 0];
    uint32 k2 = keys[(size_t)s * 131072 + (size_t)q * 2 + 1];
    m2 = umin32(m2, umax32(m1, k1)); m1 = umin32(m1, k1);
    m2 = umin32(m2, umax32(m1, k2)); m1 = umin32(m1, k2);
  }
  int i1 = (int)(m1 & 8191u), i2 = (int)(m2 & 8191u);
  float d1 = (qx - sp[i1 * 3 + 0]) * sn[i1 * 3 + 0] +
             (qy - sp[i1 * 3 + 1]) * sn[i1 * 3 + 1] +
             (qz - sp[i1 * 3 + 2]) * sn[i1 * 3 + 2];
  float d2 = (qx - sp[i2 * 3 + 0]) * sn[i2 * 3 + 0] +
             (qy - sp[i2 * 3 + 1]) * sn[i2 * 3 + 1] +
             (qz - sp[i2 * 3 + 2]) * sn[i2 * 3 + 2];
  float m = d1 + d2;
  float sg = (m > 0.f) ? 1.f : ((m < 0.f) ? -1.f : 0.f);
  float pred = isOff ? off_pred[q] : near_pred[q - M_QRY];
  float contrib = fmaxf(0.f, -pred * sg);

  __shared__ float red[256];
  int t = threadIdx.x;
  red[t] = contrib;
  __syncthreads();
  for (int s = 128; s > 0; s >>= 1) {
    if (t < s) red[t] += red[t + s];
    __syncthreads();
  }
  if (t == 0) part[blockIdx.x] = red[0];
}

// ---------------- K4: fused GEMM1+GEMM2 — dz2 passes through LDS ----------------
__global__ __launch_bounds__(512) void gemm_fused(
    const _Float16* __restrict__ h1f_hi, const _Float16* __restrict__ h1f_lo,
    const _Float16* __restrict__ w2f_hi, const _Float16* __restrict__ w2f_lo,
    const _Float16* __restrict__ w2tf_hi, const _Float16* __restrict__ w2tf_lo,
    const _Float16* __restrict__ h1C, const float* __restrict__ W1,
    const float* __restrict__ b2, const float* __restrict__ W3,
    const float* __restrict__ b3, const float* __restrict__ sn,
    float* __restrict__ sdf_part,         // [256]
    float* __restrict__ eg2) {            // [256][2]
  __shared__ __align__(16) _Float16 tlds[8][2][32][40]; // 40KB
  __shared__ float predb[8][32];
  __shared__ float gb[8][32][3];
  int tid = threadIdx.x, lane = tid & 63, wid = tid >> 6;
  int rb = blockIdx.x;                    // 0..255
  int nl = lane & 31, half = lane >> 5;

  // ---------- phase 1: z2 = h1 @ W2 ----------
  {
    int cb = wid;
    f32x16 acc = {};
#pragma unroll
    for (int s = 0; s < 16; s++) {
      f16x8 ah = *(const f16x8*)&h1f_hi[(((size_t)rb * 16 + s) * 64 + lane) * 8];
      f16x8 al = *(const f16x8*)&h1f_lo[(((size_t)rb * 16 + s) * 64 + lane) * 8];
      f16x8 bh = *(const f16x8*)&w2f_hi[(((size_t)cb * 16 + s) * 64 + lane) * 8];
      f16x8 bl = *(const f16x8*)&w2f_lo[(((size_t)cb * 16 + s) * 64 + lane) * 8];
      acc = __builtin_amdgcn_mfma_f32_32x32x16_f16(ah, bh, acc, 0, 0, 0);
      acc = __builtin_amdgcn_mfma_f32_32x32x16_f16(al, bh, acc, 0, 0, 0);
      acc = __builtin_amdgcn_mfma_f32_32x32x16_f16(ah, bl, acc, 0, 0, 0);
    }
    int n = cb * 32 + nl;
    float b2n = b2[n], w3n = W3[n];
    float psum[16];
    _Float16 dh[16], dl[16];
#pragma unroll
    for (int r = 0; r < 16; r++) {
      float z = acc[r] + b2n;
      float h2 = fmaxf(z, 0.f) + log1pf(expf(-fabsf(z)));
      psum[r] = h2 * w3n;
      float dz2 = w3n * (1.f - expf(-h2));
      _Float16 hd = (_Float16)dz2;
      dh[r] = hd; dl[r] = (_Float16)(dz2 - (float)hd);
    }
#pragma unroll
    for (int r = 0; r < 16; r++) {
#pragma unroll
      for (int m = 1; m <= 16; m <<= 1) psum[r] += __shfl_xor(psum[r], m, 64);
    }
    if (nl == 0) {
#pragma unroll
      for (int r = 0; r < 16; r++) predb[cb][RMAP(r, half)] = psum[r];
    }
#pragma unroll
    for (int r = 0; r < 16; r++) {
      int rw = RMAP(r, half);
      tlds[wid][0][rw][nl] = dh[r];
      tlds[wid][1][rw][nl] = dl[r];
    }
  }
  __syncthreads();

  // ---------- phase 2: dh1 = dz2 @ W2^T ; grad ----------
  {
    int cb2 = wid;
    f32x16 acc = {};
#pragma unroll
    for (int s = 0; s < 16; s++) {
      f16x8 ah = *(const f16x8*)&tlds[s >> 1][0][nl][(s & 1) * 16 + half * 8];
      f16x8 al = *(const f16x8*)&tlds[s >> 1][1][nl][(s & 1) * 16 + half * 8];
      f16x8 bh = *(const f16x8*)&w2tf_hi[(((size_t)cb2 * 16 + s) * 64 + lane) * 8];
      f16x8 bl = *(const f16x8*)&w2tf_lo[(((size_t)cb2 * 16 + s) * 64 + lane) * 8];
      acc = __builtin_amdgcn_mfma_f32_32x32x16_f16(ah, bh, acc, 0, 0, 0);
      acc = __builtin_amdgcn_mfma_f32_32x32x16_f16(al, bh, acc, 0, 0, 0);
      acc = __builtin_amdgcn_mfma_f32_32x32x16_f16(ah, bl, acc, 0, 0, 0);
    }
    int j = cb2 * 32 + nl;
    float w10 = W1[j], w11 = W1[256 + j], w12 = W1[512 + j];
    float gx[16], gy[16], gz[16];
#pragma unroll
    for (int r = 0; r < 16; r++) {
      int row = rb * 32 + RMAP(r, half);
      float h1 = (float)h1C[(size_t)row * 256 + j];
      float s1 = 1.f - expf(-h1);
      float dz1 = acc[r] * s1;
      gx[r] = dz1 * w10; gy[r] = dz1 * w11; gz[r] = dz1 * w12;
    }
#pragma unroll
    for (int r = 0; r < 16; r++) {
#pragma unroll
      for (int m = 1; m <= 16; m <<= 1) {
        gx[r] += __shfl_xor(gx[r], m, 64);
        gy[r] += __shfl_xor(gy[r], m, 64);
        gz[r] += __shfl_xor(gz[r], m, 64);
      }
    }
    if (nl == 0) {
#pragma unroll
      for (int r = 0; r < 16; r++) {
        int row32 = RMAP(r, half);
        gb[cb2][row32][0] = gx[r];
        gb[cb2][row32][1] = gy[r];
        gb[cb2][row32][2] = gz[r];
      }
    }
  }
  __syncthreads();

  if (tid < 64) {
    int row32 = tid & 31;
    float p = b3[0];
    float sgx = 0.f, sgy = 0.f, sgz = 0.f;
#pragma unroll
    for (int c8 = 0; c8 < 8; c8++) {
      p += predb[c8][row32];
      sgx += gb[c8][row32][0];
      sgy += gb[c8][row32][1];
      sgz += gb[c8][row32][2];
    }
    int row = rb * 32 + row32;
    float n0 = sn[row * 3 + 0], n1 = sn[row * 3 + 1], n2 = sn[row * 3 + 2];
    float nrm = sqrtf(sgx * sgx + sgy * sgy + sgz * sgz);
    float ee = (nrm - 1.f) * (nrm - 1.f);
    float gg = (sgx - n0) * (sgx - n0) + (sgy - n1) * (sgy - n1) + (sgz - n2) * (sgz - n2);
    float vee = (tid < 32) ? ee : 0.f;
    float vgg = (tid < 32) ? gg : 0.f;
    float vsq = (tid < 32) ? p * p : 0.f;
    for (int off = 32; off > 0; off >>= 1) {
      vee += __shfl_down(vee, off);
      vgg += __shfl_down(vgg, off);
      vsq += __shfl_down(vsq, off);
    }
    if (tid == 0) {
      sdf_part[rb] = vsq;
      eg2[rb * 2 + 0] = vee;
      eg2[rb * 2 + 1] = vgg;
    }
  }
}

// ---------------- K5: final reduce (tiny) ----------------
__global__ __launch_bounds__(256) void finalize(
    const float* __restrict__ sdf_part,   // 256
    const float* __restrict__ ori_part,   // 256
    const float* __restrict__ eg2,        // 512
    float* __restrict__ out) {
  __shared__ float red[256];
  int t = threadIdx.x;
  float s_sdf = sdf_part[t];
  float s_ori = (t < 128) ? ori_part[t] : 0.f;
  float s_near = (t < 128) ? ori_part[128 + t] : 0.f;
  float s_eik = eg2[t * 2 + 0];
  float s_gn = eg2[t * 2 + 1];

  float S[5];
  float vals[5] = {s_sdf, s_ori, s_near, s_eik, s_gn};
  for (int v = 0; v < 5; v++) {
    red[t] = vals[v];
    __syncthreads();
    for (int s = 128; s > 0; s >>= 1) {
      if (t < s) red[t] += red[t + s];
      __syncthreads();
    }
    S[v] = red[0];
    __syncthreads();
  }
  if (t == 0) {
    float sdf = S[0] / 8192.f;
    float ori = S[1] / 32768.f;
    float nearo = S[2] / 32768.f;
    float eik = S[3] / 8192.f;
    float gn = S[4] / 24576.f;
    out[0] = 7000.f * sdf + 600.f * eik + 500.f * ori + 10.f * nearo + 200.f * gn;
    out[1] = sdf;
    out[2] = eik;
    out[3] = ori;
    out[4] = nearo;
    out[5] = gn;
  }
}

extern "C" void kernel_launch(void* const* d_in, const int* in_sizes, int n_in,
                              void* d_out, int out_size, void* d_ws, size_t ws_size,
                              hipStream_t stream) {
  const float* sp       = (const float*)d_in[0];
  const float* sn       = (const float*)d_in[1];
  const float* offp     = (const float*)d_in[2];
  const float* nearp    = (const float*)d_in[3];
  const float* off_pred = (const float*)d_in[4];
  const float* near_pred= (const float*)d_in[5];
  const float* W1 = (const float*)d_in[6];
  const float* b1 = (const float*)d_in[7];
  const float* W2 = (const float*)d_in[8];
  const float* b2 = (const float*)d_in[9];
  const float* W3 = (const float*)d_in[10];
  const float* b3 = (const float*)d_in[11];

  float* ws = (float*)d_ws;
  uint32* keys     = (uint32*)ws;                 // 524288 u32 @0
  _Float16* AqG    = (_Float16*)(ws + 524288);    // 1048576 f16
  _Float16* BsG    = (_Float16*)(ws + 1048576);   // 131072 f16
  float* c0G       = ws + 1114112;                // 65536 fl
  _Float16* h1f_hi = (_Float16*)(ws + 1179648);   // 2097152 f16 each
  _Float16* h1f_lo = (_Float16*)(ws + 2228224);
  _Float16* h1C    = (_Float16*)(ws + 3276800);
  _Float16* w2f_hi = (_Float16*)(ws + 6422528);   // 65536 f16 each
  _Float16* w2f_lo = (_Float16*)(ws + 6455296);
  _Float16* w2tf_hi= (_Float16*)(ws + 6488064);
  _Float16* w2tf_lo= (_Float16*)(ws + 6520832);
  float* sdf_part  = ws + 6553600;                // 256
  float* ori_part  = ws + 6553856;                // 256
  float* eg2       = ws + 6554112;                // 512
  float* out = (float*)d_out;

  prep_all<<<608, 256, 0, stream>>>(sp, offp, nearp, W1, b1, W2,
                                    AqG, BsG, c0G,
                                    w2f_hi, w2f_lo, w2tf_hi, w2tf_lo,
                                    h1f_hi, h1f_lo, h1C);
  scan_knn2<<<2048, 256, 0, stream>>>((const float4*)BsG, (const float4*)AqG, c0G, keys);
  knn_finish<<<256, 256, 0, stream>>>(keys, sp, sn, offp, nearp, off_pred, near_pred, ori_part);
  gemm_fused<<<256, 512, 0, stream>>>(h1f_hi, h1f_lo, w2f_hi, w2f_lo,
                                      w2tf_hi, w2tf_lo, h1C, W1,
                                      b2, W3, b3, sn, sdf_part, eg2);
  finalize<<<1, 256, 0, stream>>>(sdf_part, ori_part, eg2, out);
}